// Round 1
// baseline (5905.227 us; speedup 1.0000x reference)
//
#include <hip/hip_runtime.h>
#include <hip/hip_bf16.h>

#define L_ 2
#define D_ 512
#define H_ 8
#define DK_ 64
#define F_ 2048
#define E_ 8
#define V_ 32000
#define B_ 2
#define S_ 1024
#define T_ 1024
#define NTOK (B_*S_)          // 2048 tokens (enc); dec identical
#define MAXPAD 4608           // N*K + E*63 rounded to 64
#define MAXRB  (MAXPAD/64)    // 72

// ---------------------------------------------------------------- embedding + PE
__global__ __launch_bounds__(256) void embed_pe(const int* __restrict__ toks,
                                                const float* __restrict__ emb,
                                                float* __restrict__ out, int Slen)
{
    int n = blockIdx.x;                 // 0 .. B*Slen-1
    int spos = n % Slen;
    int tok = toks[n];
    const float* erow = emb + (size_t)tok * D_;
    float* orow = out + (size_t)n * D_;
    for (int j = threadIdx.x; j < D_; j += 256) {
        int i = j >> 1;
        float arg = (float)spos * expf(-(float)i * 0.035977892f); // ln(10000)/256
        float pe = (j & 1) ? cosf(arg) : sinf(arg);
        orow[j] = erow[j] + pe;
    }
}

// ---------------------------------------------------------------- generic tiled GEMM
// C[M,N] = op(A)[M,Kd] @ W[Kd,N] + bias ; MODE 0=plain, 1=routed gather rows, 2=routed direct rows
template<int MODE, bool RELU>
__global__ __launch_bounds__(256) void gemm_k(
    const float* __restrict__ Abase, const float* __restrict__ Wbase,
    const float* __restrict__ biasbase, float* __restrict__ C,
    int M, int Kd, int N, int lda,
    const int* __restrict__ route_tok, const int* __restrict__ rb_expert,
    const int* __restrict__ pad_base, const int* __restrict__ counts)
{
    int row0 = blockIdx.y * 64;
    const float* Wm = Wbase;
    const float* bias = biasbase;
    int vend = M;
    if (MODE != 0) {
        int total = pad_base[E_];
        if (row0 >= total) return;
        int e = rb_expert[row0 >> 6];
        vend = pad_base[e] + counts[e];
        Wm = Wbase + (size_t)e * Kd * N;
        bias = biasbase + (size_t)e * N;
    }
    int col0 = blockIdx.x * 64;
    int tid = threadIdx.x;
    int tx = tid & 15, ty = tid >> 4;

    int lkk = tid & 15, lmb = tid >> 4;
    int arow[4];
    #pragma unroll
    for (int i = 0; i < 4; ++i) {
        int g = row0 + lmb + 16 * i;
        if (MODE == 0)            arow[i] = g;
        else if (g < vend)        arow[i] = (MODE == 1) ? route_tok[g] : g;
        else                      arow[i] = -1;
    }

    __shared__ float As[16][68];
    __shared__ float Ws[16][68];
    float acc[4][4] = {{0.f}};
    int lnn = tid & 63, lkb = tid >> 6;

    for (int k0 = 0; k0 < Kd; k0 += 16) {
        #pragma unroll
        for (int i = 0; i < 4; ++i) {
            int mm = lmb + 16 * i;
            As[lkk][mm] = (arow[i] >= 0) ? Abase[(size_t)arow[i] * lda + k0 + lkk] : 0.f;
        }
        #pragma unroll
        for (int i = 0; i < 4; ++i) {
            int kk = lkb + 4 * i;
            Ws[kk][lnn] = Wm[(size_t)(k0 + kk) * N + col0 + lnn];
        }
        __syncthreads();
        #pragma unroll
        for (int kk = 0; kk < 16; ++kk) {
            float4 av = *(const float4*)&As[kk][ty * 4];
            float4 bv = *(const float4*)&Ws[kk][tx * 4];
            float a[4] = {av.x, av.y, av.z, av.w};
            float b[4] = {bv.x, bv.y, bv.z, bv.w};
            #pragma unroll
            for (int i = 0; i < 4; ++i)
                #pragma unroll
                for (int j = 0; j < 4; ++j)
                    acc[i][j] += a[i] * b[j];
        }
        __syncthreads();
    }
    #pragma unroll
    for (int i = 0; i < 4; ++i) {
        int r = row0 + ty * 4 + i;
        if (MODE != 0 && r >= vend) continue;
        float4 o;
        float* po = &o.x;
        #pragma unroll
        for (int j = 0; j < 4; ++j) {
            float v = acc[i][j] + bias[col0 + tx * 4 + j];
            if (RELU) v = fmaxf(v, 0.f);
            po[j] = v;
        }
        *(float4*)&C[(size_t)r * N + col0 + tx * 4] = o;
    }
}

// ---------------------------------------------------------------- attention scores
// scores[bh, q, k] = (Q_h[q] . K_h[k]) / 8, masked (pad tokens, optional causal)
__global__ __launch_bounds__(256) void attn_scores(const float* __restrict__ q,
                                                   const float* __restrict__ k,
                                                   const int* __restrict__ toks,
                                                   float* __restrict__ scores, int causal)
{
    __shared__ float Qs[64][65];
    __shared__ float Ks[64][65];
    int bh = blockIdx.z; int b = bh >> 3; int h = bh & 7;
    int q0 = blockIdx.y * 64, k0 = blockIdx.x * 64;
    int tid = threadIdx.x;
    const float* qb = q + (size_t)b * S_ * D_ + h * DK_;
    const float* kb = k + (size_t)b * S_ * D_ + h * DK_;
    #pragma unroll
    for (int i = 0; i < 16; ++i) {
        int idx = tid + 256 * i;
        int r = idx >> 6, c = idx & 63;
        Qs[r][c] = qb[(size_t)(q0 + r) * D_ + c];
        Ks[r][c] = kb[(size_t)(k0 + r) * D_ + c];
    }
    __syncthreads();
    int tx = tid & 15, ty = tid >> 4;
    float acc[4][4] = {{0.f}};
    for (int d = 0; d < 64; ++d) {
        float a[4], bb[4];
        #pragma unroll
        for (int i = 0; i < 4; ++i) a[i] = Qs[ty + 16 * i][d];
        #pragma unroll
        for (int j = 0; j < 4; ++j) bb[j] = Ks[tx + 16 * j][d];
        #pragma unroll
        for (int i = 0; i < 4; ++i)
            #pragma unroll
            for (int j = 0; j < 4; ++j)
                acc[i][j] += a[i] * bb[j];
    }
    float* srow = scores + (size_t)bh * S_ * S_;
    #pragma unroll
    for (int i = 0; i < 4; ++i) {
        int qi = q0 + ty + 16 * i;
        #pragma unroll
        for (int j = 0; j < 4; ++j) {
            int ki = k0 + tx + 16 * j;
            bool keep = (toks[b * S_ + ki] != 0) && (!causal || ki <= qi);
            srow[(size_t)qi * S_ + ki] = keep ? acc[i][j] * 0.125f : -1e9f;
        }
    }
}

// ---------------------------------------------------------------- row softmax (1024 cols)
__global__ __launch_bounds__(256) void softmax_rows(float* __restrict__ s)
{
    float* p = s + (size_t)blockIdx.x * 1024;
    int tid = threadIdx.x;
    float4 v = ((float4*)p)[tid];
    float m = fmaxf(fmaxf(v.x, v.y), fmaxf(v.z, v.w));
    for (int off = 32; off; off >>= 1) m = fmaxf(m, __shfl_down(m, off));
    __shared__ float red[8];
    int lane = tid & 63, wid = tid >> 6;
    if (!lane) red[wid] = m;
    __syncthreads();
    if (!tid) red[4] = fmaxf(fmaxf(red[0], red[1]), fmaxf(red[2], red[3]));
    __syncthreads();
    m = red[4];
    v.x = expf(v.x - m); v.y = expf(v.y - m); v.z = expf(v.z - m); v.w = expf(v.w - m);
    float su = v.x + v.y + v.z + v.w;
    for (int off = 32; off; off >>= 1) su += __shfl_down(su, off);
    if (!lane) red[wid] = su;
    __syncthreads();
    if (!tid) red[5] = red[0] + red[1] + red[2] + red[3];
    __syncthreads();
    float inv = 1.0f / red[5];
    v.x *= inv; v.y *= inv; v.z *= inv; v.w *= inv;
    ((float4*)p)[tid] = v;
}

// ---------------------------------------------------------------- PV: ctx[b,q,h*64+d] = a @ V_h
__global__ __launch_bounds__(256) void attn_pv(const float* __restrict__ a,
                                               const float* __restrict__ v,
                                               float* __restrict__ ctx)
{
    __shared__ float As[16][65];
    __shared__ float Vs[16][65];
    int bh = blockIdx.y; int b = bh >> 3; int h = bh & 7;
    int q0 = blockIdx.x * 64;
    int tid = threadIdx.x;
    const float* arow = a + (size_t)bh * S_ * S_;
    const float* vb = v + (size_t)b * S_ * D_ + h * DK_;
    int tx = tid & 15, ty = tid >> 4;
    float acc[4][4] = {{0.f}};
    for (int k0 = 0; k0 < S_; k0 += 16) {
        int kk = tid & 15, qb_ = tid >> 4;
        #pragma unroll
        for (int i = 0; i < 4; ++i) {
            int qq = qb_ + 16 * i;
            As[kk][qq] = arow[(size_t)(q0 + qq) * S_ + k0 + kk];
        }
        int dd = tid & 63, kb2 = tid >> 6;
        #pragma unroll
        for (int i = 0; i < 4; ++i) {
            int k2 = kb2 + 4 * i;
            Vs[k2][dd] = vb[(size_t)(k0 + k2) * D_ + dd];
        }
        __syncthreads();
        #pragma unroll
        for (int k2 = 0; k2 < 16; ++k2) {
            float aa[4], bb[4];
            #pragma unroll
            for (int i = 0; i < 4; ++i) aa[i] = As[k2][ty + 16 * i];
            #pragma unroll
            for (int j = 0; j < 4; ++j) bb[j] = Vs[k2][tx + 16 * j];
            #pragma unroll
            for (int i = 0; i < 4; ++i)
                #pragma unroll
                for (int j = 0; j < 4; ++j)
                    acc[i][j] += aa[i] * bb[j];
        }
        __syncthreads();
    }
    #pragma unroll
    for (int i = 0; i < 4; ++i)
        #pragma unroll
        for (int j = 0; j < 4; ++j)
            ctx[(size_t)(b * S_ + q0 + ty + 16 * i) * D_ + h * DK_ + tx + 16 * j] = acc[i][j];
}

// ---------------------------------------------------------------- residual + LayerNorm (D=512)
__global__ __launch_bounds__(256) void ln_add(const float* __restrict__ x,
                                              const float* __restrict__ r,
                                              const float* __restrict__ g,
                                              const float* __restrict__ be,
                                              float* __restrict__ out)
{
    int row = blockIdx.x;
    const float* xr = x + (size_t)row * D_;
    const float* rr = r + (size_t)row * D_;
    int tid = threadIdx.x;
    float v0 = xr[tid] + rr[tid];
    float v1 = xr[tid + 256] + rr[tid + 256];
    float s = v0 + v1;
    for (int off = 32; off; off >>= 1) s += __shfl_down(s, off);
    __shared__ float red[8];
    int lane = tid & 63, wid = tid >> 6;
    if (!lane) red[wid] = s;
    __syncthreads();
    if (!tid) red[4] = (red[0] + red[1] + red[2] + red[3]) * (1.0f / 512.0f);
    __syncthreads();
    float m = red[4];
    float d0 = v0 - m, d1 = v1 - m;
    s = d0 * d0 + d1 * d1;
    for (int off = 32; off; off >>= 1) s += __shfl_down(s, off);
    if (!lane) red[wid] = s;
    __syncthreads();
    if (!tid) red[5] = rsqrtf((red[0] + red[1] + red[2] + red[3]) * (1.0f / 512.0f) + 1e-5f);
    __syncthreads();
    float rstd = red[5];
    float* orow = out + (size_t)row * D_;
    orow[tid] = d0 * rstd * g[tid] + be[tid];
    orow[tid + 256] = d1 * rstd * g[tid + 256] + be[tid + 256];
}

// ---------------------------------------------------------------- MoE gate
__global__ __launch_bounds__(256) void gate_logits(const float* __restrict__ xf,
                                                   const float* __restrict__ gw,
                                                   const float* __restrict__ gb,
                                                   float* __restrict__ lg)
{
    int id = blockIdx.x * 256 + threadIdx.x;
    if (id >= NTOK * E_) return;
    int e = id & 7, n = id >> 3;
    const float* x = xf + (size_t)n * D_;
    float s = gb[e];
    for (int d = 0; d < D_; ++d) s += x[d] * gw[d * E_ + e];
    lg[id] = s;
}

__global__ __launch_bounds__(256) void gate_top2(const float* __restrict__ lg,
                                                 float* __restrict__ topv,
                                                 int* __restrict__ topi)
{
    int n = blockIdx.x * 256 + threadIdx.x;
    if (n >= NTOK) return;
    float l[E_], p[E_];
    float m = -1e30f;
    #pragma unroll
    for (int e = 0; e < E_; ++e) { l[e] = lg[n * E_ + e]; m = fmaxf(m, l[e]); }
    float su = 0.f;
    #pragma unroll
    for (int e = 0; e < E_; ++e) { p[e] = expf(l[e] - m); su += p[e]; }
    float inv = 1.0f / su;
    int i1 = 0; float v1 = p[0];
    #pragma unroll
    for (int e = 1; e < E_; ++e) if (p[e] > v1) { v1 = p[e]; i1 = e; }
    int i2 = -1; float v2 = -1.f;
    #pragma unroll
    for (int e = 0; e < E_; ++e) if (e != i1 && p[e] > v2) { v2 = p[e]; i2 = e; }
    topv[n * 2] = v1 * inv; topv[n * 2 + 1] = v2 * inv;
    topi[n * 2] = i1;       topi[n * 2 + 1] = i2;
}

// deterministic routing tables (1 block, 64 threads; only 8 used for scans)
__global__ void build_routes(const int* __restrict__ topi,
                             int* __restrict__ route_tok, int* __restrict__ route_row,
                             int* __restrict__ counts, int* __restrict__ pad_base,
                             int* __restrict__ rb_expert)
{
    int t = threadIdx.x;
    if (t < E_) {
        int c = 0;
        for (int n = 0; n < NTOK; ++n)
            for (int s2 = 0; s2 < 2; ++s2)
                if (topi[n * 2 + s2] == t) c++;
        counts[t] = c;
    }
    __syncthreads();
    if (t == 0) {
        int pad = 0;
        for (int e = 0; e < E_; ++e) {
            pad_base[e] = pad;
            int nb = (counts[e] + 63) >> 6;
            for (int rb = 0; rb < nb; ++rb) rb_expert[(pad >> 6) + rb] = e;
            pad += nb << 6;
        }
        pad_base[E_] = pad;
    }
    __syncthreads();
    if (t < E_) {
        int idx = pad_base[t];
        for (int n = 0; n < NTOK; ++n)
            for (int s2 = 0; s2 < 2; ++s2)
                if (topi[n * 2 + s2] == t) {
                    route_tok[idx] = n;
                    route_row[n * 2 + s2] = idx;
                    idx++;
                }
    }
}

__global__ __launch_bounds__(256) void moe_combine(const float* __restrict__ eo,
                                                   const float* __restrict__ topv,
                                                   const int* __restrict__ route_row,
                                                   float* __restrict__ f)
{
    int n = blockIdx.x;
    int r0 = route_row[n * 2], r1 = route_row[n * 2 + 1];
    float w0 = topv[n * 2], w1 = topv[n * 2 + 1];
    const float* e0 = eo + (size_t)r0 * D_;
    const float* e1 = eo + (size_t)r1 * D_;
    float* fr = f + (size_t)n * D_;
    for (int j = threadIdx.x; j < D_; j += 256)
        fr[j] = w0 * e0[j] + w1 * e1[j];
}

// ================================================================ host orchestration
extern "C" void kernel_launch(void* const* d_in, const int* in_sizes, int n_in,
                              void* d_out, int out_size, void* d_ws, size_t ws_size,
                              hipStream_t stream)
{
    const int*   src        = (const int*)  d_in[0];
    const int*   tgt        = (const int*)  d_in[1];
    const float* enc_emb    = (const float*)d_in[2];
    const float* dec_emb    = (const float*)d_in[3];
    const float* enc_attn_w = (const float*)d_in[4];
    const float* enc_attn_b = (const float*)d_in[5];
    const float* enc_ln_g   = (const float*)d_in[6];
    const float* enc_ln_b   = (const float*)d_in[7];
    const float* enc_gate_w = (const float*)d_in[8];
    const float* enc_gate_b = (const float*)d_in[9];
    const float* enc_w1     = (const float*)d_in[10];
    const float* enc_b1     = (const float*)d_in[11];
    const float* enc_w2     = (const float*)d_in[12];
    const float* enc_b2     = (const float*)d_in[13];
    const float* dec_sa_w   = (const float*)d_in[14];
    const float* dec_sa_b   = (const float*)d_in[15];
    const float* dec_ca_w   = (const float*)d_in[16];
    const float* dec_ca_b   = (const float*)d_in[17];
    const float* dec_ln_g   = (const float*)d_in[18];
    const float* dec_ln_b   = (const float*)d_in[19];
    const float* dec_gate_w = (const float*)d_in[20];
    const float* dec_gate_b = (const float*)d_in[21];
    const float* dec_w1     = (const float*)d_in[22];
    const float* dec_b1     = (const float*)d_in[23];
    const float* dec_w2     = (const float*)d_in[24];
    const float* dec_b2     = (const float*)d_in[25];
    const float* out_w      = (const float*)d_in[26];
    const float* out_b      = (const float*)d_in[27];
    float* out = (float*)d_out;

    // ---- ws scratch (small, persistent activations + routing) ~17 MB
    char* wp = (char*)d_ws;
    auto alloc = [&](size_t bytes) { char* p = wp; wp += (bytes + 255) & ~(size_t)255; return p; };
    float* xA   = (float*)alloc((size_t)NTOK * D_ * 4);
    float* xB   = (float*)alloc((size_t)NTOK * D_ * 4);
    float* yA   = (float*)alloc((size_t)NTOK * D_ * 4);
    float* yB   = (float*)alloc((size_t)NTOK * D_ * 4);
    float* lg   = (float*)alloc((size_t)NTOK * E_ * 4);
    float* topv = (float*)alloc((size_t)NTOK * 2 * 4);
    int*   topi = (int*)  alloc((size_t)NTOK * 2 * 4);
    int*   route_tok = (int*)alloc((size_t)MAXPAD * 4);
    int*   route_row = (int*)alloc((size_t)NTOK * 2 * 4);
    int*   counts    = (int*)alloc(64);
    int*   pad_base  = (int*)alloc(64);
    int*   rb_expert = (int*)alloc((size_t)96 * 4);

    // ---- big transient scratch lives in d_out (262 MB; logits written last)
    char* ob = (char*)d_out;
    float* scores = (float*)(ob);                  // 16*1024*1024*4 = 64 MiB
    float* hbuf   = (float*)(ob + 67108864ll);     // 4608*2048*4   = 36 MiB
    float* eobuf  = (float*)(ob + 104857600ll);    // 4608*512*4    = 9 MiB
    float* qb     = (float*)(ob + 114294784ll);    // 4 MiB each:
    float* kb     = (float*)(ob + 118489088ll);
    float* vb     = (float*)(ob + 122683392ll);
    float* ctx    = (float*)(ob + 126877696ll);
    float* aout   = (float*)(ob + 131072000ll);

    auto run_gemm = [&](const float* A, const float* Wm, const float* bias, float* C,
                        int M, int Kd, int N) {
        dim3 g(N / 64, M / 64);
        gemm_k<0, false><<<g, 256, 0, stream>>>(A, Wm, bias, C, M, Kd, N, Kd,
                                                nullptr, nullptr, nullptr, nullptr);
    };

    auto run_mha = [&](const float* xq, const float* xkv, const float* wt, const float* bt,
                       const int* ktoks, int causal) {
        run_gemm(xq,  wt,              bt,          qb, NTOK, D_, D_);
        run_gemm(xkv, wt + D_ * D_,    bt + D_,     kb, NTOK, D_, D_);
        run_gemm(xkv, wt + 2 * D_ * D_, bt + 2 * D_, vb, NTOK, D_, D_);
        attn_scores<<<dim3(16, 16, 16), 256, 0, stream>>>(qb, kb, ktoks, scores, causal);
        softmax_rows<<<16 * 1024, 256, 0, stream>>>(scores);
        attn_pv<<<dim3(16, 16), 256, 0, stream>>>(scores, vb, ctx);
        run_gemm(ctx, wt + 3 * D_ * D_, bt + 3 * D_, aout, NTOK, D_, D_);
    };

    auto run_moe = [&](const float* x, const float* gwp, const float* gbp,
                       const float* w1p, const float* b1p,
                       const float* w2p, const float* b2p) {
        gate_logits<<<NTOK * E_ / 256, 256, 0, stream>>>(x, gwp, gbp, lg);
        gate_top2<<<NTOK / 256, 256, 0, stream>>>(lg, topv, topi);
        build_routes<<<1, 64, 0, stream>>>(topi, route_tok, route_row, counts, pad_base, rb_expert);
        gemm_k<1, true><<<dim3(F_ / 64, MAXRB), 256, 0, stream>>>(
            x, w1p, b1p, hbuf, 0, D_, F_, D_, route_tok, rb_expert, pad_base, counts);
        gemm_k<2, false><<<dim3(D_ / 64, MAXRB), 256, 0, stream>>>(
            hbuf, w2p, b2p, eobuf, 0, F_, D_, F_, route_tok, rb_expert, pad_base, counts);
        moe_combine<<<NTOK, 256, 0, stream>>>(eobuf, topv, route_row, aout);
    };

    // ---------------- encoder ----------------
    embed_pe<<<B_ * S_, 256, 0, stream>>>(src, enc_emb, xA, S_);
    float* cur = xA; float* alt = xB;
    for (int l = 0; l < L_; ++l) {
        run_mha(cur, cur, enc_attn_w + (size_t)l * 4 * D_ * D_, enc_attn_b + (size_t)l * 4 * D_, src, 0);
        ln_add<<<NTOK, 256, 0, stream>>>(cur, aout,
            enc_ln_g + (size_t)(l * 2 + 0) * D_, enc_ln_b + (size_t)(l * 2 + 0) * D_, alt);
        { float* t = cur; cur = alt; alt = t; }
        run_moe(cur, enc_gate_w + (size_t)l * D_ * E_, enc_gate_b + (size_t)l * E_,
                enc_w1 + (size_t)l * E_ * D_ * F_, enc_b1 + (size_t)l * E_ * F_,
                enc_w2 + (size_t)l * E_ * F_ * D_, enc_b2 + (size_t)l * E_ * D_);
        ln_add<<<NTOK, 256, 0, stream>>>(cur, aout,
            enc_ln_g + (size_t)(l * 2 + 1) * D_, enc_ln_b + (size_t)(l * 2 + 1) * D_, alt);
        { float* t = cur; cur = alt; alt = t; }
    }
    float* enc_out_p = cur;

    // ---------------- decoder ----------------
    embed_pe<<<B_ * T_, 256, 0, stream>>>(tgt, dec_emb, yA, T_);
    float* dc = yA; float* da = yB;
    for (int l = 0; l < L_; ++l) {
        run_mha(dc, dc, dec_sa_w + (size_t)l * 4 * D_ * D_, dec_sa_b + (size_t)l * 4 * D_, tgt, 1);
        ln_add<<<NTOK, 256, 0, stream>>>(dc, aout,
            dec_ln_g + (size_t)(l * 3 + 0) * D_, dec_ln_b + (size_t)(l * 3 + 0) * D_, da);
        { float* t = dc; dc = da; da = t; }
        run_mha(dc, enc_out_p, dec_ca_w + (size_t)l * 4 * D_ * D_, dec_ca_b + (size_t)l * 4 * D_, src, 0);
        ln_add<<<NTOK, 256, 0, stream>>>(dc, aout,
            dec_ln_g + (size_t)(l * 3 + 1) * D_, dec_ln_b + (size_t)(l * 3 + 1) * D_, da);
        { float* t = dc; dc = da; da = t; }
        run_moe(dc, dec_gate_w + (size_t)l * D_ * E_, dec_gate_b + (size_t)l * E_,
                dec_w1 + (size_t)l * E_ * D_ * F_, dec_b1 + (size_t)l * E_ * F_,
                dec_w2 + (size_t)l * E_ * F_ * D_, dec_b2 + (size_t)l * E_ * D_);
        ln_add<<<NTOK, 256, 0, stream>>>(dc, aout,
            dec_ln_g + (size_t)(l * 3 + 2) * D_, dec_ln_b + (size_t)(l * 3 + 2) * D_, da);
        { float* t = dc; dc = da; da = t; }
    }

    // ---------------- final projection (overwrites all of d_out) ----------------
    run_gemm(dc, out_w, out_b, out, NTOK, D_, V_);
}

// Round 2
// 3440.559 us; speedup vs baseline: 1.7164x; 1.7164x over previous
//
#include <hip/hip_runtime.h>
#include <hip/hip_bf16.h>

#define L_ 2
#define D_ 512
#define H_ 8
#define DK_ 64
#define F_ 2048
#define E_ 8
#define V_ 32000
#define B_ 2
#define S_ 1024
#define T_ 1024
#define NTOK (B_*S_)
#define MAXPAD 5120            // per-expert 128-padded total upper bound
#define MAXRB  (MAXPAD/128)    // 40
#define QLD 1536               // fused qkv row stride

typedef unsigned short u16;
typedef _Float16 f16x8 __attribute__((ext_vector_type(8)));
typedef float f32x4 __attribute__((ext_vector_type(4)));

__device__ __forceinline__ void gload16(const void* g, const void* l) {
    __builtin_amdgcn_global_load_lds(
        (const __attribute__((address_space(1))) void*)g,
        (__attribute__((address_space(3))) void*)l, 16, 0, 0);
}

__device__ __forceinline__ void split_f16(float v, _Float16& h, _Float16& l) {
    h = (_Float16)v;
    l = (_Float16)(v - (float)h);
}

// ---------------------------------------------------------------- embedding + PE (f32 + hi/lo f16)
__global__ __launch_bounds__(256) void embed_pe(const int* __restrict__ toks,
                                                const float* __restrict__ emb,
                                                float* __restrict__ o,
                                                _Float16* __restrict__ oh,
                                                _Float16* __restrict__ ol, int Slen)
{
    int n = blockIdx.x;
    int spos = n % Slen;
    int tok = toks[n];
    const float* erow = emb + (size_t)tok * D_;
    size_t rb = (size_t)n * D_;
    for (int j = threadIdx.x; j < D_; j += 256) {
        int i = j >> 1;
        float arg = (float)spos * expf(-(float)i * 0.035977892f);
        float pe = (j & 1) ? cosf(arg) : sinf(arg);
        float v = erow[j] + pe;
        o[rb + j] = v;
        _Float16 h, l; split_f16(v, h, l);
        oh[rb + j] = h; ol[rb + j] = l;
    }
}

// ---------------------------------------------------------------- weight transpose f32[K][N] -> f16 hi/lo [N][K]
template<bool WLO>
__global__ __launch_bounds__(256) void transpose_w(const float* __restrict__ in,
                                                   _Float16* __restrict__ oh,
                                                   _Float16* __restrict__ ol, int R, int C)
{
    __shared__ float t[64][65];
    size_t sb = (size_t)blockIdx.z * R * C;
    in += sb; oh += sb; if (WLO) ol += sb;
    int c0 = blockIdx.x * 64, r0 = blockIdx.y * 64;
    int tid = threadIdx.x;
    int cc = tid & 63, r4 = tid >> 6;
    #pragma unroll
    for (int p = 0; p < 16; ++p) {
        int r = p * 4 + r4;
        t[r][cc] = in[(size_t)(r0 + r) * C + c0 + cc];
    }
    __syncthreads();
    int rr = tid & 63, c4 = tid >> 6;
    #pragma unroll
    for (int p = 0; p < 16; ++p) {
        int c = p * 4 + c4;
        float v = t[rr][c];
        _Float16 h = (_Float16)v;
        oh[(size_t)(c0 + c) * R + r0 + rr] = h;
        if (WLO) ol[(size_t)(c0 + c) * R + r0 + rr] = (_Float16)(v - (float)h);
    }
}

// ---------------------------------------------------------------- MFMA GEMM
// C[M,N] = A[M,K] @ Wt[N,K]^T + bias ; split-f16 3-pass (PASSES=3) or single hi (PASSES=1)
// MODE 0 plain, 1 routed gather, 2 routed direct
template<int MODE, bool RELU, bool OUTSPLIT, int PASSES>
__global__ __launch_bounds__(256, 2) void gemm_mfma(
    const _Float16* __restrict__ Ah, const _Float16* __restrict__ Al,
    const _Float16* __restrict__ Wh, const _Float16* __restrict__ Wl,
    const float* __restrict__ biasbase,
    float* __restrict__ Cf, _Float16* __restrict__ Ch, _Float16* __restrict__ Cl,
    int M, int Kd, int N, int ldc,
    const int* __restrict__ route_tok, const int* __restrict__ rb_expert,
    const int* __restrict__ pad_base, const int* __restrict__ counts)
{
    int row0 = blockIdx.y * 128;
    const _Float16* Wmh = Wh;
    const _Float16* Wml = Wl;
    const float* bias = biasbase;
    int vend = M;
    if (MODE != 0) {
        int total = pad_base[E_];
        if (row0 >= total) return;
        int e = rb_expert[row0 >> 7];
        vend = pad_base[e] + counts[e];
        Wmh = Wh + (size_t)e * Kd * N;
        if (PASSES == 3) Wml = Wl + (size_t)e * Kd * N;
        bias = biasbase + (size_t)e * N;
    }
    int col0 = blockIdx.x * 128;
    int tid = threadIdx.x;
    int lane = tid & 63, w = tid >> 6;
    int wm = w >> 1, wn = w & 1;

    __shared__ _Float16 lds[(PASSES == 3 ? 4 : 2) * 8192];
    _Float16* lAh = lds;
    _Float16* lBh = lds + 8192;
    _Float16* lAl = (PASSES == 3) ? lds + 16384 : nullptr;
    _Float16* lBl = (PASSES == 3) ? lds + 24576 : nullptr;

    // staging: wave w covers rows [w*32, w*32+32) of each 128x64 tile in 4 issues of 8 rows
    int srow8 = lane >> 3;          // row within 8-row issue
    int q8 = lane & 7;              // linear 16B slot
    size_t aoff[4], boff[4];
    #pragma unroll
    for (int j = 0; j < 4; ++j) {
        int m = w * 32 + j * 8 + srow8;
        int gr = row0 + m;
        int ar = (MODE == 1) ? route_tok[gr] : gr;
        int sslot = (q8 ^ (m & 7)) << 3;     // inverse-swizzled source slot (elements)
        aoff[j] = (size_t)ar * Kd + sslot;
        boff[j] = (size_t)(col0 + m) * Kd + sslot;
    }

    f32x4 zero4 = {0.f, 0.f, 0.f, 0.f};
    f32x4 acc[4][4];
    #pragma unroll
    for (int i = 0; i < 4; ++i)
        #pragma unroll
        for (int j = 0; j < 4; ++j) acc[i][j] = zero4;

    int lm = lane & 15, kg = lane >> 4;

    for (int k0 = 0; k0 < Kd; k0 += 64) {
        #pragma unroll
        for (int j = 0; j < 4; ++j) {
            int lb = (w * 32 + j * 8) * 64;   // wave-uniform LDS element base
            gload16(Ah + aoff[j] + k0, lAh + lb);
            gload16(Wmh + boff[j] + k0, lBh + lb);
            if (PASSES == 3) {
                gload16(Al + aoff[j] + k0, lAl + lb);
                gload16(Wml + boff[j] + k0, lBl + lb);
            }
        }
        __syncthreads();
        #pragma unroll
        for (int ks = 0; ks < 2; ++ks) {
            f16x8 ah[4], bh[4];
            #pragma unroll
            for (int i = 0; i < 4; ++i) {
                int m = wm * 64 + i * 16 + lm;
                ah[i] = *(const f16x8*)&lAh[m * 64 + ((((ks << 2) + kg) ^ (m & 7)) << 3)];
                int n = wn * 64 + i * 16 + lm;
                bh[i] = *(const f16x8*)&lBh[n * 64 + ((((ks << 2) + kg) ^ (n & 7)) << 3)];
            }
            #pragma unroll
            for (int i = 0; i < 4; ++i)
                #pragma unroll
                for (int jn = 0; jn < 4; ++jn)
                    acc[i][jn] = __builtin_amdgcn_mfma_f32_16x16x32_f16(ah[i], bh[jn], acc[i][jn], 0, 0, 0);
            if (PASSES == 3) {
                f16x8 bl[4];
                #pragma unroll
                for (int i = 0; i < 4; ++i) {
                    int n = wn * 64 + i * 16 + lm;
                    bl[i] = *(const f16x8*)&lBl[n * 64 + ((((ks << 2) + kg) ^ (n & 7)) << 3)];
                }
                #pragma unroll
                for (int i = 0; i < 4; ++i)
                    #pragma unroll
                    for (int jn = 0; jn < 4; ++jn)
                        acc[i][jn] = __builtin_amdgcn_mfma_f32_16x16x32_f16(ah[i], bl[jn], acc[i][jn], 0, 0, 0);
                f16x8 al[4];
                #pragma unroll
                for (int i = 0; i < 4; ++i) {
                    int m = wm * 64 + i * 16 + lm;
                    al[i] = *(const f16x8*)&lAl[m * 64 + ((((ks << 2) + kg) ^ (m & 7)) << 3)];
                }
                #pragma unroll
                for (int i = 0; i < 4; ++i)
                    #pragma unroll
                    for (int jn = 0; jn < 4; ++jn)
                        acc[i][jn] = __builtin_amdgcn_mfma_f32_16x16x32_f16(al[i], bh[jn], acc[i][jn], 0, 0, 0);
            }
        }
        __syncthreads();
    }

    // epilogue: C/D layout col=lane&15, row=(lane>>4)*4+reg
    float bv[4];
    #pragma unroll
    for (int jn = 0; jn < 4; ++jn) bv[jn] = bias[col0 + wn * 64 + jn * 16 + lm];
    int rowb = row0 + wm * 64 + (lane >> 4) * 4;
    #pragma unroll
    for (int i = 0; i < 4; ++i) {
        #pragma unroll
        for (int r = 0; r < 4; ++r) {
            int row = rowb + i * 16 + r;
            if (MODE != 0 && row >= vend) continue;
            #pragma unroll
            for (int jn = 0; jn < 4; ++jn) {
                float v = acc[i][jn][r] + bv[jn];
                if (RELU) v = fmaxf(v, 0.f);
                int c = col0 + wn * 64 + jn * 16 + lm;
                if (OUTSPLIT) {
                    _Float16 h, l; split_f16(v, h, l);
                    Ch[(size_t)row * ldc + c] = h;
                    Cl[(size_t)row * ldc + c] = l;
                } else {
                    Cf[(size_t)row * ldc + c] = v;
                }
            }
        }
    }
}

// ---------------------------------------------------------------- attention scores (f32, exact)
__global__ __launch_bounds__(256) void attn_scores(const float* __restrict__ qkv,
                                                   const int* __restrict__ toks,
                                                   float* __restrict__ scores, int causal)
{
    __shared__ float Qs[64][65];
    __shared__ float Ks[64][65];
    int bh = blockIdx.z; int b = bh >> 3; int h = bh & 7;
    int q0 = blockIdx.y * 64, k0 = blockIdx.x * 64;
    int tid = threadIdx.x;
    const float* qb = qkv + (size_t)b * S_ * QLD + h * DK_;
    const float* kb = qkv + (size_t)b * S_ * QLD + 512 + h * DK_;
    #pragma unroll
    for (int i = 0; i < 16; ++i) {
        int idx = tid + 256 * i;
        int r = idx >> 6, c = idx & 63;
        Qs[r][c] = qb[(size_t)(q0 + r) * QLD + c];
        Ks[r][c] = kb[(size_t)(k0 + r) * QLD + c];
    }
    __syncthreads();
    int tx = tid & 15, ty = tid >> 4;
    float acc[4][4] = {{0.f}};
    for (int d = 0; d < 64; ++d) {
        float a[4], bb[4];
        #pragma unroll
        for (int i = 0; i < 4; ++i) a[i] = Qs[ty + 16 * i][d];
        #pragma unroll
        for (int j = 0; j < 4; ++j) bb[j] = Ks[tx + 16 * j][d];
        #pragma unroll
        for (int i = 0; i < 4; ++i)
            #pragma unroll
            for (int j = 0; j < 4; ++j)
                acc[i][j] += a[i] * bb[j];
    }
    float* srow = scores + (size_t)bh * S_ * S_;
    #pragma unroll
    for (int i = 0; i < 4; ++i) {
        int qi = q0 + ty + 16 * i;
        #pragma unroll
        for (int j = 0; j < 4; ++j) {
            int ki = k0 + tx + 16 * j;
            bool keep = (toks[b * S_ + ki] != 0) && (!causal || ki <= qi);
            srow[(size_t)qi * S_ + ki] = keep ? acc[i][j] * 0.125f : -1e9f;
        }
    }
}

// ---------------------------------------------------------------- row softmax
__global__ __launch_bounds__(256) void softmax_rows(float* __restrict__ s)
{
    float* p = s + (size_t)blockIdx.x * 1024;
    int tid = threadIdx.x;
    float4 v = ((float4*)p)[tid];
    float m = fmaxf(fmaxf(v.x, v.y), fmaxf(v.z, v.w));
    for (int off = 32; off; off >>= 1) m = fmaxf(m, __shfl_down(m, off));
    __shared__ float red[8];
    int lane = tid & 63, wid = tid >> 6;
    if (!lane) red[wid] = m;
    __syncthreads();
    if (!tid) red[4] = fmaxf(fmaxf(red[0], red[1]), fmaxf(red[2], red[3]));
    __syncthreads();
    m = red[4];
    v.x = expf(v.x - m); v.y = expf(v.y - m); v.z = expf(v.z - m); v.w = expf(v.w - m);
    float su = v.x + v.y + v.z + v.w;
    for (int off = 32; off; off >>= 1) su += __shfl_down(su, off);
    if (!lane) red[wid] = su;
    __syncthreads();
    if (!tid) red[5] = red[0] + red[1] + red[2] + red[3];
    __syncthreads();
    float inv = 1.0f / red[5];
    v.x *= inv; v.y *= inv; v.z *= inv; v.w *= inv;
    ((float4*)p)[tid] = v;
}

// ---------------------------------------------------------------- PV (f32) -> ctx hi/lo f16
__global__ __launch_bounds__(256) void attn_pv(const float* __restrict__ a,
                                               const float* __restrict__ qkv,
                                               _Float16* __restrict__ ch,
                                               _Float16* __restrict__ cl)
{
    __shared__ float As[16][65];
    __shared__ float Vs[16][65];
    int bh = blockIdx.y; int b = bh >> 3; int h = bh & 7;
    int q0 = blockIdx.x * 64;
    int tid = threadIdx.x;
    const float* arow = a + (size_t)bh * S_ * S_;
    const float* vb = qkv + (size_t)b * S_ * QLD + 1024 + h * DK_;
    int tx = tid & 15, ty = tid >> 4;
    float acc[4][4] = {{0.f}};
    for (int k0 = 0; k0 < S_; k0 += 16) {
        int kk = tid & 15, qb_ = tid >> 4;
        #pragma unroll
        for (int i = 0; i < 4; ++i) {
            int qq = qb_ + 16 * i;
            As[kk][qq] = arow[(size_t)(q0 + qq) * S_ + k0 + kk];
        }
        int dd = tid & 63, kb2 = tid >> 6;
        #pragma unroll
        for (int i = 0; i < 4; ++i) {
            int k2 = kb2 + 4 * i;
            Vs[k2][dd] = vb[(size_t)(k0 + k2) * QLD + dd];
        }
        __syncthreads();
        #pragma unroll
        for (int k2 = 0; k2 < 16; ++k2) {
            float aa[4], bb[4];
            #pragma unroll
            for (int i = 0; i < 4; ++i) aa[i] = As[k2][ty + 16 * i];
            #pragma unroll
            for (int j = 0; j < 4; ++j) bb[j] = Vs[k2][tx + 16 * j];
            #pragma unroll
            for (int i = 0; i < 4; ++i)
                #pragma unroll
                for (int j = 0; j < 4; ++j)
                    acc[i][j] += aa[i] * bb[j];
        }
        __syncthreads();
    }
    #pragma unroll
    for (int i = 0; i < 4; ++i)
        #pragma unroll
        for (int j = 0; j < 4; ++j) {
            size_t idx = (size_t)(b * S_ + q0 + ty + 16 * i) * D_ + h * DK_ + tx + 16 * j;
            _Float16 h2, l2; split_f16(acc[i][j], h2, l2);
            ch[idx] = h2; cl[idx] = l2;
        }
}

// ---------------------------------------------------------------- residual + LayerNorm (f32 + hi/lo)
__global__ __launch_bounds__(256) void ln_add(const float* __restrict__ x,
                                              const float* __restrict__ r,
                                              const float* __restrict__ g,
                                              const float* __restrict__ be,
                                              float* __restrict__ o,
                                              _Float16* __restrict__ oh,
                                              _Float16* __restrict__ ol)
{
    int row = blockIdx.x;
    const float* xr = x + (size_t)row * D_;
    const float* rr = r + (size_t)row * D_;
    int tid = threadIdx.x;
    float v0 = xr[tid] + rr[tid];
    float v1 = xr[tid + 256] + rr[tid + 256];
    float s = v0 + v1;
    for (int off = 32; off; off >>= 1) s += __shfl_down(s, off);
    __shared__ float red[8];
    int lane = tid & 63, wid = tid >> 6;
    if (!lane) red[wid] = s;
    __syncthreads();
    if (!tid) red[4] = (red[0] + red[1] + red[2] + red[3]) * (1.0f / 512.0f);
    __syncthreads();
    float m = red[4];
    float d0 = v0 - m, d1 = v1 - m;
    s = d0 * d0 + d1 * d1;
    for (int off = 32; off; off >>= 1) s += __shfl_down(s, off);
    if (!lane) red[wid] = s;
    __syncthreads();
    if (!tid) red[5] = rsqrtf((red[0] + red[1] + red[2] + red[3]) * (1.0f / 512.0f) + 1e-5f);
    __syncthreads();
    float rstd = red[5];
    size_t rb = (size_t)row * D_;
    float y0 = d0 * rstd * g[tid] + be[tid];
    float y1 = d1 * rstd * g[tid + 256] + be[tid + 256];
    o[rb + tid] = y0; o[rb + tid + 256] = y1;
    _Float16 h, l;
    split_f16(y0, h, l); oh[rb + tid] = h; ol[rb + tid] = l;
    split_f16(y1, h, l); oh[rb + tid + 256] = h; ol[rb + tid + 256] = l;
}

// ---------------------------------------------------------------- MoE gate
__global__ __launch_bounds__(256) void gate_logits(const float* __restrict__ xf,
                                                   const float* __restrict__ gw,
                                                   const float* __restrict__ gb,
                                                   float* __restrict__ lg)
{
    int id = blockIdx.x * 256 + threadIdx.x;
    if (id >= NTOK * E_) return;
    int e = id & 7, n = id >> 3;
    const float* x = xf + (size_t)n * D_;
    float s = gb[e];
    for (int d = 0; d < D_; ++d) s += x[d] * gw[d * E_ + e];
    lg[id] = s;
}

__global__ __launch_bounds__(256) void gate_top2(const float* __restrict__ lg,
                                                 float* __restrict__ topv,
                                                 int* __restrict__ topi)
{
    int n = blockIdx.x * 256 + threadIdx.x;
    if (n >= NTOK) return;
    float l[E_], p[E_];
    float m = -1e30f;
    #pragma unroll
    for (int e = 0; e < E_; ++e) { l[e] = lg[n * E_ + e]; m = fmaxf(m, l[e]); }
    float su = 0.f;
    #pragma unroll
    for (int e = 0; e < E_; ++e) { p[e] = expf(l[e] - m); su += p[e]; }
    float inv = 1.0f / su;
    int i1 = 0; float v1 = p[0];
    #pragma unroll
    for (int e = 1; e < E_; ++e) if (p[e] > v1) { v1 = p[e]; i1 = e; }
    int i2 = -1; float v2 = -1.f;
    #pragma unroll
    for (int e = 0; e < E_; ++e) if (e != i1 && p[e] > v2) { v2 = p[e]; i2 = e; }
    topv[n * 2] = v1 * inv; topv[n * 2 + 1] = v2 * inv;
    topi[n * 2] = i1;       topi[n * 2 + 1] = i2;
}

// deterministic routing tables, 128-row padded per expert
__global__ void build_routes(const int* __restrict__ topi,
                             int* __restrict__ route_tok, int* __restrict__ route_row,
                             int* __restrict__ counts, int* __restrict__ pad_base,
                             int* __restrict__ rb_expert)
{
    int t = threadIdx.x;
    if (t < E_) {
        int c = 0;
        for (int n = 0; n < NTOK; ++n)
            for (int s2 = 0; s2 < 2; ++s2)
                if (topi[n * 2 + s2] == t) c++;
        counts[t] = c;
    }
    __syncthreads();
    if (t == 0) {
        int pad = 0;
        for (int e = 0; e < E_; ++e) {
            pad_base[e] = pad;
            int nb = (counts[e] + 127) >> 7;
            for (int rb = 0; rb < nb; ++rb) rb_expert[(pad >> 7) + rb] = e;
            pad += nb << 7;
        }
        pad_base[E_] = pad;
    }
    __syncthreads();
    if (t < E_) {
        int idx = pad_base[t];
        for (int n = 0; n < NTOK; ++n)
            for (int s2 = 0; s2 < 2; ++s2)
                if (topi[n * 2 + s2] == t) {
                    route_tok[idx] = n;
                    route_row[n * 2 + s2] = idx;
                    idx++;
                }
        int end = pad_base[t] + ((counts[t] + 127) & ~127);
        for (int g = idx; g < end; ++g) route_tok[g] = 0;
    }
}

__global__ __launch_bounds__(256) void moe_combine(const float* __restrict__ eo,
                                                   const float* __restrict__ topv,
                                                   const int* __restrict__ route_row,
                                                   float* __restrict__ f)
{
    int n = blockIdx.x;
    int r0 = route_row[n * 2], r1 = route_row[n * 2 + 1];
    float w0 = topv[n * 2], w1 = topv[n * 2 + 1];
    const float* e0 = eo + (size_t)r0 * D_;
    const float* e1 = eo + (size_t)r1 * D_;
    float* fr = f + (size_t)n * D_;
    for (int j = threadIdx.x; j < D_; j += 256)
        fr[j] = w0 * e0[j] + w1 * e1[j];
}

// ================================================================ host orchestration
extern "C" void kernel_launch(void* const* d_in, const int* in_sizes, int n_in,
                              void* d_out, int out_size, void* d_ws, size_t ws_size,
                              hipStream_t stream)
{
    const int*   src        = (const int*)  d_in[0];
    const int*   tgt        = (const int*)  d_in[1];
    const float* enc_emb    = (const float*)d_in[2];
    const float* dec_emb    = (const float*)d_in[3];
    const float* enc_attn_w = (const float*)d_in[4];
    const float* enc_attn_b = (const float*)d_in[5];
    const float* enc_ln_g   = (const float*)d_in[6];
    const float* enc_ln_b   = (const float*)d_in[7];
    const float* enc_gate_w = (const float*)d_in[8];
    const float* enc_gate_b = (const float*)d_in[9];
    const float* enc_w1     = (const float*)d_in[10];
    const float* enc_b1     = (const float*)d_in[11];
    const float* enc_w2     = (const float*)d_in[12];
    const float* enc_b2     = (const float*)d_in[13];
    const float* dec_sa_w   = (const float*)d_in[14];
    const float* dec_sa_b   = (const float*)d_in[15];
    const float* dec_ca_w   = (const float*)d_in[16];
    const float* dec_ca_b   = (const float*)d_in[17];
    const float* dec_ln_g   = (const float*)d_in[18];
    const float* dec_ln_b   = (const float*)d_in[19];
    const float* dec_gate_w = (const float*)d_in[20];
    const float* dec_gate_b = (const float*)d_in[21];
    const float* dec_w1     = (const float*)d_in[22];
    const float* dec_b1     = (const float*)d_in[23];
    const float* dec_w2     = (const float*)d_in[24];
    const float* dec_b2     = (const float*)d_in[25];
    const float* out_w      = (const float*)d_in[26];
    const float* out_b      = (const float*)d_in[27];
    float* out = (float*)d_out;

    // ---- d_out scratch layout (dead until final GEMM overwrites everything)
    char* ob = (char*)d_out;
    size_t oc = 0;
    auto dalloc = [&](size_t bytes) { char* p = ob + oc; oc += (bytes + 255) & ~(size_t)255; return p; };
    // union region: scores (67.1MB) == moe w1t/w2t hi+lo (4 x 16.77MB) -- never live together
    char* unionp = dalloc(67108864);
    float*    scores = (float*)unionp;
    _Float16* w1t_h  = (_Float16*)unionp;
    _Float16* w1t_l  = w1t_h + (size_t)E_ * F_ * D_;
    _Float16* w2t_h  = w1t_l + (size_t)E_ * F_ * D_;
    _Float16* w2t_l  = w2t_h + (size_t)E_ * F_ * D_;
    float* qkvb  = (float*)dalloc((size_t)NTOK * QLD * 4);
    float* aout  = (float*)dalloc((size_t)NTOK * D_ * 4);
    _Float16* ctx_h = (_Float16*)dalloc((size_t)NTOK * D_ * 2);
    _Float16* ctx_l = (_Float16*)dalloc((size_t)NTOK * D_ * 2);
    _Float16* hbuf_h = (_Float16*)dalloc((size_t)MAXPAD * F_ * 2);
    _Float16* hbuf_l = (_Float16*)dalloc((size_t)MAXPAD * F_ * 2);
    float* eobuf = (float*)dalloc((size_t)MAXPAD * D_ * 4);
    _Float16* encA_h = (_Float16*)dalloc((size_t)L_ * 4 * D_ * D_ * 2);
    _Float16* encA_l = (_Float16*)dalloc((size_t)L_ * 4 * D_ * D_ * 2);
    _Float16* saA_h  = (_Float16*)dalloc((size_t)L_ * 4 * D_ * D_ * 2);
    _Float16* saA_l  = (_Float16*)dalloc((size_t)L_ * 4 * D_ * D_ * 2);
    _Float16* caA_h  = (_Float16*)dalloc((size_t)L_ * 4 * D_ * D_ * 2);
    _Float16* caA_l  = (_Float16*)dalloc((size_t)L_ * 4 * D_ * D_ * 2);
    float* xA = (float*)dalloc((size_t)NTOK * D_ * 4);
    float* xB = (float*)dalloc((size_t)NTOK * D_ * 4);
    float* yA = (float*)dalloc((size_t)NTOK * D_ * 4);
    float* yB = (float*)dalloc((size_t)NTOK * D_ * 4);
    _Float16* xA_h = (_Float16*)dalloc((size_t)NTOK * D_ * 2);
    _Float16* xA_l = (_Float16*)dalloc((size_t)NTOK * D_ * 2);
    _Float16* xB_h = (_Float16*)dalloc((size_t)NTOK * D_ * 2);
    _Float16* xB_l = (_Float16*)dalloc((size_t)NTOK * D_ * 2);
    _Float16* yA_h = (_Float16*)dalloc((size_t)NTOK * D_ * 2);
    _Float16* yA_l = (_Float16*)dalloc((size_t)NTOK * D_ * 2);
    _Float16* yB_h = (_Float16*)dalloc((size_t)NTOK * D_ * 2);
    _Float16* yB_l = (_Float16*)dalloc((size_t)NTOK * D_ * 2);

    // ---- ws (survives the final GEMM): transposed out_w hi, final activation hi, routing
    char* wp = (char*)d_ws;
    size_t wc = 0;
    auto walloc = [&](size_t bytes) { char* p = wp + wc; wc += (bytes + 255) & ~(size_t)255; return p; };
    _Float16* outwT_h = (_Float16*)walloc((size_t)V_ * D_ * 2);
    _Float16* final_h = (_Float16*)walloc((size_t)NTOK * D_ * 2);
    float* lg   = (float*)walloc((size_t)NTOK * E_ * 4);
    float* topv = (float*)walloc((size_t)NTOK * 2 * 4);
    int*   topi = (int*)  walloc((size_t)NTOK * 2 * 4);
    int*   route_tok = (int*)walloc((size_t)MAXPAD * 4);
    int*   route_row = (int*)walloc((size_t)NTOK * 2 * 4);
    int*   counts    = (int*)walloc(64);
    int*   pad_base  = (int*)walloc(64);
    int*   rb_expert = (int*)walloc((size_t)64 * 4);

    // ---- weight transposes (once per launch)
    transpose_w<true><<<dim3(8, 8, 8), 256, 0, stream>>>(enc_attn_w, encA_h, encA_l, D_, D_);
    transpose_w<true><<<dim3(8, 8, 8), 256, 0, stream>>>(dec_sa_w, saA_h, saA_l, D_, D_);
    transpose_w<true><<<dim3(8, 8, 8), 256, 0, stream>>>(dec_ca_w, caA_h, caA_l, D_, D_);
    transpose_w<false><<<dim3(500, 8, 1), 256, 0, stream>>>(out_w, outwT_h, nullptr, D_, V_);

    auto g3 = [&](const _Float16* Ahp, const _Float16* Alp,
                  const _Float16* Whp, const _Float16* Wlp,
                  const float* bias, float* Cf, int M, int Kd, int N, int ldc) {
        gemm_mfma<0, false, false, 3><<<dim3(N / 128, M / 128), 256, 0, stream>>>(
            Ahp, Alp, Whp, Wlp, bias, Cf, nullptr, nullptr, M, Kd, N, ldc,
            nullptr, nullptr, nullptr, nullptr);
    };

    auto run_mha = [&](const _Float16* q_h, const _Float16* q_l,
                       const _Float16* kv_h, const _Float16* kv_l,
                       const _Float16* wT_h, const _Float16* wT_l, const float* bt,
                       const int* ktoks, int causal, bool fused) {
        if (fused) {
            g3(q_h, q_l, wT_h, wT_l, bt, qkvb, NTOK, D_, 1536, QLD);
        } else {
            g3(q_h, q_l, wT_h, wT_l, bt, qkvb, NTOK, D_, 512, QLD);
            g3(kv_h, kv_l, wT_h + (size_t)D_ * D_, wT_l + (size_t)D_ * D_, bt + D_,
               qkvb + 512, NTOK, D_, 1024, QLD);
        }
        attn_scores<<<dim3(16, 16, 16), 256, 0, stream>>>(qkvb, ktoks, scores, causal);
        softmax_rows<<<16 * 1024, 256, 0, stream>>>(scores);
        attn_pv<<<dim3(16, 16), 256, 0, stream>>>(scores, qkvb, ctx_h, ctx_l);
        g3(ctx_h, ctx_l, wT_h + (size_t)3 * D_ * D_, wT_l + (size_t)3 * D_ * D_,
           bt + 3 * D_, aout, NTOK, D_, 512, 512);
    };

    auto run_moe = [&](const float* x, const _Float16* x_h, const _Float16* x_l,
                       const float* gwp, const float* gbp,
                       const float* w1p, const float* b1p,
                       const float* w2p, const float* b2p) {
        gate_logits<<<NTOK * E_ / 256, 256, 0, stream>>>(x, gwp, gbp, lg);
        gate_top2<<<NTOK / 256, 256, 0, stream>>>(lg, topv, topi);
        build_routes<<<1, 64, 0, stream>>>(topi, route_tok, route_row, counts, pad_base, rb_expert);
        transpose_w<true><<<dim3(32, 8, 8), 256, 0, stream>>>(w1p, w1t_h, w1t_l, D_, F_);
        transpose_w<true><<<dim3(8, 32, 8), 256, 0, stream>>>(w2p, w2t_h, w2t_l, F_, D_);
        gemm_mfma<1, true, true, 3><<<dim3(F_ / 128, MAXRB), 256, 0, stream>>>(
            x_h, x_l, w1t_h, w1t_l, b1p, nullptr, hbuf_h, hbuf_l, 0, D_, F_, F_,
            route_tok, rb_expert, pad_base, counts);
        gemm_mfma<2, false, false, 3><<<dim3(D_ / 128, MAXRB), 256, 0, stream>>>(
            hbuf_h, hbuf_l, w2t_h, w2t_l, b2p, eobuf, nullptr, nullptr, 0, F_, D_, D_,
            route_tok, rb_expert, pad_base, counts);
        moe_combine<<<NTOK, 256, 0, stream>>>(eobuf, topv, route_row, aout);
    };

    // ---------------- encoder ----------------
    embed_pe<<<B_ * S_, 256, 0, stream>>>(src, enc_emb, xA, xA_h, xA_l, S_);
    float* cur = xA; float* alt = xB;
    _Float16* cur_h = xA_h; _Float16* cur_l = xA_l;
    _Float16* alt_h = xB_h; _Float16* alt_l = xB_l;
    for (int l = 0; l < L_; ++l) {
        run_mha(cur_h, cur_l, nullptr, nullptr,
                encA_h + (size_t)l * 4 * D_ * D_, encA_l + (size_t)l * 4 * D_ * D_,
                enc_attn_b + (size_t)l * 4 * D_, src, 0, true);
        ln_add<<<NTOK, 256, 0, stream>>>(cur, aout,
            enc_ln_g + (size_t)(l * 2 + 0) * D_, enc_ln_b + (size_t)(l * 2 + 0) * D_,
            alt, alt_h, alt_l);
        { float* t = cur; cur = alt; alt = t; }
        { _Float16* t = cur_h; cur_h = alt_h; alt_h = t; t = cur_l; cur_l = alt_l; alt_l = t; }
        run_moe(cur, cur_h, cur_l, enc_gate_w + (size_t)l * D_ * E_, enc_gate_b + (size_t)l * E_,
                enc_w1 + (size_t)l * E_ * D_ * F_, enc_b1 + (size_t)l * E_ * F_,
                enc_w2 + (size_t)l * E_ * F_ * D_, enc_b2 + (size_t)l * E_ * D_);
        ln_add<<<NTOK, 256, 0, stream>>>(cur, aout,
            enc_ln_g + (size_t)(l * 2 + 1) * D_, enc_ln_b + (size_t)(l * 2 + 1) * D_,
            alt, alt_h, alt_l);
        { float* t = cur; cur = alt; alt = t; }
        { _Float16* t = cur_h; cur_h = alt_h; alt_h = t; t = cur_l; cur_l = alt_l; alt_l = t; }
    }
    _Float16* enc_h = cur_h; _Float16* enc_l = cur_l;

    // ---------------- decoder ----------------
    embed_pe<<<B_ * T_, 256, 0, stream>>>(tgt, dec_emb, yA, yA_h, yA_l, T_);
    float* dc = yA; float* da = yB;
    _Float16* dc_h = yA_h; _Float16* dc_l = yA_l;
    _Float16* da_h = yB_h; _Float16* da_l = yB_l;
    for (int l = 0; l < L_; ++l) {
        run_mha(dc_h, dc_l, nullptr, nullptr,
                saA_h + (size_t)l * 4 * D_ * D_, saA_l + (size_t)l * 4 * D_ * D_,
                dec_sa_b + (size_t)l * 4 * D_, tgt, 1, true);
        ln_add<<<NTOK, 256, 0, stream>>>(dc, aout,
            dec_ln_g + (size_t)(l * 3 + 0) * D_, dec_ln_b + (size_t)(l * 3 + 0) * D_,
            da, da_h, da_l);
        { float* t = dc; dc = da; da = t; }
        { _Float16* t = dc_h; dc_h = da_h; da_h = t; t = dc_l; dc_l = da_l; da_l = t; }
        run_mha(dc_h, dc_l, enc_h, enc_l,
                caA_h + (size_t)l * 4 * D_ * D_, caA_l + (size_t)l * 4 * D_ * D_,
                dec_ca_b + (size_t)l * 4 * D_, src, 0, false);
        ln_add<<<NTOK, 256, 0, stream>>>(dc, aout,
            dec_ln_g + (size_t)(l * 3 + 1) * D_, dec_ln_b + (size_t)(l * 3 + 1) * D_,
            da, da_h, da_l);
        { float* t = dc; dc = da; da = t; }
        { _Float16* t = dc_h; dc_h = da_h; da_h = t; t = dc_l; dc_l = da_l; da_l = t; }
        run_moe(dc, dc_h, dc_l, dec_gate_w + (size_t)l * D_ * E_, dec_gate_b + (size_t)l * E_,
                dec_w1 + (size_t)l * E_ * D_ * F_, dec_b1 + (size_t)l * E_ * F_,
                dec_w2 + (size_t)l * E_ * F_ * D_, dec_b2 + (size_t)l * E_ * D_);
        bool last = (l == L_ - 1);
        ln_add<<<NTOK, 256, 0, stream>>>(dc, aout,
            dec_ln_g + (size_t)(l * 3 + 2) * D_, dec_ln_b + (size_t)(l * 3 + 2) * D_,
            da, last ? final_h : da_h, da_l);
        { float* t = dc; dc = da; da = t; }
        { _Float16* t = dc_h; dc_h = da_h; da_h = t; t = dc_l; dc_l = da_l; da_l = t; }
    }

    // ---------------- final projection (single-pass f16 MFMA; overwrites all of d_out)
    gemm_mfma<0, false, false, 1><<<dim3(V_ / 128, NTOK / 128), 256, 0, stream>>>(
        final_h, nullptr, outwT_h, nullptr, out_b, out, nullptr, nullptr,
        NTOK, D_, V_, V_, nullptr, nullptr, nullptr, nullptr);
}

// Round 3
// 2093.835 us; speedup vs baseline: 2.8203x; 1.6432x over previous
//
#include <hip/hip_runtime.h>
#include <hip/hip_bf16.h>

#define L_ 2
#define D_ 512
#define H_ 8
#define DK_ 64
#define F_ 2048
#define E_ 8
#define V_ 32000
#define B_ 2
#define S_ 1024
#define T_ 1024
#define NTOK (B_*S_)
#define MAXPAD 5120            // per-expert 128-padded total upper bound
#define MAXRB  (MAXPAD/128)    // 40
#define QLD 1536               // fused qkv row stride

typedef unsigned short u16;
typedef _Float16 f16x8 __attribute__((ext_vector_type(8)));
typedef float f32x4 __attribute__((ext_vector_type(4)));

__device__ __forceinline__ void gload16(const void* g, const void* l) {
    __builtin_amdgcn_global_load_lds(
        (const __attribute__((address_space(1))) void*)g,
        (__attribute__((address_space(3))) void*)l, 16, 0, 0);
}

__device__ __forceinline__ void split_f16(float v, _Float16& h, _Float16& l) {
    h = (_Float16)v;
    l = (_Float16)(v - (float)h);
}

// ---------------------------------------------------------------- embedding + PE (f32 + hi/lo f16)
__global__ __launch_bounds__(256) void embed_pe(const int* __restrict__ toks,
                                                const float* __restrict__ emb,
                                                float* __restrict__ o,
                                                _Float16* __restrict__ oh,
                                                _Float16* __restrict__ ol, int Slen)
{
    int n = blockIdx.x;
    int spos = n % Slen;
    int tok = toks[n];
    const float* erow = emb + (size_t)tok * D_;
    size_t rb = (size_t)n * D_;
    for (int j = threadIdx.x; j < D_; j += 256) {
        int i = j >> 1;
        float arg = (float)spos * expf(-(float)i * 0.035977892f);
        float pe = (j & 1) ? cosf(arg) : sinf(arg);
        float v = erow[j] + pe;
        o[rb + j] = v;
        _Float16 h, l; split_f16(v, h, l);
        oh[rb + j] = h; ol[rb + j] = l;
    }
}

// ---------------------------------------------------------------- weight transpose f32[K][N] -> f16 hi/lo [N][K]
template<bool WLO>
__global__ __launch_bounds__(256) void transpose_w(const float* __restrict__ in,
                                                   _Float16* __restrict__ oh,
                                                   _Float16* __restrict__ ol, int R, int C)
{
    __shared__ float t[64][65];
    size_t sb = (size_t)blockIdx.z * R * C;
    in += sb; oh += sb; if (WLO) ol += sb;
    int c0 = blockIdx.x * 64, r0 = blockIdx.y * 64;
    int tid = threadIdx.x;
    int cc = tid & 63, r4 = tid >> 6;
    #pragma unroll
    for (int p = 0; p < 16; ++p) {
        int r = p * 4 + r4;
        t[r][cc] = in[(size_t)(r0 + r) * C + c0 + cc];
    }
    __syncthreads();
    int rr = tid & 63, c4 = tid >> 6;
    #pragma unroll
    for (int p = 0; p < 16; ++p) {
        int c = p * 4 + c4;
        float v = t[rr][c];
        _Float16 h = (_Float16)v;
        oh[(size_t)(c0 + c) * R + r0 + rr] = h;
        if (WLO) ol[(size_t)(c0 + c) * R + r0 + rr] = (_Float16)(v - (float)h);
    }
}

// ---------------------------------------------------------------- MFMA GEMM
// C[M,N] = A[M,K] @ Wt[N,K]^T + bias ; split-f16 3-pass (PASSES=3) or single hi (PASSES=1)
// MODE 0 plain, 1 routed gather, 2 routed direct
template<int MODE, bool RELU, bool OUTSPLIT, int PASSES>
__global__ __launch_bounds__(256, 2) void gemm_mfma(
    const _Float16* __restrict__ Ah, const _Float16* __restrict__ Al,
    const _Float16* __restrict__ Wh, const _Float16* __restrict__ Wl,
    const float* __restrict__ biasbase,
    float* __restrict__ Cf, _Float16* __restrict__ Ch, _Float16* __restrict__ Cl,
    int M, int Kd, int N, int ldc,
    const int* __restrict__ route_tok, const int* __restrict__ rb_expert,
    const int* __restrict__ pad_base, const int* __restrict__ counts)
{
    int row0 = blockIdx.y * 128;
    const _Float16* Wmh = Wh;
    const _Float16* Wml = Wl;
    const float* bias = biasbase;
    int vend = M;
    if (MODE != 0) {
        int total = pad_base[E_];
        if (row0 >= total) return;
        int e = rb_expert[row0 >> 7];
        vend = pad_base[e] + counts[e];
        Wmh = Wh + (size_t)e * Kd * N;
        if (PASSES == 3) Wml = Wl + (size_t)e * Kd * N;
        bias = biasbase + (size_t)e * N;
    }
    int col0 = blockIdx.x * 128;
    int tid = threadIdx.x;
    int lane = tid & 63, w = tid >> 6;
    int wm = w >> 1, wn = w & 1;

    __shared__ _Float16 lds[(PASSES == 3 ? 4 : 2) * 8192];
    _Float16* lAh = lds;
    _Float16* lBh = lds + 8192;
    _Float16* lAl = (PASSES == 3) ? lds + 16384 : nullptr;
    _Float16* lBl = (PASSES == 3) ? lds + 24576 : nullptr;

    // staging: wave w covers rows [w*32, w*32+32) of each 128x64 tile in 4 issues of 8 rows
    int srow8 = lane >> 3;          // row within 8-row issue
    int q8 = lane & 7;              // linear 16B slot
    size_t aoff[4], boff[4];
    #pragma unroll
    for (int j = 0; j < 4; ++j) {
        int m = w * 32 + j * 8 + srow8;
        int gr = row0 + m;
        int ar = (MODE == 1) ? route_tok[gr] : gr;
        int sslot = (q8 ^ (m & 7)) << 3;     // inverse-swizzled source slot (elements)
        aoff[j] = (size_t)ar * Kd + sslot;
        boff[j] = (size_t)(col0 + m) * Kd + sslot;
    }

    f32x4 zero4 = {0.f, 0.f, 0.f, 0.f};
    f32x4 acc[4][4];
    #pragma unroll
    for (int i = 0; i < 4; ++i)
        #pragma unroll
        for (int j = 0; j < 4; ++j) acc[i][j] = zero4;

    int lm = lane & 15, kg = lane >> 4;

    for (int k0 = 0; k0 < Kd; k0 += 64) {
        #pragma unroll
        for (int j = 0; j < 4; ++j) {
            int lb = (w * 32 + j * 8) * 64;   // wave-uniform LDS element base
            gload16(Ah + aoff[j] + k0, lAh + lb);
            gload16(Wmh + boff[j] + k0, lBh + lb);
            if (PASSES == 3) {
                gload16(Al + aoff[j] + k0, lAl + lb);
                gload16(Wml + boff[j] + k0, lBl + lb);
            }
        }
        __syncthreads();
        #pragma unroll
        for (int ks = 0; ks < 2; ++ks) {
            f16x8 ah[4], bh[4];
            #pragma unroll
            for (int i = 0; i < 4; ++i) {
                int m = wm * 64 + i * 16 + lm;
                ah[i] = *(const f16x8*)&lAh[m * 64 + ((((ks << 2) + kg) ^ (m & 7)) << 3)];
                int n = wn * 64 + i * 16 + lm;
                bh[i] = *(const f16x8*)&lBh[n * 64 + ((((ks << 2) + kg) ^ (n & 7)) << 3)];
            }
            #pragma unroll
            for (int i = 0; i < 4; ++i)
                #pragma unroll
                for (int jn = 0; jn < 4; ++jn)
                    acc[i][jn] = __builtin_amdgcn_mfma_f32_16x16x32_f16(ah[i], bh[jn], acc[i][jn], 0, 0, 0);
            if (PASSES == 3) {
                f16x8 bl[4];
                #pragma unroll
                for (int i = 0; i < 4; ++i) {
                    int n = wn * 64 + i * 16 + lm;
                    bl[i] = *(const f16x8*)&lBl[n * 64 + ((((ks << 2) + kg) ^ (n & 7)) << 3)];
                }
                #pragma unroll
                for (int i = 0; i < 4; ++i)
                    #pragma unroll
                    for (int jn = 0; jn < 4; ++jn)
                        acc[i][jn] = __builtin_amdgcn_mfma_f32_16x16x32_f16(ah[i], bl[jn], acc[i][jn], 0, 0, 0);
                f16x8 al[4];
                #pragma unroll
                for (int i = 0; i < 4; ++i) {
                    int m = wm * 64 + i * 16 + lm;
                    al[i] = *(const f16x8*)&lAl[m * 64 + ((((ks << 2) + kg) ^ (m & 7)) << 3)];
                }
                #pragma unroll
                for (int i = 0; i < 4; ++i)
                    #pragma unroll
                    for (int jn = 0; jn < 4; ++jn)
                        acc[i][jn] = __builtin_amdgcn_mfma_f32_16x16x32_f16(al[i], bh[jn], acc[i][jn], 0, 0, 0);
            }
        }
        __syncthreads();
    }

    // epilogue: C/D layout col=lane&15, row=(lane>>4)*4+reg
    float bv[4];
    #pragma unroll
    for (int jn = 0; jn < 4; ++jn) bv[jn] = bias[col0 + wn * 64 + jn * 16 + lm];
    int rowb = row0 + wm * 64 + (lane >> 4) * 4;
    #pragma unroll
    for (int i = 0; i < 4; ++i) {
        #pragma unroll
        for (int r = 0; r < 4; ++r) {
            int row = rowb + i * 16 + r;
            if (MODE != 0 && row >= vend) continue;
            #pragma unroll
            for (int jn = 0; jn < 4; ++jn) {
                float v = acc[i][jn][r] + bv[jn];
                if (RELU) v = fmaxf(v, 0.f);
                int c = col0 + wn * 64 + jn * 16 + lm;
                if (OUTSPLIT) {
                    _Float16 h, l; split_f16(v, h, l);
                    Ch[(size_t)row * ldc + c] = h;
                    Cl[(size_t)row * ldc + c] = l;
                } else {
                    Cf[(size_t)row * ldc + c] = v;
                }
            }
        }
    }
}

// ---------------------------------------------------------------- attention scores (f32, exact)
__global__ __launch_bounds__(256) void attn_scores(const float* __restrict__ qkv,
                                                   const int* __restrict__ toks,
                                                   float* __restrict__ scores, int causal)
{
    __shared__ float Qs[64][65];
    __shared__ float Ks[64][65];
    int bh = blockIdx.z; int b = bh >> 3; int h = bh & 7;
    int q0 = blockIdx.y * 64, k0 = blockIdx.x * 64;
    int tid = threadIdx.x;
    const float* qb = qkv + (size_t)b * S_ * QLD + h * DK_;
    const float* kb = qkv + (size_t)b * S_ * QLD + 512 + h * DK_;
    #pragma unroll
    for (int i = 0; i < 16; ++i) {
        int idx = tid + 256 * i;
        int r = idx >> 6, c = idx & 63;
        Qs[r][c] = qb[(size_t)(q0 + r) * QLD + c];
        Ks[r][c] = kb[(size_t)(k0 + r) * QLD + c];
    }
    __syncthreads();
    int tx = tid & 15, ty = tid >> 4;
    float acc[4][4] = {{0.f}};
    for (int d = 0; d < 64; ++d) {
        float a[4], bb[4];
        #pragma unroll
        for (int i = 0; i < 4; ++i) a[i] = Qs[ty + 16 * i][d];
        #pragma unroll
        for (int j = 0; j < 4; ++j) bb[j] = Ks[tx + 16 * j][d];
        #pragma unroll
        for (int i = 0; i < 4; ++i)
            #pragma unroll
            for (int j = 0; j < 4; ++j)
                acc[i][j] += a[i] * bb[j];
    }
    float* srow = scores + (size_t)bh * S_ * S_;
    #pragma unroll
    for (int i = 0; i < 4; ++i) {
        int qi = q0 + ty + 16 * i;
        #pragma unroll
        for (int j = 0; j < 4; ++j) {
            int ki = k0 + tx + 16 * j;
            bool keep = (toks[b * S_ + ki] != 0) && (!causal || ki <= qi);
            srow[(size_t)qi * S_ + ki] = keep ? acc[i][j] * 0.125f : -1e9f;
        }
    }
}

// ---------------------------------------------------------------- row softmax
__global__ __launch_bounds__(256) void softmax_rows(float* __restrict__ s)
{
    float* p = s + (size_t)blockIdx.x * 1024;
    int tid = threadIdx.x;
    float4 v = ((float4*)p)[tid];
    float m = fmaxf(fmaxf(v.x, v.y), fmaxf(v.z, v.w));
    for (int off = 32; off; off >>= 1) m = fmaxf(m, __shfl_down(m, off));
    __shared__ float red[8];
    int lane = tid & 63, wid = tid >> 6;
    if (!lane) red[wid] = m;
    __syncthreads();
    if (!tid) red[4] = fmaxf(fmaxf(red[0], red[1]), fmaxf(red[2], red[3]));
    __syncthreads();
    m = red[4];
    v.x = expf(v.x - m); v.y = expf(v.y - m); v.z = expf(v.z - m); v.w = expf(v.w - m);
    float su = v.x + v.y + v.z + v.w;
    for (int off = 32; off; off >>= 1) su += __shfl_down(su, off);
    if (!lane) red[wid] = su;
    __syncthreads();
    if (!tid) red[5] = red[0] + red[1] + red[2] + red[3];
    __syncthreads();
    float inv = 1.0f / red[5];
    v.x *= inv; v.y *= inv; v.z *= inv; v.w *= inv;
    ((float4*)p)[tid] = v;
}

// ---------------------------------------------------------------- PV (f32) -> ctx hi/lo f16
__global__ __launch_bounds__(256) void attn_pv(const float* __restrict__ a,
                                               const float* __restrict__ qkv,
                                               _Float16* __restrict__ ch,
                                               _Float16* __restrict__ cl)
{
    __shared__ float As[16][65];
    __shared__ float Vs[16][65];
    int bh = blockIdx.y; int b = bh >> 3; int h = bh & 7;
    int q0 = blockIdx.x * 64;
    int tid = threadIdx.x;
    const float* arow = a + (size_t)bh * S_ * S_;
    const float* vb = qkv + (size_t)b * S_ * QLD + 1024 + h * DK_;
    int tx = tid & 15, ty = tid >> 4;
    float acc[4][4] = {{0.f}};
    for (int k0 = 0; k0 < S_; k0 += 16) {
        int kk = tid & 15, qb_ = tid >> 4;
        #pragma unroll
        for (int i = 0; i < 4; ++i) {
            int qq = qb_ + 16 * i;
            As[kk][qq] = arow[(size_t)(q0 + qq) * S_ + k0 + kk];
        }
        int dd = tid & 63, kb2 = tid >> 6;
        #pragma unroll
        for (int i = 0; i < 4; ++i) {
            int k2 = kb2 + 4 * i;
            Vs[k2][dd] = vb[(size_t)(k0 + k2) * QLD + dd];
        }
        __syncthreads();
        #pragma unroll
        for (int k2 = 0; k2 < 16; ++k2) {
            float aa[4], bb[4];
            #pragma unroll
            for (int i = 0; i < 4; ++i) aa[i] = As[k2][ty + 16 * i];
            #pragma unroll
            for (int j = 0; j < 4; ++j) bb[j] = Vs[k2][tx + 16 * j];
            #pragma unroll
            for (int i = 0; i < 4; ++i)
                #pragma unroll
                for (int j = 0; j < 4; ++j)
                    acc[i][j] += aa[i] * bb[j];
        }
        __syncthreads();
    }
    #pragma unroll
    for (int i = 0; i < 4; ++i)
        #pragma unroll
        for (int j = 0; j < 4; ++j) {
            size_t idx = (size_t)(b * S_ + q0 + ty + 16 * i) * D_ + h * DK_ + tx + 16 * j;
            _Float16 h2, l2; split_f16(acc[i][j], h2, l2);
            ch[idx] = h2; cl[idx] = l2;
        }
}

// ---------------------------------------------------------------- residual + LayerNorm (f32 + hi/lo)
__global__ __launch_bounds__(256) void ln_add(const float* __restrict__ x,
                                              const float* __restrict__ r,
                                              const float* __restrict__ g,
                                              const float* __restrict__ be,
                                              float* __restrict__ o,
                                              _Float16* __restrict__ oh,
                                              _Float16* __restrict__ ol)
{
    int row = blockIdx.x;
    const float* xr = x + (size_t)row * D_;
    const float* rr = r + (size_t)row * D_;
    int tid = threadIdx.x;
    float v0 = xr[tid] + rr[tid];
    float v1 = xr[tid + 256] + rr[tid + 256];
    float s = v0 + v1;
    for (int off = 32; off; off >>= 1) s += __shfl_down(s, off);
    __shared__ float red[8];
    int lane = tid & 63, wid = tid >> 6;
    if (!lane) red[wid] = s;
    __syncthreads();
    if (!tid) red[4] = (red[0] + red[1] + red[2] + red[3]) * (1.0f / 512.0f);
    __syncthreads();
    float m = red[4];
    float d0 = v0 - m, d1 = v1 - m;
    s = d0 * d0 + d1 * d1;
    for (int off = 32; off; off >>= 1) s += __shfl_down(s, off);
    if (!lane) red[wid] = s;
    __syncthreads();
    if (!tid) red[5] = rsqrtf((red[0] + red[1] + red[2] + red[3]) * (1.0f / 512.0f) + 1e-5f);
    __syncthreads();
    float rstd = red[5];
    size_t rb = (size_t)row * D_;
    float y0 = d0 * rstd * g[tid] + be[tid];
    float y1 = d1 * rstd * g[tid + 256] + be[tid + 256];
    o[rb + tid] = y0; o[rb + tid + 256] = y1;
    _Float16 h, l;
    split_f16(y0, h, l); oh[rb + tid] = h; ol[rb + tid] = l;
    split_f16(y1, h, l); oh[rb + tid + 256] = h; ol[rb + tid + 256] = l;
}

// ---------------------------------------------------------------- MoE gate
__global__ __launch_bounds__(256) void gate_logits(const float* __restrict__ xf,
                                                   const float* __restrict__ gw,
                                                   const float* __restrict__ gb,
                                                   float* __restrict__ lg)
{
    int id = blockIdx.x * 256 + threadIdx.x;
    if (id >= NTOK * E_) return;
    int e = id & 7, n = id >> 3;
    const float* x = xf + (size_t)n * D_;
    float s = gb[e];
    for (int d = 0; d < D_; ++d) s += x[d] * gw[d * E_ + e];
    lg[id] = s;
}

__global__ __launch_bounds__(256) void gate_top2(const float* __restrict__ lg,
                                                 float* __restrict__ topv,
                                                 int* __restrict__ topi)
{
    int n = blockIdx.x * 256 + threadIdx.x;
    if (n >= NTOK) return;
    float l[E_], p[E_];
    float m = -1e30f;
    #pragma unroll
    for (int e = 0; e < E_; ++e) { l[e] = lg[n * E_ + e]; m = fmaxf(m, l[e]); }
    float su = 0.f;
    #pragma unroll
    for (int e = 0; e < E_; ++e) { p[e] = expf(l[e] - m); su += p[e]; }
    float inv = 1.0f / su;
    int i1 = 0; float v1 = p[0];
    #pragma unroll
    for (int e = 1; e < E_; ++e) if (p[e] > v1) { v1 = p[e]; i1 = e; }
    int i2 = -1; float v2 = -1.f;
    #pragma unroll
    for (int e = 0; e < E_; ++e) if (e != i1 && p[e] > v2) { v2 = p[e]; i2 = e; }
    topv[n * 2] = v1 * inv; topv[n * 2 + 1] = v2 * inv;
    topi[n * 2] = i1;       topi[n * 2 + 1] = i2;
}

// ---------------------------------------------------------------- parallel deterministic routing
// single block, 1024 threads. 4096 slots -> 256 chunks of 16.
__global__ __launch_bounds__(1024) void build_routes(const int* __restrict__ topi,
                                                     int* __restrict__ route_tok,
                                                     int* __restrict__ route_row,
                                                     int* __restrict__ counts,
                                                     int* __restrict__ pad_base,
                                                     int* __restrict__ rb_expert)
{
    __shared__ int eid[NTOK * 2];                 // 16 KB
    __shared__ unsigned short chist[256][8];      // 4 KB
    __shared__ int pb[E_ + 1];
    __shared__ int cnt[E_];
    int t = threadIdx.x;
    #pragma unroll
    for (int i = 0; i < 4; ++i) eid[t + 1024 * i] = topi[t + 1024 * i];
    // zero the padded route table (valid entries overwritten below, same block, barriered)
    #pragma unroll
    for (int g = 0; g < 5; ++g) route_tok[t + 1024 * g] = 0;
    __syncthreads();

    if (t < 256) {
        int r[16];
        #pragma unroll
        for (int i = 0; i < 16; ++i) r[i] = eid[t * 16 + i];
        #pragma unroll
        for (int e = 0; e < 8; ++e) {
            int h = 0;
            #pragma unroll
            for (int i = 0; i < 16; ++i) h += (r[i] == e) ? 1 : 0;
            chist[t][e] = (unsigned short)h;
        }
    }
    __syncthreads();

    if (t < 8) {   // exclusive prefix over chunks, per expert
        int run = 0;
        for (int c = 0; c < 256; ++c) {
            int v = chist[c][t];
            chist[c][t] = (unsigned short)run;
            run += v;
        }
        cnt[t] = run;
        counts[t] = run;
    }
    __syncthreads();

    if (t == 0) {
        int pad = 0;
        for (int e = 0; e < 8; ++e) {
            pb[e] = pad;
            pad_base[e] = pad;
            int nb = (cnt[e] + 127) >> 7;
            for (int rb = 0; rb < nb; ++rb) rb_expert[(pad >> 7) + rb] = e;
            pad += nb << 7;
        }
        pb[8] = pad;
        pad_base[8] = pad;
    }
    __syncthreads();

    if (t < 256) {
        int r[16];
        #pragma unroll
        for (int i = 0; i < 16; ++i) r[i] = eid[t * 16 + i];
        #pragma unroll
        for (int e = 0; e < 8; ++e) {   // static expert loop: register-only offsets
            int o = pb[e] + chist[t][e];
            #pragma unroll
            for (int i = 0; i < 16; ++i) {
                if (r[i] == e) {
                    int slot = t * 16 + i;
                    route_tok[o] = slot >> 1;
                    route_row[slot] = o;
                    o++;
                }
            }
        }
    }
}

__global__ __launch_bounds__(256) void moe_combine(const float* __restrict__ eo,
                                                   const float* __restrict__ topv,
                                                   const int* __restrict__ route_row,
                                                   float* __restrict__ f)
{
    int n = blockIdx.x;
    int r0 = route_row[n * 2], r1 = route_row[n * 2 + 1];
    float w0 = topv[n * 2], w1 = topv[n * 2 + 1];
    const float* e0 = eo + (size_t)r0 * D_;
    const float* e1 = eo + (size_t)r1 * D_;
    float* fr = f + (size_t)n * D_;
    for (int j = threadIdx.x; j < D_; j += 256)
        fr[j] = w0 * e0[j] + w1 * e1[j];
}

// ================================================================ host orchestration
extern "C" void kernel_launch(void* const* d_in, const int* in_sizes, int n_in,
                              void* d_out, int out_size, void* d_ws, size_t ws_size,
                              hipStream_t stream)
{
    const int*   src        = (const int*)  d_in[0];
    const int*   tgt        = (const int*)  d_in[1];
    const float* enc_emb    = (const float*)d_in[2];
    const float* dec_emb    = (const float*)d_in[3];
    const float* enc_attn_w = (const float*)d_in[4];
    const float* enc_attn_b = (const float*)d_in[5];
    const float* enc_ln_g   = (const float*)d_in[6];
    const float* enc_ln_b   = (const float*)d_in[7];
    const float* enc_gate_w = (const float*)d_in[8];
    const float* enc_gate_b = (const float*)d_in[9];
    const float* enc_w1     = (const float*)d_in[10];
    const float* enc_b1     = (const float*)d_in[11];
    const float* enc_w2     = (const float*)d_in[12];
    const float* enc_b2     = (const float*)d_in[13];
    const float* dec_sa_w   = (const float*)d_in[14];
    const float* dec_sa_b   = (const float*)d_in[15];
    const float* dec_ca_w   = (const float*)d_in[16];
    const float* dec_ca_b   = (const float*)d_in[17];
    const float* dec_ln_g   = (const float*)d_in[18];
    const float* dec_ln_b   = (const float*)d_in[19];
    const float* dec_gate_w = (const float*)d_in[20];
    const float* dec_gate_b = (const float*)d_in[21];
    const float* dec_w1     = (const float*)d_in[22];
    const float* dec_b1     = (const float*)d_in[23];
    const float* dec_w2     = (const float*)d_in[24];
    const float* dec_b2     = (const float*)d_in[25];
    const float* out_w      = (const float*)d_in[26];
    const float* out_b      = (const float*)d_in[27];
    float* out = (float*)d_out;

    // ---- d_out scratch layout (dead until final GEMM overwrites everything)
    char* ob = (char*)d_out;
    size_t oc = 0;
    auto dalloc = [&](size_t bytes) { char* p = ob + oc; oc += (bytes + 255) & ~(size_t)255; return p; };
    // union region: scores (67.1MB) == moe w1t/w2t hi+lo (4 x 16.77MB) -- never live together
    char* unionp = dalloc(67108864);
    float*    scores = (float*)unionp;
    _Float16* w1t_h  = (_Float16*)unionp;
    _Float16* w1t_l  = w1t_h + (size_t)E_ * F_ * D_;
    _Float16* w2t_h  = w1t_l + (size_t)E_ * F_ * D_;
    _Float16* w2t_l  = w2t_h + (size_t)E_ * F_ * D_;
    float* qkvb  = (float*)dalloc((size_t)NTOK * QLD * 4);
    float* aout  = (float*)dalloc((size_t)NTOK * D_ * 4);
    _Float16* ctx_h = (_Float16*)dalloc((size_t)NTOK * D_ * 2);
    _Float16* ctx_l = (_Float16*)dalloc((size_t)NTOK * D_ * 2);
    _Float16* hbuf_h = (_Float16*)dalloc((size_t)MAXPAD * F_ * 2);
    _Float16* hbuf_l = (_Float16*)dalloc((size_t)MAXPAD * F_ * 2);
    float* eobuf = (float*)dalloc((size_t)MAXPAD * D_ * 4);
    _Float16* encA_h = (_Float16*)dalloc((size_t)L_ * 4 * D_ * D_ * 2);
    _Float16* encA_l = (_Float16*)dalloc((size_t)L_ * 4 * D_ * D_ * 2);
    _Float16* saA_h  = (_Float16*)dalloc((size_t)L_ * 4 * D_ * D_ * 2);
    _Float16* saA_l  = (_Float16*)dalloc((size_t)L_ * 4 * D_ * D_ * 2);
    _Float16* caA_h  = (_Float16*)dalloc((size_t)L_ * 4 * D_ * D_ * 2);
    _Float16* caA_l  = (_Float16*)dalloc((size_t)L_ * 4 * D_ * D_ * 2);
    float* xA = (float*)dalloc((size_t)NTOK * D_ * 4);
    float* xB = (float*)dalloc((size_t)NTOK * D_ * 4);
    float* yA = (float*)dalloc((size_t)NTOK * D_ * 4);
    float* yB = (float*)dalloc((size_t)NTOK * D_ * 4);
    _Float16* xA_h = (_Float16*)dalloc((size_t)NTOK * D_ * 2);
    _Float16* xA_l = (_Float16*)dalloc((size_t)NTOK * D_ * 2);
    _Float16* xB_h = (_Float16*)dalloc((size_t)NTOK * D_ * 2);
    _Float16* xB_l = (_Float16*)dalloc((size_t)NTOK * D_ * 2);
    _Float16* yA_h = (_Float16*)dalloc((size_t)NTOK * D_ * 2);
    _Float16* yA_l = (_Float16*)dalloc((size_t)NTOK * D_ * 2);
    _Float16* yB_h = (_Float16*)dalloc((size_t)NTOK * D_ * 2);
    _Float16* yB_l = (_Float16*)dalloc((size_t)NTOK * D_ * 2);

    // ---- ws (survives the final GEMM): transposed out_w hi, final activation hi, routing
    char* wp = (char*)d_ws;
    size_t wc = 0;
    auto walloc = [&](size_t bytes) { char* p = wp + wc; wc += (bytes + 255) & ~(size_t)255; return p; };
    _Float16* outwT_h = (_Float16*)walloc((size_t)V_ * D_ * 2);
    _Float16* final_h = (_Float16*)walloc((size_t)NTOK * D_ * 2);
    float* lg   = (float*)walloc((size_t)NTOK * E_ * 4);
    float* topv = (float*)walloc((size_t)NTOK * 2 * 4);
    int*   topi = (int*)  walloc((size_t)NTOK * 2 * 4);
    int*   route_tok = (int*)walloc((size_t)MAXPAD * 4);
    int*   route_row = (int*)walloc((size_t)NTOK * 2 * 4);
    int*   counts    = (int*)walloc(64);
    int*   pad_base  = (int*)walloc(64);
    int*   rb_expert = (int*)walloc((size_t)64 * 4);

    // ---- weight transposes (once per launch)
    transpose_w<true><<<dim3(8, 8, 8), 256, 0, stream>>>(enc_attn_w, encA_h, encA_l, D_, D_);
    transpose_w<true><<<dim3(8, 8, 8), 256, 0, stream>>>(dec_sa_w, saA_h, saA_l, D_, D_);
    transpose_w<true><<<dim3(8, 8, 8), 256, 0, stream>>>(dec_ca_w, caA_h, caA_l, D_, D_);
    transpose_w<false><<<dim3(500, 8, 1), 256, 0, stream>>>(out_w, outwT_h, nullptr, D_, V_);

    auto g3 = [&](const _Float16* Ahp, const _Float16* Alp,
                  const _Float16* Whp, const _Float16* Wlp,
                  const float* bias, float* Cf, int M, int Kd, int N, int ldc) {
        gemm_mfma<0, false, false, 3><<<dim3(N / 128, M / 128), 256, 0, stream>>>(
            Ahp, Alp, Whp, Wlp, bias, Cf, nullptr, nullptr, M, Kd, N, ldc,
            nullptr, nullptr, nullptr, nullptr);
    };

    auto run_mha = [&](const _Float16* q_h, const _Float16* q_l,
                       const _Float16* kv_h, const _Float16* kv_l,
                       const _Float16* wT_h, const _Float16* wT_l, const float* bt,
                       const int* ktoks, int causal, bool fused) {
        if (fused) {
            g3(q_h, q_l, wT_h, wT_l, bt, qkvb, NTOK, D_, 1536, QLD);
        } else {
            g3(q_h, q_l, wT_h, wT_l, bt, qkvb, NTOK, D_, 512, QLD);
            g3(kv_h, kv_l, wT_h + (size_t)D_ * D_, wT_l + (size_t)D_ * D_, bt + D_,
               qkvb + 512, NTOK, D_, 1024, QLD);
        }
        attn_scores<<<dim3(16, 16, 16), 256, 0, stream>>>(qkvb, ktoks, scores, causal);
        softmax_rows<<<16 * 1024, 256, 0, stream>>>(scores);
        attn_pv<<<dim3(16, 16), 256, 0, stream>>>(scores, qkvb, ctx_h, ctx_l);
        g3(ctx_h, ctx_l, wT_h + (size_t)3 * D_ * D_, wT_l + (size_t)3 * D_ * D_,
           bt + 3 * D_, aout, NTOK, D_, 512, 512);
    };

    auto run_moe = [&](const float* x, const _Float16* x_h, const _Float16* x_l,
                       const float* gwp, const float* gbp,
                       const float* w1p, const float* b1p,
                       const float* w2p, const float* b2p) {
        gate_logits<<<NTOK * E_ / 256, 256, 0, stream>>>(x, gwp, gbp, lg);
        gate_top2<<<NTOK / 256, 256, 0, stream>>>(lg, topv, topi);
        build_routes<<<1, 1024, 0, stream>>>(topi, route_tok, route_row, counts, pad_base, rb_expert);
        transpose_w<true><<<dim3(32, 8, 8), 256, 0, stream>>>(w1p, w1t_h, w1t_l, D_, F_);
        transpose_w<true><<<dim3(8, 32, 8), 256, 0, stream>>>(w2p, w2t_h, w2t_l, F_, D_);
        gemm_mfma<1, true, true, 3><<<dim3(F_ / 128, MAXRB), 256, 0, stream>>>(
            x_h, x_l, w1t_h, w1t_l, b1p, nullptr, hbuf_h, hbuf_l, 0, D_, F_, F_,
            route_tok, rb_expert, pad_base, counts);
        gemm_mfma<2, false, false, 3><<<dim3(D_ / 128, MAXRB), 256, 0, stream>>>(
            hbuf_h, hbuf_l, w2t_h, w2t_l, b2p, eobuf, nullptr, nullptr, 0, F_, D_, D_,
            route_tok, rb_expert, pad_base, counts);
        moe_combine<<<NTOK, 256, 0, stream>>>(eobuf, topv, route_row, aout);
    };

    // ---------------- encoder ----------------
    embed_pe<<<B_ * S_, 256, 0, stream>>>(src, enc_emb, xA, xA_h, xA_l, S_);
    float* cur = xA; float* alt = xB;
    _Float16* cur_h = xA_h; _Float16* cur_l = xA_l;
    _Float16* alt_h = xB_h; _Float16* alt_l = xB_l;
    for (int l = 0; l < L_; ++l) {
        run_mha(cur_h, cur_l, nullptr, nullptr,
                encA_h + (size_t)l * 4 * D_ * D_, encA_l + (size_t)l * 4 * D_ * D_,
                enc_attn_b + (size_t)l * 4 * D_, src, 0, true);
        ln_add<<<NTOK, 256, 0, stream>>>(cur, aout,
            enc_ln_g + (size_t)(l * 2 + 0) * D_, enc_ln_b + (size_t)(l * 2 + 0) * D_,
            alt, alt_h, alt_l);
        { float* t = cur; cur = alt; alt = t; }
        { _Float16* t = cur_h; cur_h = alt_h; alt_h = t; t = cur_l; cur_l = alt_l; alt_l = t; }
        run_moe(cur, cur_h, cur_l, enc_gate_w + (size_t)l * D_ * E_, enc_gate_b + (size_t)l * E_,
                enc_w1 + (size_t)l * E_ * D_ * F_, enc_b1 + (size_t)l * E_ * F_,
                enc_w2 + (size_t)l * E_ * F_ * D_, enc_b2 + (size_t)l * E_ * D_);
        ln_add<<<NTOK, 256, 0, stream>>>(cur, aout,
            enc_ln_g + (size_t)(l * 2 + 1) * D_, enc_ln_b + (size_t)(l * 2 + 1) * D_,
            alt, alt_h, alt_l);
        { float* t = cur; cur = alt; alt = t; }
        { _Float16* t = cur_h; cur_h = alt_h; alt_h = t; t = cur_l; cur_l = alt_l; alt_l = t; }
    }
    _Float16* enc_h = cur_h; _Float16* enc_l = cur_l;

    // ---------------- decoder ----------------
    embed_pe<<<B_ * T_, 256, 0, stream>>>(tgt, dec_emb, yA, yA_h, yA_l, T_);
    float* dc = yA; float* da = yB;
    _Float16* dc_h = yA_h; _Float16* dc_l = yA_l;
    _Float16* da_h = yB_h; _Float16* da_l = yB_l;
    for (int l = 0; l < L_; ++l) {
        run_mha(dc_h, dc_l, nullptr, nullptr,
                saA_h + (size_t)l * 4 * D_ * D_, saA_l + (size_t)l * 4 * D_ * D_,
                dec_sa_b + (size_t)l * 4 * D_, tgt, 1, true);
        ln_add<<<NTOK, 256, 0, stream>>>(dc, aout,
            dec_ln_g + (size_t)(l * 3 + 0) * D_, dec_ln_b + (size_t)(l * 3 + 0) * D_,
            da, da_h, da_l);
        { float* t = dc; dc = da; da = t; }
        { _Float16* t = dc_h; dc_h = da_h; da_h = t; t = dc_l; dc_l = da_l; da_l = t; }
        run_mha(dc_h, dc_l, enc_h, enc_l,
                caA_h + (size_t)l * 4 * D_ * D_, caA_l + (size_t)l * 4 * D_ * D_,
                dec_ca_b + (size_t)l * 4 * D_, src, 0, false);
        ln_add<<<NTOK, 256, 0, stream>>>(dc, aout,
            dec_ln_g + (size_t)(l * 3 + 1) * D_, dec_ln_b + (size_t)(l * 3 + 1) * D_,
            da, da_h, da_l);
        { float* t = dc; dc = da; da = t; }
        { _Float16* t = dc_h; dc_h = da_h; da_h = t; t = dc_l; dc_l = da_l; da_l = t; }
        run_moe(dc, dc_h, dc_l, dec_gate_w + (size_t)l * D_ * E_, dec_gate_b + (size_t)l * E_,
                dec_w1 + (size_t)l * E_ * D_ * F_, dec_b1 + (size_t)l * E_ * F_,
                dec_w2 + (size_t)l * E_ * F_ * D_, dec_b2 + (size_t)l * E_ * D_);
        bool last = (l == L_ - 1);
        ln_add<<<NTOK, 256, 0, stream>>>(dc, aout,
            dec_ln_g + (size_t)(l * 3 + 2) * D_, dec_ln_b + (size_t)(l * 3 + 2) * D_,
            da, last ? final_h : da_h, da_l);
        { float* t = dc; dc = da; da = t; }
        { _Float16* t = dc_h; dc_h = da_h; da_h = t; t = dc_l; dc_l = da_l; da_l = t; }
    }

    // ---------------- final projection (single-pass f16 MFMA; overwrites all of d_out)
    gemm_mfma<0, false, false, 1><<<dim3(V_ / 128, NTOK / 128), 256, 0, stream>>>(
        final_h, nullptr, outwT_h, nullptr, out_b, out, nullptr, nullptr,
        NTOK, D_, V_, V_, nullptr, nullptr, nullptr, nullptr);
}

// Round 4
// 1751.856 us; speedup vs baseline: 3.3708x; 1.1952x over previous
//
#include <hip/hip_runtime.h>
#include <hip/hip_bf16.h>

#define L_ 2
#define D_ 512
#define H_ 8
#define DK_ 64
#define F_ 2048
#define E_ 8
#define V_ 32000
#define B_ 2
#define S_ 1024
#define T_ 1024
#define NTOK (B_*S_)
#define MAXPAD 5120            // per-expert 128-padded total upper bound
#define MAXRB  (MAXPAD/128)    // 40
#define QLD 1536               // fused qkv row stride

typedef unsigned short u16;
typedef _Float16 f16x8 __attribute__((ext_vector_type(8)));
typedef _Float16 f16x4 __attribute__((ext_vector_type(4)));
typedef float f32x4 __attribute__((ext_vector_type(4)));

__device__ __forceinline__ void gload16(const void* g, const void* l) {
    __builtin_amdgcn_global_load_lds(
        (const __attribute__((address_space(1))) void*)g,
        (__attribute__((address_space(3))) void*)l, 16, 0, 0);
}

__device__ __forceinline__ void split_f16(float v, _Float16& h, _Float16& l) {
    h = (_Float16)v;
    l = (_Float16)(v - (float)h);
}

// ---------------------------------------------------------------- embedding + PE (f32 + hi/lo f16)
__global__ __launch_bounds__(256) void embed_pe(const int* __restrict__ toks,
                                                const float* __restrict__ emb,
                                                float* __restrict__ o,
                                                _Float16* __restrict__ oh,
                                                _Float16* __restrict__ ol, int Slen)
{
    int n = blockIdx.x;
    int spos = n % Slen;
    int tok = toks[n];
    const float* erow = emb + (size_t)tok * D_;
    size_t rb = (size_t)n * D_;
    for (int j = threadIdx.x; j < D_; j += 256) {
        int i = j >> 1;
        float arg = (float)spos * expf(-(float)i * 0.035977892f);
        float pe = (j & 1) ? cosf(arg) : sinf(arg);
        float v = erow[j] + pe;
        o[rb + j] = v;
        _Float16 h, l; split_f16(v, h, l);
        oh[rb + j] = h; ol[rb + j] = l;
    }
}

// ---------------------------------------------------------------- weight transpose f32[K][N] -> f16 hi/lo [N][K]
template<bool WLO>
__global__ __launch_bounds__(256) void transpose_w(const float* __restrict__ in,
                                                   _Float16* __restrict__ oh,
                                                   _Float16* __restrict__ ol, int R, int C)
{
    __shared__ float t[64][65];
    size_t sb = (size_t)blockIdx.z * R * C;
    in += sb; oh += sb; if (WLO) ol += sb;
    int c0 = blockIdx.x * 64, r0 = blockIdx.y * 64;
    int tid = threadIdx.x;
    int cc = tid & 63, r4 = tid >> 6;
    #pragma unroll
    for (int p = 0; p < 16; ++p) {
        int r = p * 4 + r4;
        t[r][cc] = in[(size_t)(r0 + r) * C + c0 + cc];
    }
    __syncthreads();
    int rr = tid & 63, c4 = tid >> 6;
    #pragma unroll
    for (int p = 0; p < 16; ++p) {
        int c = p * 4 + c4;
        float v = t[rr][c];
        _Float16 h = (_Float16)v;
        oh[(size_t)(c0 + c) * R + r0 + rr] = h;
        if (WLO) ol[(size_t)(c0 + c) * R + r0 + rr] = (_Float16)(v - (float)h);
    }
}

// ---------------------------------------------------------------- MFMA GEMM
// C[M,N] = A[M,K] @ Wt[N,K]^T + bias ; split-f16 3-pass (PASSES=3) or single hi (PASSES=1)
// MODE 0 plain, 1 routed gather, 2 routed direct
// OUTMODE 0 f32, 1 hi/lo split, 2 qkv (hi/lo; cols with cbase+c>=1024 are V, written transposed to vt)
template<int MODE, bool RELU, int OUTMODE, int PASSES>
__global__ __launch_bounds__(256, 2) void gemm_mfma(
    const _Float16* __restrict__ Ah, const _Float16* __restrict__ Al,
    const _Float16* __restrict__ Wh, const _Float16* __restrict__ Wl,
    const float* __restrict__ biasbase,
    float* __restrict__ Cf, _Float16* __restrict__ Ch, _Float16* __restrict__ Cl,
    _Float16* __restrict__ vt_h, _Float16* __restrict__ vt_l, int cbase,
    int M, int Kd, int N, int ldc,
    const int* __restrict__ route_tok, const int* __restrict__ rb_expert,
    const int* __restrict__ pad_base, const int* __restrict__ counts)
{
    int row0 = blockIdx.y * 128;
    const _Float16* Wmh = Wh;
    const _Float16* Wml = Wl;
    const float* bias = biasbase;
    int vend = M;
    if (MODE != 0) {
        int total = pad_base[E_];
        if (row0 >= total) return;
        int e = rb_expert[row0 >> 7];
        vend = pad_base[e] + counts[e];
        Wmh = Wh + (size_t)e * Kd * N;
        if (PASSES == 3) Wml = Wl + (size_t)e * Kd * N;
        bias = biasbase + (size_t)e * N;
    }
    int col0 = blockIdx.x * 128;
    int tid = threadIdx.x;
    int lane = tid & 63, w = tid >> 6;
    int wm = w >> 1, wn = w & 1;

    __shared__ _Float16 lds[(PASSES == 3 ? 4 : 2) * 8192];
    _Float16* lAh = lds;
    _Float16* lBh = lds + 8192;
    _Float16* lAl = (PASSES == 3) ? lds + 16384 : nullptr;
    _Float16* lBl = (PASSES == 3) ? lds + 24576 : nullptr;

    int srow8 = lane >> 3;
    int q8 = lane & 7;
    size_t aoff[4], boff[4];
    #pragma unroll
    for (int j = 0; j < 4; ++j) {
        int m = w * 32 + j * 8 + srow8;
        int gr = row0 + m;
        int ar = (MODE == 1) ? route_tok[gr] : gr;
        int sslot = (q8 ^ (m & 7)) << 3;
        aoff[j] = (size_t)ar * Kd + sslot;
        boff[j] = (size_t)(col0 + m) * Kd + sslot;
    }

    f32x4 zero4 = {0.f, 0.f, 0.f, 0.f};
    f32x4 acc[4][4];
    #pragma unroll
    for (int i = 0; i < 4; ++i)
        #pragma unroll
        for (int j = 0; j < 4; ++j) acc[i][j] = zero4;

    int lm = lane & 15, kg = lane >> 4;

    for (int k0 = 0; k0 < Kd; k0 += 64) {
        #pragma unroll
        for (int j = 0; j < 4; ++j) {
            int lb = (w * 32 + j * 8) * 64;
            gload16(Ah + aoff[j] + k0, lAh + lb);
            gload16(Wmh + boff[j] + k0, lBh + lb);
            if (PASSES == 3) {
                gload16(Al + aoff[j] + k0, lAl + lb);
                gload16(Wml + boff[j] + k0, lBl + lb);
            }
        }
        __syncthreads();
        #pragma unroll
        for (int ks = 0; ks < 2; ++ks) {
            f16x8 ah[4], bh[4];
            #pragma unroll
            for (int i = 0; i < 4; ++i) {
                int m = wm * 64 + i * 16 + lm;
                ah[i] = *(const f16x8*)&lAh[m * 64 + ((((ks << 2) + kg) ^ (m & 7)) << 3)];
                int n = wn * 64 + i * 16 + lm;
                bh[i] = *(const f16x8*)&lBh[n * 64 + ((((ks << 2) + kg) ^ (n & 7)) << 3)];
            }
            #pragma unroll
            for (int i = 0; i < 4; ++i)
                #pragma unroll
                for (int jn = 0; jn < 4; ++jn)
                    acc[i][jn] = __builtin_amdgcn_mfma_f32_16x16x32_f16(ah[i], bh[jn], acc[i][jn], 0, 0, 0);
            if (PASSES == 3) {
                f16x8 bl[4];
                #pragma unroll
                for (int i = 0; i < 4; ++i) {
                    int n = wn * 64 + i * 16 + lm;
                    bl[i] = *(const f16x8*)&lBl[n * 64 + ((((ks << 2) + kg) ^ (n & 7)) << 3)];
                }
                #pragma unroll
                for (int i = 0; i < 4; ++i)
                    #pragma unroll
                    for (int jn = 0; jn < 4; ++jn)
                        acc[i][jn] = __builtin_amdgcn_mfma_f32_16x16x32_f16(ah[i], bl[jn], acc[i][jn], 0, 0, 0);
                f16x8 al[4];
                #pragma unroll
                for (int i = 0; i < 4; ++i) {
                    int m = wm * 64 + i * 16 + lm;
                    al[i] = *(const f16x8*)&lAl[m * 64 + ((((ks << 2) + kg) ^ (m & 7)) << 3)];
                }
                #pragma unroll
                for (int i = 0; i < 4; ++i)
                    #pragma unroll
                    for (int jn = 0; jn < 4; ++jn)
                        acc[i][jn] = __builtin_amdgcn_mfma_f32_16x16x32_f16(al[i], bh[jn], acc[i][jn], 0, 0, 0);
            }
        }
        __syncthreads();
    }

    // epilogue: C/D layout col=lane&15, row=(lane>>4)*4+reg
    float bv[4];
    #pragma unroll
    for (int jn = 0; jn < 4; ++jn) bv[jn] = bias[col0 + wn * 64 + jn * 16 + lm];
    int rowb = row0 + wm * 64 + (lane >> 4) * 4;

    if (OUTMODE == 2 && (col0 + cbase) >= 1024) {
        // V columns: write transposed hi/lo to vt[(b*8+h)*64+d][q]
        #pragma unroll
        for (int i = 0; i < 4; ++i) {
            int row = rowb + i * 16;
            int b = row >> 10, q = row & 1023;
            #pragma unroll
            for (int jn = 0; jn < 4; ++jn) {
                int vcol = col0 + cbase - 1024 + wn * 64 + jn * 16 + lm;
                int hh = vcol >> 6, dd = vcol & 63;
                f16x4 hv, lv;
                #pragma unroll
                for (int r = 0; r < 4; ++r) {
                    float v = acc[i][jn][r] + bv[jn];
                    _Float16 x1, x2; split_f16(v, x1, x2);
                    hv[r] = x1; lv[r] = x2;
                }
                size_t vtoff = ((size_t)((b << 3) + hh) * 64 + dd) * 1024 + q;
                *(f16x4*)&vt_h[vtoff] = hv;
                *(f16x4*)&vt_l[vtoff] = lv;
            }
        }
        return;
    }

    #pragma unroll
    for (int i = 0; i < 4; ++i) {
        #pragma unroll
        for (int r = 0; r < 4; ++r) {
            int row = rowb + i * 16 + r;
            if (MODE != 0 && row >= vend) continue;
            #pragma unroll
            for (int jn = 0; jn < 4; ++jn) {
                float v = acc[i][jn][r] + bv[jn];
                if (RELU) v = fmaxf(v, 0.f);
                int c = col0 + wn * 64 + jn * 16 + lm;
                if (OUTMODE == 0) {
                    Cf[(size_t)row * ldc + c] = v;
                } else {
                    _Float16 h, l; split_f16(v, h, l);
                    Ch[(size_t)row * ldc + cbase + c] = h;
                    Cl[(size_t)row * ldc + cbase + c] = l;
                }
            }
        }
    }
}

// ---------------------------------------------------------------- MFMA attention scores (split-f16 3-pass)
// scores[bh,q,k] = (Q.K)/8 masked
template<int CAUSAL>
__global__ __launch_bounds__(256, 2) void attn_scores_mfma(
    const _Float16* __restrict__ qh, const _Float16* __restrict__ ql,
    const int* __restrict__ toks, float* __restrict__ scores)
{
    int bh = blockIdx.z, b = bh >> 3, h = bh & 7;
    int q0 = blockIdx.y * 128, k0 = blockIdx.x * 128;
    int tid = threadIdx.x, lane = tid & 63, w = tid >> 6;
    int wm = w >> 1, wn = w & 1;
    float* srow = scores + (size_t)bh * S_ * S_;
    if (CAUSAL && k0 > q0 + 127) {
        float4 m4 = {-1e9f, -1e9f, -1e9f, -1e9f};
        #pragma unroll
        for (int i = 0; i < 16; ++i) {
            int idx = tid + 256 * i;
            int r = idx >> 5, c = (idx & 31) << 2;
            *(float4*)&srow[(size_t)(q0 + r) * S_ + k0 + c] = m4;
        }
        return;
    }
    __shared__ _Float16 lds[32768];
    _Float16* lQh = lds;
    _Float16* lKh = lds + 8192;
    _Float16* lQl = lds + 16384;
    _Float16* lKl = lds + 24576;
    size_t base = (size_t)b * S_ * QLD + h * DK_;
    const _Float16* Qh = qh + base;
    const _Float16* Kh = qh + base + 512;
    const _Float16* Qlp = ql + base;
    const _Float16* Klp = ql + base + 512;
    int srow8 = lane >> 3, q8 = lane & 7;
    #pragma unroll
    for (int j = 0; j < 4; ++j) {
        int m = w * 32 + j * 8 + srow8;
        int sslot = (q8 ^ (m & 7)) << 3;
        int lb = (w * 32 + j * 8) * 64;
        gload16(Qh + (size_t)(q0 + m) * QLD + sslot, lQh + lb);
        gload16(Kh + (size_t)(k0 + m) * QLD + sslot, lKh + lb);
        gload16(Qlp + (size_t)(q0 + m) * QLD + sslot, lQl + lb);
        gload16(Klp + (size_t)(k0 + m) * QLD + sslot, lKl + lb);
    }
    __syncthreads();
    f32x4 zero4 = {0.f, 0.f, 0.f, 0.f};
    f32x4 acc[4][4];
    #pragma unroll
    for (int i = 0; i < 4; ++i)
        #pragma unroll
        for (int j = 0; j < 4; ++j) acc[i][j] = zero4;
    int lm = lane & 15, kg = lane >> 4;
    #pragma unroll
    for (int ks = 0; ks < 2; ++ks) {
        f16x8 ah[4], bh[4], al[4], bl[4];
        #pragma unroll
        for (int i = 0; i < 4; ++i) {
            int m = wm * 64 + i * 16 + lm;
            int so = m * 64 + ((((ks << 2) + kg) ^ (m & 7)) << 3);
            ah[i] = *(const f16x8*)&lQh[so];
            al[i] = *(const f16x8*)&lQl[so];
            int n = wn * 64 + i * 16 + lm;
            int sn = n * 64 + ((((ks << 2) + kg) ^ (n & 7)) << 3);
            bh[i] = *(const f16x8*)&lKh[sn];
            bl[i] = *(const f16x8*)&lKl[sn];
        }
        #pragma unroll
        for (int i = 0; i < 4; ++i)
            #pragma unroll
            for (int jn = 0; jn < 4; ++jn) {
                acc[i][jn] = __builtin_amdgcn_mfma_f32_16x16x32_f16(ah[i], bh[jn], acc[i][jn], 0, 0, 0);
                acc[i][jn] = __builtin_amdgcn_mfma_f32_16x16x32_f16(ah[i], bl[jn], acc[i][jn], 0, 0, 0);
                acc[i][jn] = __builtin_amdgcn_mfma_f32_16x16x32_f16(al[i], bh[jn], acc[i][jn], 0, 0, 0);
            }
    }
    int rowb = wm * 64 + (lane >> 4) * 4;
    #pragma unroll
    for (int i = 0; i < 4; ++i) {
        #pragma unroll
        for (int r = 0; r < 4; ++r) {
            int qi = q0 + rowb + i * 16 + r;
            #pragma unroll
            for (int jn = 0; jn < 4; ++jn) {
                int ki = k0 + wn * 64 + jn * 16 + lm;
                bool keep = (toks[b * S_ + ki] != 0) && (!CAUSAL || ki <= qi);
                srow[(size_t)qi * S_ + ki] = keep ? acc[i][jn][r] * 0.125f : -1e9f;
            }
        }
    }
}

// ---------------------------------------------------------------- row softmax -> P hi/lo f16
__global__ __launch_bounds__(256) void softmax_rows(const float* __restrict__ s,
                                                    _Float16* __restrict__ ph,
                                                    _Float16* __restrict__ pl)
{
    const float* p = s + (size_t)blockIdx.x * 1024;
    int tid = threadIdx.x;
    float4 v = ((const float4*)p)[tid];
    float m = fmaxf(fmaxf(v.x, v.y), fmaxf(v.z, v.w));
    for (int off = 32; off; off >>= 1) m = fmaxf(m, __shfl_down(m, off));
    __shared__ float red[8];
    int lane = tid & 63, wid = tid >> 6;
    if (!lane) red[wid] = m;
    __syncthreads();
    if (!tid) red[4] = fmaxf(fmaxf(red[0], red[1]), fmaxf(red[2], red[3]));
    __syncthreads();
    m = red[4];
    v.x = expf(v.x - m); v.y = expf(v.y - m); v.z = expf(v.z - m); v.w = expf(v.w - m);
    float su = v.x + v.y + v.z + v.w;
    for (int off = 32; off; off >>= 1) su += __shfl_down(su, off);
    if (!lane) red[wid] = su;
    __syncthreads();
    if (!tid) red[5] = red[0] + red[1] + red[2] + red[3];
    __syncthreads();
    float inv = 1.0f / red[5];
    f16x4 h4, l4;
    float pv0 = v.x * inv, pv1 = v.y * inv, pv2 = v.z * inv, pv3 = v.w * inv;
    _Float16 hh, ll;
    split_f16(pv0, hh, ll); h4[0] = hh; l4[0] = ll;
    split_f16(pv1, hh, ll); h4[1] = hh; l4[1] = ll;
    split_f16(pv2, hh, ll); h4[2] = hh; l4[2] = ll;
    split_f16(pv3, hh, ll); h4[3] = hh; l4[3] = ll;
    size_t ob = (size_t)blockIdx.x * 1024 + tid * 4;
    *(f16x4*)&ph[ob] = h4;
    *(f16x4*)&pl[ob] = l4;
}

// ---------------------------------------------------------------- MFMA PV (split 3-pass) -> ctx hi/lo
__global__ __launch_bounds__(256, 2) void attn_pv_mfma(
    const _Float16* __restrict__ ph, const _Float16* __restrict__ pl,
    const _Float16* __restrict__ vth, const _Float16* __restrict__ vtl,
    _Float16* __restrict__ ch, _Float16* __restrict__ cl)
{
    int bh = blockIdx.y, b = bh >> 3, h = bh & 7;
    int q0 = blockIdx.x * 128;
    int tid = threadIdx.x, lane = tid & 63, w = tid >> 6;
    __shared__ _Float16 lds[24576];
    _Float16* pAh = lds;
    _Float16* pAl = lds + 8192;
    _Float16* vBh = lds + 16384;
    _Float16* vBl = lds + 20480;
    const _Float16* Pbh = ph + (size_t)bh * S_ * S_;
    const _Float16* Pbl = pl + (size_t)bh * S_ * S_;
    const _Float16* Vbh = vth + (size_t)bh * 64 * 1024;
    const _Float16* Vbl = vtl + (size_t)bh * 64 * 1024;
    f32x4 zero4 = {0.f, 0.f, 0.f, 0.f};
    f32x4 acc[2][4];
    #pragma unroll
    for (int i = 0; i < 2; ++i)
        #pragma unroll
        for (int j = 0; j < 4; ++j) acc[i][j] = zero4;
    int srow8 = lane >> 3, q8 = lane & 7, lm = lane & 15, kg = lane >> 4;

    for (int k0 = 0; k0 < S_; k0 += 64) {
        #pragma unroll
        for (int j = 0; j < 4; ++j) {
            int m = w * 32 + j * 8 + srow8;
            int sslot = (q8 ^ (m & 7)) << 3;
            int lb = (w * 32 + j * 8) * 64;
            gload16(Pbh + (size_t)(q0 + m) * S_ + k0 + sslot, pAh + lb);
            gload16(Pbl + (size_t)(q0 + m) * S_ + k0 + sslot, pAl + lb);
        }
        #pragma unroll
        for (int j = 0; j < 2; ++j) {
            int n = w * 16 + j * 8 + srow8;
            int sslot = (q8 ^ (n & 7)) << 3;
            int lb = (w * 16 + j * 8) * 64;
            gload16(Vbh + (size_t)n * 1024 + k0 + sslot, vBh + lb);
            gload16(Vbl + (size_t)n * 1024 + k0 + sslot, vBl + lb);
        }
        __syncthreads();
        #pragma unroll
        for (int ks = 0; ks < 2; ++ks) {
            f16x8 pa[2], paL[2], vb[4], vbL[4];
            #pragma unroll
            for (int i = 0; i < 2; ++i) {
                int m = w * 32 + i * 16 + lm;
                int so = m * 64 + ((((ks << 2) + kg) ^ (m & 7)) << 3);
                pa[i] = *(const f16x8*)&pAh[so];
                paL[i] = *(const f16x8*)&pAl[so];
            }
            #pragma unroll
            for (int jn = 0; jn < 4; ++jn) {
                int n = jn * 16 + lm;
                int sn = n * 64 + ((((ks << 2) + kg) ^ (n & 7)) << 3);
                vb[jn] = *(const f16x8*)&vBh[sn];
                vbL[jn] = *(const f16x8*)&vBl[sn];
            }
            #pragma unroll
            for (int i = 0; i < 2; ++i)
                #pragma unroll
                for (int jn = 0; jn < 4; ++jn) {
                    acc[i][jn] = __builtin_amdgcn_mfma_f32_16x16x32_f16(pa[i], vb[jn], acc[i][jn], 0, 0, 0);
                    acc[i][jn] = __builtin_amdgcn_mfma_f32_16x16x32_f16(pa[i], vbL[jn], acc[i][jn], 0, 0, 0);
                    acc[i][jn] = __builtin_amdgcn_mfma_f32_16x16x32_f16(paL[i], vb[jn], acc[i][jn], 0, 0, 0);
                }
        }
        __syncthreads();
    }
    #pragma unroll
    for (int i = 0; i < 2; ++i) {
        #pragma unroll
        for (int r = 0; r < 4; ++r) {
            int q = q0 + w * 32 + i * 16 + (lane >> 4) * 4 + r;
            size_t rbase = (size_t)(b * S_ + q) * D_ + h * DK_;
            #pragma unroll
            for (int jn = 0; jn < 4; ++jn) {
                int d = jn * 16 + lm;
                _Float16 hh, ll; split_f16(acc[i][jn][r], hh, ll);
                ch[rbase + d] = hh; cl[rbase + d] = ll;
            }
        }
    }
}

// ---------------------------------------------------------------- residual + LayerNorm (f32 + hi/lo)
__global__ __launch_bounds__(256) void ln_add(const float* __restrict__ x,
                                              const float* __restrict__ r,
                                              const float* __restrict__ g,
                                              const float* __restrict__ be,
                                              float* __restrict__ o,
                                              _Float16* __restrict__ oh,
                                              _Float16* __restrict__ ol)
{
    int row = blockIdx.x;
    const float* xr = x + (size_t)row * D_;
    const float* rr = r + (size_t)row * D_;
    int tid = threadIdx.x;
    float v0 = xr[tid] + rr[tid];
    float v1 = xr[tid + 256] + rr[tid + 256];
    float s = v0 + v1;
    for (int off = 32; off; off >>= 1) s += __shfl_down(s, off);
    __shared__ float red[8];
    int lane = tid & 63, wid = tid >> 6;
    if (!lane) red[wid] = s;
    __syncthreads();
    if (!tid) red[4] = (red[0] + red[1] + red[2] + red[3]) * (1.0f / 512.0f);
    __syncthreads();
    float m = red[4];
    float d0 = v0 - m, d1 = v1 - m;
    s = d0 * d0 + d1 * d1;
    for (int off = 32; off; off >>= 1) s += __shfl_down(s, off);
    if (!lane) red[wid] = s;
    __syncthreads();
    if (!tid) red[5] = rsqrtf((red[0] + red[1] + red[2] + red[3]) * (1.0f / 512.0f) + 1e-5f);
    __syncthreads();
    float rstd = red[5];
    size_t rb = (size_t)row * D_;
    float y0 = d0 * rstd * g[tid] + be[tid];
    float y1 = d1 * rstd * g[tid + 256] + be[tid + 256];
    o[rb + tid] = y0; o[rb + tid + 256] = y1;
    _Float16 h, l;
    split_f16(y0, h, l); oh[rb + tid] = h; ol[rb + tid] = l;
    split_f16(y1, h, l); oh[rb + tid + 256] = h; ol[rb + tid + 256] = l;
}

// ---------------------------------------------------------------- MoE gate
__global__ __launch_bounds__(256) void gate_logits(const float* __restrict__ xf,
                                                   const float* __restrict__ gw,
                                                   const float* __restrict__ gb,
                                                   float* __restrict__ lg)
{
    int id = blockIdx.x * 256 + threadIdx.x;
    if (id >= NTOK * E_) return;
    int e = id & 7, n = id >> 3;
    const float* x = xf + (size_t)n * D_;
    float s = gb[e];
    for (int d = 0; d < D_; ++d) s += x[d] * gw[d * E_ + e];
    lg[id] = s;
}

__global__ __launch_bounds__(256) void gate_top2(const float* __restrict__ lg,
                                                 float* __restrict__ topv,
                                                 int* __restrict__ topi)
{
    int n = blockIdx.x * 256 + threadIdx.x;
    if (n >= NTOK) return;
    float l[E_], p[E_];
    float m = -1e30f;
    #pragma unroll
    for (int e = 0; e < E_; ++e) { l[e] = lg[n * E_ + e]; m = fmaxf(m, l[e]); }
    float su = 0.f;
    #pragma unroll
    for (int e = 0; e < E_; ++e) { p[e] = expf(l[e] - m); su += p[e]; }
    float inv = 1.0f / su;
    int i1 = 0; float v1 = p[0];
    #pragma unroll
    for (int e = 1; e < E_; ++e) if (p[e] > v1) { v1 = p[e]; i1 = e; }
    int i2 = -1; float v2 = -1.f;
    #pragma unroll
    for (int e = 0; e < E_; ++e) if (e != i1 && p[e] > v2) { v2 = p[e]; i2 = e; }
    topv[n * 2] = v1 * inv; topv[n * 2 + 1] = v2 * inv;
    topi[n * 2] = i1;       topi[n * 2 + 1] = i2;
}

// ---------------------------------------------------------------- parallel deterministic routing
__global__ __launch_bounds__(1024) void build_routes(const int* __restrict__ topi,
                                                     int* __restrict__ route_tok,
                                                     int* __restrict__ route_row,
                                                     int* __restrict__ counts,
                                                     int* __restrict__ pad_base,
                                                     int* __restrict__ rb_expert)
{
    __shared__ int eid[NTOK * 2];
    __shared__ unsigned short chist[256][8];
    __shared__ int pb[E_ + 1];
    __shared__ int cnt[E_];
    int t = threadIdx.x;
    #pragma unroll
    for (int i = 0; i < 4; ++i) eid[t + 1024 * i] = topi[t + 1024 * i];
    #pragma unroll
    for (int g = 0; g < 5; ++g) route_tok[t + 1024 * g] = 0;
    __syncthreads();

    if (t < 256) {
        int r[16];
        #pragma unroll
        for (int i = 0; i < 16; ++i) r[i] = eid[t * 16 + i];
        #pragma unroll
        for (int e = 0; e < 8; ++e) {
            int h = 0;
            #pragma unroll
            for (int i = 0; i < 16; ++i) h += (r[i] == e) ? 1 : 0;
            chist[t][e] = (unsigned short)h;
        }
    }
    __syncthreads();

    if (t < 8) {
        int run = 0;
        for (int c = 0; c < 256; ++c) {
            int v = chist[c][t];
            chist[c][t] = (unsigned short)run;
            run += v;
        }
        cnt[t] = run;
        counts[t] = run;
    }
    __syncthreads();

    if (t == 0) {
        int pad = 0;
        for (int e = 0; e < 8; ++e) {
            pb[e] = pad;
            pad_base[e] = pad;
            int nb = (cnt[e] + 127) >> 7;
            for (int rb = 0; rb < nb; ++rb) rb_expert[(pad >> 7) + rb] = e;
            pad += nb << 7;
        }
        pb[8] = pad;
        pad_base[8] = pad;
    }
    __syncthreads();

    if (t < 256) {
        int r[16];
        #pragma unroll
        for (int i = 0; i < 16; ++i) r[i] = eid[t * 16 + i];
        #pragma unroll
        for (int e = 0; e < 8; ++e) {
            int o = pb[e] + chist[t][e];
            #pragma unroll
            for (int i = 0; i < 16; ++i) {
                if (r[i] == e) {
                    int slot = t * 16 + i;
                    route_tok[o] = slot >> 1;
                    route_row[slot] = o;
                    o++;
                }
            }
        }
    }
}

__global__ __launch_bounds__(256) void moe_combine(const float* __restrict__ eo,
                                                   const float* __restrict__ topv,
                                                   const int* __restrict__ route_row,
                                                   float* __restrict__ f)
{
    int n = blockIdx.x;
    int r0 = route_row[n * 2], r1 = route_row[n * 2 + 1];
    float w0 = topv[n * 2], w1 = topv[n * 2 + 1];
    const float* e0 = eo + (size_t)r0 * D_;
    const float* e1 = eo + (size_t)r1 * D_;
    float* fr = f + (size_t)n * D_;
    for (int j = threadIdx.x; j < D_; j += 256)
        fr[j] = w0 * e0[j] + w1 * e1[j];
}

// ================================================================ host orchestration
extern "C" void kernel_launch(void* const* d_in, const int* in_sizes, int n_in,
                              void* d_out, int out_size, void* d_ws, size_t ws_size,
                              hipStream_t stream)
{
    const int*   src        = (const int*)  d_in[0];
    const int*   tgt        = (const int*)  d_in[1];
    const float* enc_emb    = (const float*)d_in[2];
    const float* dec_emb    = (const float*)d_in[3];
    const float* enc_attn_w = (const float*)d_in[4];
    const float* enc_attn_b = (const float*)d_in[5];
    const float* enc_ln_g   = (const float*)d_in[6];
    const float* enc_ln_b   = (const float*)d_in[7];
    const float* enc_gate_w = (const float*)d_in[8];
    const float* enc_gate_b = (const float*)d_in[9];
    const float* enc_w1     = (const float*)d_in[10];
    const float* enc_b1     = (const float*)d_in[11];
    const float* enc_w2     = (const float*)d_in[12];
    const float* enc_b2     = (const float*)d_in[13];
    const float* dec_sa_w   = (const float*)d_in[14];
    const float* dec_sa_b   = (const float*)d_in[15];
    const float* dec_ca_w   = (const float*)d_in[16];
    const float* dec_ca_b   = (const float*)d_in[17];
    const float* dec_ln_g   = (const float*)d_in[18];
    const float* dec_ln_b   = (const float*)d_in[19];
    const float* dec_gate_w = (const float*)d_in[20];
    const float* dec_gate_b = (const float*)d_in[21];
    const float* dec_w1     = (const float*)d_in[22];
    const float* dec_b1     = (const float*)d_in[23];
    const float* dec_w2     = (const float*)d_in[24];
    const float* dec_b2     = (const float*)d_in[25];
    const float* out_w      = (const float*)d_in[26];
    const float* out_b      = (const float*)d_in[27];
    float* out = (float*)d_out;

    // ---- d_out scratch (dead until final GEMM overwrites all of it)
    char* ob = (char*)d_out;
    size_t oc = 0;
    auto dalloc = [&](size_t bytes) { char* p = ob + oc; oc += (bytes + 255) & ~(size_t)255; return p; };
    float*    scores = (float*)dalloc((size_t)16 * S_ * S_ * 4);          // 67.1 MB
    _Float16* ph     = (_Float16*)dalloc((size_t)16 * S_ * S_ * 2);       // 33.5 MB
    _Float16* pl     = (_Float16*)dalloc((size_t)16 * S_ * S_ * 2);       // 33.5 MB
    _Float16* qkv_h  = (_Float16*)dalloc((size_t)NTOK * QLD * 2);
    _Float16* qkv_l  = (_Float16*)dalloc((size_t)NTOK * QLD * 2);
    _Float16* vt_h   = (_Float16*)dalloc((size_t)16 * 64 * 1024 * 2);
    _Float16* vt_l   = (_Float16*)dalloc((size_t)16 * 64 * 1024 * 2);
    float* aout  = (float*)dalloc((size_t)NTOK * D_ * 4);
    _Float16* ctx_h = (_Float16*)dalloc((size_t)NTOK * D_ * 2);
    _Float16* ctx_l = (_Float16*)dalloc((size_t)NTOK * D_ * 2);
    _Float16* encA_h = (_Float16*)dalloc((size_t)L_ * 4 * D_ * D_ * 2);
    _Float16* encA_l = (_Float16*)dalloc((size_t)L_ * 4 * D_ * D_ * 2);
    _Float16* saA_h  = (_Float16*)dalloc((size_t)L_ * 4 * D_ * D_ * 2);
    _Float16* saA_l  = (_Float16*)dalloc((size_t)L_ * 4 * D_ * D_ * 2);
    _Float16* caA_h  = (_Float16*)dalloc((size_t)L_ * 4 * D_ * D_ * 2);
    _Float16* caA_l  = (_Float16*)dalloc((size_t)L_ * 4 * D_ * D_ * 2);
    float* xA = (float*)dalloc((size_t)NTOK * D_ * 4);
    float* xB = (float*)dalloc((size_t)NTOK * D_ * 4);
    float* yA = (float*)dalloc((size_t)NTOK * D_ * 4);
    float* yB = (float*)dalloc((size_t)NTOK * D_ * 4);
    _Float16* xA_h = (_Float16*)dalloc((size_t)NTOK * D_ * 2);
    _Float16* xA_l = (_Float16*)dalloc((size_t)NTOK * D_ * 2);
    _Float16* xB_h = (_Float16*)dalloc((size_t)NTOK * D_ * 2);
    _Float16* xB_l = (_Float16*)dalloc((size_t)NTOK * D_ * 2);
    _Float16* yA_h = (_Float16*)dalloc((size_t)NTOK * D_ * 2);
    _Float16* yA_l = (_Float16*)dalloc((size_t)NTOK * D_ * 2);
    _Float16* yB_h = (_Float16*)dalloc((size_t)NTOK * D_ * 2);
    _Float16* yB_l = (_Float16*)dalloc((size_t)NTOK * D_ * 2);

    // ---- ws scratch (~155 MB; harness fill shows ws ~1 GB)
    char* wp = (char*)d_ws;
    size_t wc = 0;
    auto walloc = [&](size_t bytes) { char* p = wp + wc; wc += (bytes + 255) & ~(size_t)255; return p; };
    _Float16* outwT_h = (_Float16*)walloc((size_t)V_ * D_ * 2);
    _Float16* final_h = (_Float16*)walloc((size_t)NTOK * D_ * 2);
    _Float16* w1t_h   = (_Float16*)walloc((size_t)E_ * F_ * D_ * 2);
    _Float16* w1t_l   = (_Float16*)walloc((size_t)E_ * F_ * D_ * 2);
    _Float16* w2t_h   = (_Float16*)walloc((size_t)E_ * F_ * D_ * 2);
    _Float16* w2t_l   = (_Float16*)walloc((size_t)E_ * F_ * D_ * 2);
    _Float16* hbuf_h  = (_Float16*)walloc((size_t)MAXPAD * F_ * 2);
    _Float16* hbuf_l  = (_Float16*)walloc((size_t)MAXPAD * F_ * 2);
    float*    eobuf   = (float*)walloc((size_t)MAXPAD * D_ * 4);
    float* lg   = (float*)walloc((size_t)NTOK * E_ * 4);
    float* topv = (float*)walloc((size_t)NTOK * 2 * 4);
    int*   topi = (int*)  walloc((size_t)NTOK * 2 * 4);
    int*   route_tok = (int*)walloc((size_t)MAXPAD * 4);
    int*   route_row = (int*)walloc((size_t)NTOK * 2 * 4);
    int*   counts    = (int*)walloc(64);
    int*   pad_base  = (int*)walloc(64);
    int*   rb_expert = (int*)walloc((size_t)64 * 4);

    // ---- weight transposes (once per launch)
    transpose_w<true><<<dim3(8, 8, 8), 256, 0, stream>>>(enc_attn_w, encA_h, encA_l, D_, D_);
    transpose_w<true><<<dim3(8, 8, 8), 256, 0, stream>>>(dec_sa_w, saA_h, saA_l, D_, D_);
    transpose_w<true><<<dim3(8, 8, 8), 256, 0, stream>>>(dec_ca_w, caA_h, caA_l, D_, D_);
    transpose_w<false><<<dim3(500, 8, 1), 256, 0, stream>>>(out_w, outwT_h, nullptr, D_, V_);

    auto run_mha = [&](const _Float16* q_h, const _Float16* q_l,
                       const _Float16* kv_h, const _Float16* kv_l,
                       const _Float16* wT_h, const _Float16* wT_l, const float* bt,
                       const int* ktoks, int causal, bool fused) {
        if (fused) {
            gemm_mfma<0, false, 2, 3><<<dim3(12, 16), 256, 0, stream>>>(
                q_h, q_l, wT_h, wT_l, bt, nullptr, qkv_h, qkv_l, vt_h, vt_l, 0,
                NTOK, D_, 1536, QLD, nullptr, nullptr, nullptr, nullptr);
        } else {
            gemm_mfma<0, false, 1, 3><<<dim3(4, 16), 256, 0, stream>>>(
                q_h, q_l, wT_h, wT_l, bt, nullptr, qkv_h, qkv_l, nullptr, nullptr, 0,
                NTOK, D_, 512, QLD, nullptr, nullptr, nullptr, nullptr);
            gemm_mfma<0, false, 2, 3><<<dim3(8, 16), 256, 0, stream>>>(
                kv_h, kv_l, wT_h + (size_t)D_ * D_, wT_l + (size_t)D_ * D_, bt + D_,
                nullptr, qkv_h, qkv_l, vt_h, vt_l, 512,
                NTOK, D_, 1024, QLD, nullptr, nullptr, nullptr, nullptr);
        }
        if (causal)
            attn_scores_mfma<1><<<dim3(8, 8, 16), 256, 0, stream>>>(qkv_h, qkv_l, ktoks, scores);
        else
            attn_scores_mfma<0><<<dim3(8, 8, 16), 256, 0, stream>>>(qkv_h, qkv_l, ktoks, scores);
        softmax_rows<<<16 * 1024, 256, 0, stream>>>(scores, ph, pl);
        attn_pv_mfma<<<dim3(8, 16), 256, 0, stream>>>(ph, pl, vt_h, vt_l, ctx_h, ctx_l);
        gemm_mfma<0, false, 0, 3><<<dim3(4, 16), 256, 0, stream>>>(
            ctx_h, ctx_l, wT_h + (size_t)3 * D_ * D_, wT_l + (size_t)3 * D_ * D_,
            bt + 3 * D_, aout, nullptr, nullptr, nullptr, nullptr, 0,
            NTOK, D_, 512, 512, nullptr, nullptr, nullptr, nullptr);
    };

    auto run_moe = [&](const float* x, const _Float16* x_h, const _Float16* x_l,
                       const float* gwp, const float* gbp,
                       const float* w1p, const float* b1p,
                       const float* w2p, const float* b2p) {
        gate_logits<<<NTOK * E_ / 256, 256, 0, stream>>>(x, gwp, gbp, lg);
        gate_top2<<<NTOK / 256, 256, 0, stream>>>(lg, topv, topi);
        build_routes<<<1, 1024, 0, stream>>>(topi, route_tok, route_row, counts, pad_base, rb_expert);
        transpose_w<true><<<dim3(32, 8, 8), 256, 0, stream>>>(w1p, w1t_h, w1t_l, D_, F_);
        transpose_w<true><<<dim3(8, 32, 8), 256, 0, stream>>>(w2p, w2t_h, w2t_l, F_, D_);
        gemm_mfma<1, true, 1, 3><<<dim3(F_ / 128, MAXRB), 256, 0, stream>>>(
            x_h, x_l, w1t_h, w1t_l, b1p, nullptr, hbuf_h, hbuf_l, nullptr, nullptr, 0,
            0, D_, F_, F_, route_tok, rb_expert, pad_base, counts);
        gemm_mfma<2, false, 0, 3><<<dim3(D_ / 128, MAXRB), 256, 0, stream>>>(
            hbuf_h, hbuf_l, w2t_h, w2t_l, b2p, eobuf, nullptr, nullptr, nullptr, nullptr, 0,
            0, F_, D_, D_, route_tok, rb_expert, pad_base, counts);
        moe_combine<<<NTOK, 256, 0, stream>>>(eobuf, topv, route_row, aout);
    };

    // ---------------- encoder ----------------
    embed_pe<<<B_ * S_, 256, 0, stream>>>(src, enc_emb, xA, xA_h, xA_l, S_);
    float* cur = xA; float* alt = xB;
    _Float16* cur_h = xA_h; _Float16* cur_l = xA_l;
    _Float16* alt_h = xB_h; _Float16* alt_l = xB_l;
    for (int l = 0; l < L_; ++l) {
        run_mha(cur_h, cur_l, nullptr, nullptr,
                encA_h + (size_t)l * 4 * D_ * D_, encA_l + (size_t)l * 4 * D_ * D_,
                enc_attn_b + (size_t)l * 4 * D_, src, 0, true);
        ln_add<<<NTOK, 256, 0, stream>>>(cur, aout,
            enc_ln_g + (size_t)(l * 2 + 0) * D_, enc_ln_b + (size_t)(l * 2 + 0) * D_,
            alt, alt_h, alt_l);
        { float* t = cur; cur = alt; alt = t; }
        { _Float16* t = cur_h; cur_h = alt_h; alt_h = t; t = cur_l; cur_l = alt_l; alt_l = t; }
        run_moe(cur, cur_h, cur_l, enc_gate_w + (size_t)l * D_ * E_, enc_gate_b + (size_t)l * E_,
                enc_w1 + (size_t)l * E_ * D_ * F_, enc_b1 + (size_t)l * E_ * F_,
                enc_w2 + (size_t)l * E_ * F_ * D_, enc_b2 + (size_t)l * E_ * D_);
        ln_add<<<NTOK, 256, 0, stream>>>(cur, aout,
            enc_ln_g + (size_t)(l * 2 + 1) * D_, enc_ln_b + (size_t)(l * 2 + 1) * D_,
            alt, alt_h, alt_l);
        { float* t = cur; cur = alt; alt = t; }
        { _Float16* t = cur_h; cur_h = alt_h; alt_h = t; t = cur_l; cur_l = alt_l; alt_l = t; }
    }
    _Float16* enc_h = cur_h; _Float16* enc_l = cur_l;

    // ---------------- decoder ----------------
    embed_pe<<<B_ * T_, 256, 0, stream>>>(tgt, dec_emb, yA, yA_h, yA_l, T_);
    float* dc = yA; float* da = yB;
    _Float16* dc_h = yA_h; _Float16* dc_l = yA_l;
    _Float16* da_h = yB_h; _Float16* da_l = yB_l;
    for (int l = 0; l < L_; ++l) {
        run_mha(dc_h, dc_l, nullptr, nullptr,
                saA_h + (size_t)l * 4 * D_ * D_, saA_l + (size_t)l * 4 * D_ * D_,
                dec_sa_b + (size_t)l * 4 * D_, tgt, 1, true);
        ln_add<<<NTOK, 256, 0, stream>>>(dc, aout,
            dec_ln_g + (size_t)(l * 3 + 0) * D_, dec_ln_b + (size_t)(l * 3 + 0) * D_,
            da, da_h, da_l);
        { float* t = dc; dc = da; da = t; }
        { _Float16* t = dc_h; dc_h = da_h; da_h = t; t = dc_l; dc_l = da_l; da_l = t; }
        run_mha(dc_h, dc_l, enc_h, enc_l,
                caA_h + (size_t)l * 4 * D_ * D_, caA_l + (size_t)l * 4 * D_ * D_,
                dec_ca_b + (size_t)l * 4 * D_, src, 0, false);
        ln_add<<<NTOK, 256, 0, stream>>>(dc, aout,
            dec_ln_g + (size_t)(l * 3 + 1) * D_, dec_ln_b + (size_t)(l * 3 + 1) * D_,
            da, da_h, da_l);
        { float* t = dc; dc = da; da = t; }
        { _Float16* t = dc_h; dc_h = da_h; da_h = t; t = dc_l; dc_l = da_l; da_l = t; }
        run_moe(dc, dc_h, dc_l, dec_gate_w + (size_t)l * D_ * E_, dec_gate_b + (size_t)l * E_,
                dec_w1 + (size_t)l * E_ * D_ * F_, dec_b1 + (size_t)l * E_ * F_,
                dec_w2 + (size_t)l * E_ * F_ * D_, dec_b2 + (size_t)l * E_ * D_);
        bool last = (l == L_ - 1);
        ln_add<<<NTOK, 256, 0, stream>>>(dc, aout,
            dec_ln_g + (size_t)(l * 3 + 2) * D_, dec_ln_b + (size_t)(l * 3 + 2) * D_,
            da, last ? final_h : da_h, da_l);
        { float* t = dc; dc = da; da = t; }
        { _Float16* t = dc_h; dc_h = da_h; da_h = t; t = dc_l; dc_l = da_l; da_l = t; }
    }

    // ---------------- final projection (single-pass f16 MFMA; overwrites all of d_out)
    gemm_mfma<0, false, 0, 1><<<dim3(V_ / 128, NTOK / 128), 256, 0, stream>>>(
        final_h, nullptr, outwT_h, nullptr, out_b, out, nullptr, nullptr, nullptr, nullptr, 0,
        NTOK, D_, V_, V_, nullptr, nullptr, nullptr, nullptr);
}

// Round 5
// 1553.871 us; speedup vs baseline: 3.8003x; 1.1274x over previous
//
#include <hip/hip_runtime.h>
#include <hip/hip_bf16.h>

#define L_ 2
#define D_ 512
#define H_ 8
#define DK_ 64
#define F_ 2048
#define E_ 8
#define V_ 32000
#define B_ 2
#define S_ 1024
#define T_ 1024
#define NTOK (B_*S_)
#define MAXPAD 5120
#define MAXRB  (MAXPAD/128)
#define QLD 1536

typedef unsigned short u16;
typedef _Float16 f16x8 __attribute__((ext_vector_type(8)));
typedef _Float16 f16x4 __attribute__((ext_vector_type(4)));
typedef float f32x4 __attribute__((ext_vector_type(4)));

__device__ __forceinline__ void gload16(const void* g, const void* l) {
    __builtin_amdgcn_global_load_lds(
        (const __attribute__((address_space(1))) void*)g,
        (__attribute__((address_space(3))) void*)l, 16, 0, 0);
}

__device__ __forceinline__ void split_f16(float v, _Float16& h, _Float16& l) {
    h = (_Float16)v;
    l = (_Float16)(v - (float)h);
}

// ---------------------------------------------------------------- embedding + PE (f32 + hi/lo f16)
__global__ __launch_bounds__(256) void embed_pe(const int* __restrict__ toks,
                                                const float* __restrict__ emb,
                                                float* __restrict__ o,
                                                _Float16* __restrict__ oh,
                                                _Float16* __restrict__ ol, int Slen)
{
    int n = blockIdx.x;
    int spos = n % Slen;
    int tok = toks[n];
    const float* erow = emb + (size_t)tok * D_;
    size_t rb = (size_t)n * D_;
    for (int j = threadIdx.x; j < D_; j += 256) {
        int i = j >> 1;
        float arg = (float)spos * expf(-(float)i * 0.035977892f);
        float pe = (j & 1) ? cosf(arg) : sinf(arg);
        float v = erow[j] + pe;
        o[rb + j] = v;
        _Float16 h, l; split_f16(v, h, l);
        oh[rb + j] = h; ol[rb + j] = l;
    }
}

// ---------------------------------------------------------------- weight transpose f32[K][N] -> f16 hi/lo [N][K]
template<bool WLO>
__global__ __launch_bounds__(256) void transpose_w(const float* __restrict__ in,
                                                   _Float16* __restrict__ oh,
                                                   _Float16* __restrict__ ol, int R, int C)
{
    __shared__ float t[64][65];
    size_t sb = (size_t)blockIdx.z * R * C;
    in += sb; oh += sb; if (WLO) ol += sb;
    int c0 = blockIdx.x * 64, r0 = blockIdx.y * 64;
    int tid = threadIdx.x;
    int cc = tid & 63, r4 = tid >> 6;
    #pragma unroll
    for (int p = 0; p < 16; ++p) {
        int r = p * 4 + r4;
        t[r][cc] = in[(size_t)(r0 + r) * C + c0 + cc];
    }
    __syncthreads();
    int rr = tid & 63, c4 = tid >> 6;
    #pragma unroll
    for (int p = 0; p < 16; ++p) {
        int c = p * 4 + c4;
        float v = t[rr][c];
        _Float16 h = (_Float16)v;
        oh[(size_t)(c0 + c) * R + r0 + rr] = h;
        if (WLO) ol[(size_t)(c0 + c) * R + r0 + rr] = (_Float16)(v - (float)h);
    }
}

// ---------------------------------------------------------------- MFMA GEMM
template<int MODE, bool RELU, int OUTMODE, int PASSES>
__global__ __launch_bounds__(256, 2) void gemm_mfma(
    const _Float16* __restrict__ Ah, const _Float16* __restrict__ Al,
    const _Float16* __restrict__ Wh, const _Float16* __restrict__ Wl,
    const float* __restrict__ biasbase,
    float* __restrict__ Cf, _Float16* __restrict__ Ch, _Float16* __restrict__ Cl,
    _Float16* __restrict__ vt_h, _Float16* __restrict__ vt_l, int cbase,
    int M, int Kd, int N, int ldc,
    const int* __restrict__ route_tok, const int* __restrict__ rb_expert,
    const int* __restrict__ pad_base, const int* __restrict__ counts)
{
    int row0 = blockIdx.y * 128;
    const _Float16* Wmh = Wh;
    const _Float16* Wml = Wl;
    const float* bias = biasbase;
    int vend = M;
    if (MODE != 0) {
        int total = pad_base[E_];
        if (row0 >= total) return;
        int e = rb_expert[row0 >> 7];
        vend = pad_base[e] + counts[e];
        Wmh = Wh + (size_t)e * Kd * N;
        if (PASSES == 3) Wml = Wl + (size_t)e * Kd * N;
        bias = biasbase + (size_t)e * N;
    }
    int col0 = blockIdx.x * 128;
    int tid = threadIdx.x;
    int lane = tid & 63, w = tid >> 6;
    int wm = w >> 1, wn = w & 1;

    __shared__ _Float16 lds[(PASSES == 3 ? 4 : 2) * 8192];
    _Float16* lAh = lds;
    _Float16* lBh = lds + 8192;
    _Float16* lAl = (PASSES == 3) ? lds + 16384 : nullptr;
    _Float16* lBl = (PASSES == 3) ? lds + 24576 : nullptr;

    int srow8 = lane >> 3;
    int q8 = lane & 7;
    size_t aoff[4], boff[4];
    #pragma unroll
    for (int j = 0; j < 4; ++j) {
        int m = w * 32 + j * 8 + srow8;
        int gr = row0 + m;
        int ar = (MODE == 1) ? route_tok[gr] : gr;
        int sslot = (q8 ^ (m & 7)) << 3;
        aoff[j] = (size_t)ar * Kd + sslot;
        boff[j] = (size_t)(col0 + m) * Kd + sslot;
    }

    f32x4 zero4 = {0.f, 0.f, 0.f, 0.f};
    f32x4 acc[4][4];
    #pragma unroll
    for (int i = 0; i < 4; ++i)
        #pragma unroll
        for (int j = 0; j < 4; ++j) acc[i][j] = zero4;

    int lm = lane & 15, kg = lane >> 4;

    for (int k0 = 0; k0 < Kd; k0 += 64) {
        #pragma unroll
        for (int j = 0; j < 4; ++j) {
            int lb = (w * 32 + j * 8) * 64;
            gload16(Ah + aoff[j] + k0, lAh + lb);
            gload16(Wmh + boff[j] + k0, lBh + lb);
            if (PASSES == 3) {
                gload16(Al + aoff[j] + k0, lAl + lb);
                gload16(Wml + boff[j] + k0, lBl + lb);
            }
        }
        __syncthreads();
        #pragma unroll
        for (int ks = 0; ks < 2; ++ks) {
            f16x8 ah[4], bh[4];
            #pragma unroll
            for (int i = 0; i < 4; ++i) {
                int m = wm * 64 + i * 16 + lm;
                ah[i] = *(const f16x8*)&lAh[m * 64 + ((((ks << 2) + kg) ^ (m & 7)) << 3)];
                int n = wn * 64 + i * 16 + lm;
                bh[i] = *(const f16x8*)&lBh[n * 64 + ((((ks << 2) + kg) ^ (n & 7)) << 3)];
            }
            #pragma unroll
            for (int i = 0; i < 4; ++i)
                #pragma unroll
                for (int jn = 0; jn < 4; ++jn)
                    acc[i][jn] = __builtin_amdgcn_mfma_f32_16x16x32_f16(ah[i], bh[jn], acc[i][jn], 0, 0, 0);
            if (PASSES == 3) {
                f16x8 bl[4];
                #pragma unroll
                for (int i = 0; i < 4; ++i) {
                    int n = wn * 64 + i * 16 + lm;
                    bl[i] = *(const f16x8*)&lBl[n * 64 + ((((ks << 2) + kg) ^ (n & 7)) << 3)];
                }
                #pragma unroll
                for (int i = 0; i < 4; ++i)
                    #pragma unroll
                    for (int jn = 0; jn < 4; ++jn)
                        acc[i][jn] = __builtin_amdgcn_mfma_f32_16x16x32_f16(ah[i], bl[jn], acc[i][jn], 0, 0, 0);
                f16x8 al[4];
                #pragma unroll
                for (int i = 0; i < 4; ++i) {
                    int m = wm * 64 + i * 16 + lm;
                    al[i] = *(const f16x8*)&lAl[m * 64 + ((((ks << 2) + kg) ^ (m & 7)) << 3)];
                }
                #pragma unroll
                for (int i = 0; i < 4; ++i)
                    #pragma unroll
                    for (int jn = 0; jn < 4; ++jn)
                        acc[i][jn] = __builtin_amdgcn_mfma_f32_16x16x32_f16(al[i], bh[jn], acc[i][jn], 0, 0, 0);
            }
        }
        __syncthreads();
    }

    float bv[4];
    #pragma unroll
    for (int jn = 0; jn < 4; ++jn) bv[jn] = bias[col0 + wn * 64 + jn * 16 + lm];
    int rowb = row0 + wm * 64 + (lane >> 4) * 4;

    if (OUTMODE == 2 && (col0 + cbase) >= 1024) {
        #pragma unroll
        for (int i = 0; i < 4; ++i) {
            int row = rowb + i * 16;
            int b = row >> 10, q = row & 1023;
            #pragma unroll
            for (int jn = 0; jn < 4; ++jn) {
                int vcol = col0 + cbase - 1024 + wn * 64 + jn * 16 + lm;
                int hh = vcol >> 6, dd = vcol & 63;
                f16x4 hv, lv;
                #pragma unroll
                for (int r = 0; r < 4; ++r) {
                    float v = acc[i][jn][r] + bv[jn];
                    _Float16 x1, x2; split_f16(v, x1, x2);
                    hv[r] = x1; lv[r] = x2;
                }
                size_t vtoff = ((size_t)((b << 3) + hh) * 64 + dd) * 1024 + q;
                *(f16x4*)&vt_h[vtoff] = hv;
                *(f16x4*)&vt_l[vtoff] = lv;
            }
        }
        return;
    }

    #pragma unroll
    for (int i = 0; i < 4; ++i) {
        #pragma unroll
        for (int r = 0; r < 4; ++r) {
            int row = rowb + i * 16 + r;
            if (MODE != 0 && row >= vend) continue;
            #pragma unroll
            for (int jn = 0; jn < 4; ++jn) {
                float v = acc[i][jn][r] + bv[jn];
                if (RELU) v = fmaxf(v, 0.f);
                int c = col0 + wn * 64 + jn * 16 + lm;
                if (OUTMODE == 0) {
                    Cf[(size_t)row * ldc + c] = v;
                } else {
                    _Float16 h, l; split_f16(v, h, l);
                    Ch[(size_t)row * ldc + cbase + c] = h;
                    Cl[(size_t)row * ldc + cbase + c] = l;
                }
            }
        }
    }
}

// ---------------------------------------------------------------- flash attention (split-f16 3-pass, online softmax)
// grid (16 q-tiles, 16 bh), 256 thr / 4 waves; QBLK=KBLK=64; wave owns 16 q-rows.
template<int CAUSAL>
__global__ __launch_bounds__(256, 2) void attn_flash(
    const _Float16* __restrict__ qkvh, const _Float16* __restrict__ qkvl,
    const _Float16* __restrict__ vth, const _Float16* __restrict__ vtl,
    const int* __restrict__ ktoks,
    _Float16* __restrict__ ch, _Float16* __restrict__ cl)
{
    int q0 = blockIdx.x * 64;
    int bh = blockIdx.y, b = bh >> 3, h = bh & 7;
    int tid = threadIdx.x, lane = tid & 63, w = tid >> 6;
    int lm = lane & 15, kg = lane >> 4;
    int srow8 = lane >> 3, q8 = lane & 7;
    int tb = b * S_;

    __shared__ _Float16 smem[32768];     // 64 KB
    _Float16* lQh = smem;
    _Float16* lQl = smem + 4096;
    _Float16* lKh = smem + 8192;
    _Float16* lKl = smem + 12288;
    _Float16* lVh = smem + 16384;
    _Float16* lVl = smem + 20480;
    _Float16* lPh = smem + 24576;
    _Float16* lPl = smem + 28672;

    size_t qbase = (size_t)b * S_ * QLD + h * DK_;
    const _Float16* Qh = qkvh + qbase;
    const _Float16* Ql = qkvl + qbase;
    const _Float16* Kh = qkvh + qbase + 512;
    const _Float16* Kl = qkvl + qbase + 512;
    const _Float16* Vh = vth + (size_t)bh * 64 * 1024;
    const _Float16* Vl = vtl + (size_t)bh * 64 * 1024;

    // stage Q (once)
    #pragma unroll
    for (int j = 0; j < 2; ++j) {
        int row = w * 16 + j * 8 + srow8;
        int lb = (w * 16 + j * 8) * 64;
        int ss = (q8 ^ (row & 7)) << 3;
        gload16(Qh + (size_t)(q0 + row) * QLD + ss, lQh + lb);
        gload16(Ql + (size_t)(q0 + row) * QLD + ss, lQl + lb);
    }
    // stage K/V tile 0
    #pragma unroll
    for (int j = 0; j < 2; ++j) {
        int row = w * 16 + j * 8 + srow8;
        int lb = (w * 16 + j * 8) * 64;
        int ss = (q8 ^ (row & 7)) << 3;
        gload16(Kh + (size_t)row * QLD + ss, lKh + lb);
        gload16(Kl + (size_t)row * QLD + ss, lKl + lb);
        gload16(Vh + (size_t)row * 1024 + ss, lVh + lb);
        gload16(Vl + (size_t)row * 1024 + ss, lVl + lb);
    }
    __syncthreads();

    float mreg[4], lreg[4];
    f32x4 od[4];
    f32x4 zero4 = {0.f, 0.f, 0.f, 0.f};
    #pragma unroll
    for (int r = 0; r < 4; ++r) { mreg[r] = -1e30f; lreg[r] = 0.f; }
    #pragma unroll
    for (int jn = 0; jn < 4; ++jn) od[jn] = zero4;

    int qrow[4];
    #pragma unroll
    for (int r = 0; r < 4; ++r) qrow[r] = q0 + w * 16 + (lane >> 4) * 4 + r;

    int nkt = CAUSAL ? (q0 >> 6) + 1 : 16;

    for (int kt = 0; kt < nkt; ++kt) {
        int k0 = kt * 64;
        bool diag = CAUSAL && (kt == (q0 >> 6));

        // ---- S = QK^T (3-pass)
        f32x4 accs[4];
        #pragma unroll
        for (int jn = 0; jn < 4; ++jn) accs[jn] = zero4;
        #pragma unroll
        for (int ks = 0; ks < 2; ++ks) {
            int qm = w * 16 + lm;
            int qoff = qm * 64 + ((((ks << 2) + kg) ^ (qm & 7)) << 3);
            f16x8 ah = *(const f16x8*)&lQh[qoff];
            f16x8 al = *(const f16x8*)&lQl[qoff];
            #pragma unroll
            for (int jn = 0; jn < 4; ++jn) {
                int n = jn * 16 + lm;
                int koff = n * 64 + ((((ks << 2) + kg) ^ (n & 7)) << 3);
                f16x8 bhv = *(const f16x8*)&lKh[koff];
                f16x8 blv = *(const f16x8*)&lKl[koff];
                accs[jn] = __builtin_amdgcn_mfma_f32_16x16x32_f16(ah, bhv, accs[jn], 0, 0, 0);
                accs[jn] = __builtin_amdgcn_mfma_f32_16x16x32_f16(ah, blv, accs[jn], 0, 0, 0);
                accs[jn] = __builtin_amdgcn_mfma_f32_16x16x32_f16(al, bhv, accs[jn], 0, 0, 0);
            }
        }

        // ---- mask + online softmax stats
        float sv[4][4];
        #pragma unroll
        for (int jn = 0; jn < 4; ++jn) {
            int kglob = k0 + jn * 16 + lm;
            bool pad_ok = (ktoks[tb + kglob] != 0);
            #pragma unroll
            for (int r = 0; r < 4; ++r) {
                float s = accs[jn][r] * 0.125f;
                bool keep = pad_ok && (!diag || kglob <= qrow[r]);
                sv[jn][r] = keep ? s : -1e9f;
            }
        }
        float pv[4][4];
        #pragma unroll
        for (int r = 0; r < 4; ++r) {
            float tm = fmaxf(fmaxf(sv[0][r], sv[1][r]), fmaxf(sv[2][r], sv[3][r]));
            tm = fmaxf(tm, __shfl_xor(tm, 1));
            tm = fmaxf(tm, __shfl_xor(tm, 2));
            tm = fmaxf(tm, __shfl_xor(tm, 4));
            tm = fmaxf(tm, __shfl_xor(tm, 8));
            float mnew = fmaxf(mreg[r], tm);
            float corr = expf(mreg[r] - mnew);
            lreg[r] *= corr;
            #pragma unroll
            for (int jn = 0; jn < 4; ++jn) od[jn][r] *= corr;
            float psum = 0.f;
            #pragma unroll
            for (int jn = 0; jn < 4; ++jn) {
                float p = expf(sv[jn][r] - mnew);
                pv[jn][r] = p;
                psum += p;
            }
            psum += __shfl_xor(psum, 1);
            psum += __shfl_xor(psum, 2);
            psum += __shfl_xor(psum, 4);
            psum += __shfl_xor(psum, 8);
            lreg[r] += psum;
            mreg[r] = mnew;
        }

        // ---- write P hi/lo to LDS (wave-private 16 rows)
        #pragma unroll
        for (int jn = 0; jn < 4; ++jn) {
            int col = jn * 16 + lm;
            #pragma unroll
            for (int r = 0; r < 4; ++r) {
                int row = w * 16 + (lane >> 4) * 4 + r;
                int idx = row * 64 + (((col >> 3) ^ (row & 7)) << 3) + (col & 7);
                _Float16 hh, ll; split_f16(pv[jn][r], hh, ll);
                lPh[idx] = hh; lPl[idx] = ll;
            }
        }

        // ---- PV (3-pass) accumulate into od
        #pragma unroll
        for (int ks = 0; ks < 2; ++ks) {
            int prow = w * 16 + lm;
            int poff = prow * 64 + ((((ks << 2) + kg) ^ (prow & 7)) << 3);
            f16x8 pah = *(const f16x8*)&lPh[poff];
            f16x8 pal = *(const f16x8*)&lPl[poff];
            #pragma unroll
            for (int jn = 0; jn < 4; ++jn) {
                int n = jn * 16 + lm;
                int noff = n * 64 + ((((ks << 2) + kg) ^ (n & 7)) << 3);
                f16x8 vbh = *(const f16x8*)&lVh[noff];
                f16x8 vbl = *(const f16x8*)&lVl[noff];
                od[jn] = __builtin_amdgcn_mfma_f32_16x16x32_f16(pah, vbh, od[jn], 0, 0, 0);
                od[jn] = __builtin_amdgcn_mfma_f32_16x16x32_f16(pah, vbl, od[jn], 0, 0, 0);
                od[jn] = __builtin_amdgcn_mfma_f32_16x16x32_f16(pal, vbh, od[jn], 0, 0, 0);
            }
        }
        __syncthreads();   // all waves done with lK/lV/lP

        if (kt + 1 < nkt) {
            int k0n = (kt + 1) * 64;
            #pragma unroll
            for (int j = 0; j < 2; ++j) {
                int row = w * 16 + j * 8 + srow8;
                int lb = (w * 16 + j * 8) * 64;
                int ss = (q8 ^ (row & 7)) << 3;
                gload16(Kh + (size_t)(k0n + row) * QLD + ss, lKh + lb);
                gload16(Kl + (size_t)(k0n + row) * QLD + ss, lKl + lb);
                gload16(Vh + (size_t)row * 1024 + k0n + ss, lVh + lb);
                gload16(Vl + (size_t)row * 1024 + k0n + ss, lVl + lb);
            }
            __syncthreads();
        }
    }

    // ---- finalize: O = od / l, split to hi/lo
    float inv[4];
    #pragma unroll
    for (int r = 0; r < 4; ++r) inv[r] = 1.0f / lreg[r];
    #pragma unroll
    for (int r = 0; r < 4; ++r) {
        size_t rbase = (size_t)(tb + qrow[r]) * D_ + h * DK_;
        #pragma unroll
        for (int jn = 0; jn < 4; ++jn) {
            float o = od[jn][r] * inv[r];
            _Float16 hh, ll; split_f16(o, hh, ll);
            int d = jn * 16 + lm;
            ch[rbase + d] = hh; cl[rbase + d] = ll;
        }
    }
}

// ---------------------------------------------------------------- residual + LayerNorm (f32 + hi/lo)
__global__ __launch_bounds__(256) void ln_add(const float* __restrict__ x,
                                              const float* __restrict__ r,
                                              const float* __restrict__ g,
                                              const float* __restrict__ be,
                                              float* __restrict__ o,
                                              _Float16* __restrict__ oh,
                                              _Float16* __restrict__ ol)
{
    int row = blockIdx.x;
    const float* xr = x + (size_t)row * D_;
    const float* rr = r + (size_t)row * D_;
    int tid = threadIdx.x;
    float v0 = xr[tid] + rr[tid];
    float v1 = xr[tid + 256] + rr[tid + 256];
    float s = v0 + v1;
    for (int off = 32; off; off >>= 1) s += __shfl_down(s, off);
    __shared__ float red[8];
    int lane = tid & 63, wid = tid >> 6;
    if (!lane) red[wid] = s;
    __syncthreads();
    if (!tid) red[4] = (red[0] + red[1] + red[2] + red[3]) * (1.0f / 512.0f);
    __syncthreads();
    float m = red[4];
    float d0 = v0 - m, d1 = v1 - m;
    s = d0 * d0 + d1 * d1;
    for (int off = 32; off; off >>= 1) s += __shfl_down(s, off);
    if (!lane) red[wid] = s;
    __syncthreads();
    if (!tid) red[5] = rsqrtf((red[0] + red[1] + red[2] + red[3]) * (1.0f / 512.0f) + 1e-5f);
    __syncthreads();
    float rstd = red[5];
    size_t rb = (size_t)row * D_;
    float y0 = d0 * rstd * g[tid] + be[tid];
    float y1 = d1 * rstd * g[tid + 256] + be[tid + 256];
    o[rb + tid] = y0; o[rb + tid + 256] = y1;
    _Float16 h, l;
    split_f16(y0, h, l); oh[rb + tid] = h; ol[rb + tid] = l;
    split_f16(y1, h, l); oh[rb + tid + 256] = h; ol[rb + tid + 256] = l;
}

// ---------------------------------------------------------------- MoE combine + residual + LN fused
__global__ __launch_bounds__(256) void ln_add_moe(const float* __restrict__ x,
                                                  const float* __restrict__ eo,
                                                  const float* __restrict__ topv,
                                                  const int* __restrict__ route_row,
                                                  const float* __restrict__ g,
                                                  const float* __restrict__ be,
                                                  float* __restrict__ o,
                                                  _Float16* __restrict__ oh,
                                                  _Float16* __restrict__ ol)
{
    int row = blockIdx.x;
    int r0 = route_row[row * 2], r1 = route_row[row * 2 + 1];
    float w0 = topv[row * 2], w1 = topv[row * 2 + 1];
    const float* xr = x + (size_t)row * D_;
    const float* e0 = eo + (size_t)r0 * D_;
    const float* e1 = eo + (size_t)r1 * D_;
    int tid = threadIdx.x;
    float v0 = xr[tid] + w0 * e0[tid] + w1 * e1[tid];
    float v1 = xr[tid + 256] + w0 * e0[tid + 256] + w1 * e1[tid + 256];
    float s = v0 + v1;
    for (int off = 32; off; off >>= 1) s += __shfl_down(s, off);
    __shared__ float red[8];
    int lane = tid & 63, wid = tid >> 6;
    if (!lane) red[wid] = s;
    __syncthreads();
    if (!tid) red[4] = (red[0] + red[1] + red[2] + red[3]) * (1.0f / 512.0f);
    __syncthreads();
    float m = red[4];
    float d0 = v0 - m, d1 = v1 - m;
    s = d0 * d0 + d1 * d1;
    for (int off = 32; off; off >>= 1) s += __shfl_down(s, off);
    if (!lane) red[wid] = s;
    __syncthreads();
    if (!tid) red[5] = rsqrtf((red[0] + red[1] + red[2] + red[3]) * (1.0f / 512.0f) + 1e-5f);
    __syncthreads();
    float rstd = red[5];
    size_t rb = (size_t)row * D_;
    float y0 = d0 * rstd * g[tid] + be[tid];
    float y1 = d1 * rstd * g[tid + 256] + be[tid + 256];
    o[rb + tid] = y0; o[rb + tid + 256] = y1;
    _Float16 h, l;
    split_f16(y0, h, l); oh[rb + tid] = h; ol[rb + tid] = l;
    split_f16(y1, h, l); oh[rb + tid + 256] = h; ol[rb + tid + 256] = l;
}

// ---------------------------------------------------------------- MoE gate
__global__ __launch_bounds__(256) void gate_logits(const float* __restrict__ xf,
                                                   const float* __restrict__ gw,
                                                   const float* __restrict__ gb,
                                                   float* __restrict__ lg)
{
    int id = blockIdx.x * 256 + threadIdx.x;
    if (id >= NTOK * E_) return;
    int e = id & 7, n = id >> 3;
    const float* x = xf + (size_t)n * D_;
    float s = gb[e];
    for (int d = 0; d < D_; ++d) s += x[d] * gw[d * E_ + e];
    lg[id] = s;
}

__global__ __launch_bounds__(256) void gate_top2(const float* __restrict__ lg,
                                                 float* __restrict__ topv,
                                                 int* __restrict__ topi)
{
    int n = blockIdx.x * 256 + threadIdx.x;
    if (n >= NTOK) return;
    float l[E_], p[E_];
    float m = -1e30f;
    #pragma unroll
    for (int e = 0; e < E_; ++e) { l[e] = lg[n * E_ + e]; m = fmaxf(m, l[e]); }
    float su = 0.f;
    #pragma unroll
    for (int e = 0; e < E_; ++e) { p[e] = expf(l[e] - m); su += p[e]; }
    float inv = 1.0f / su;
    int i1 = 0; float v1 = p[0];
    #pragma unroll
    for (int e = 1; e < E_; ++e) if (p[e] > v1) { v1 = p[e]; i1 = e; }
    int i2 = -1; float v2 = -1.f;
    #pragma unroll
    for (int e = 0; e < E_; ++e) if (e != i1 && p[e] > v2) { v2 = p[e]; i2 = e; }
    topv[n * 2] = v1 * inv; topv[n * 2 + 1] = v2 * inv;
    topi[n * 2] = i1;       topi[n * 2 + 1] = i2;
}

// ---------------------------------------------------------------- parallel deterministic routing
__global__ __launch_bounds__(1024) void build_routes(const int* __restrict__ topi,
                                                     int* __restrict__ route_tok,
                                                     int* __restrict__ route_row,
                                                     int* __restrict__ counts,
                                                     int* __restrict__ pad_base,
                                                     int* __restrict__ rb_expert)
{
    __shared__ int eid[NTOK * 2];
    __shared__ unsigned short chist[256][8];
    __shared__ int pb[E_ + 1];
    __shared__ int cnt[E_];
    int t = threadIdx.x;
    #pragma unroll
    for (int i = 0; i < 4; ++i) eid[t + 1024 * i] = topi[t + 1024 * i];
    #pragma unroll
    for (int g = 0; g < 5; ++g) route_tok[t + 1024 * g] = 0;
    __syncthreads();

    if (t < 256) {
        int r[16];
        #pragma unroll
        for (int i = 0; i < 16; ++i) r[i] = eid[t * 16 + i];
        #pragma unroll
        for (int e = 0; e < 8; ++e) {
            int h = 0;
            #pragma unroll
            for (int i = 0; i < 16; ++i) h += (r[i] == e) ? 1 : 0;
            chist[t][e] = (unsigned short)h;
        }
    }
    __syncthreads();

    if (t < 8) {
        int run = 0;
        for (int c = 0; c < 256; ++c) {
            int v = chist[c][t];
            chist[c][t] = (unsigned short)run;
            run += v;
        }
        cnt[t] = run;
        counts[t] = run;
    }
    __syncthreads();

    if (t == 0) {
        int pad = 0;
        for (int e = 0; e < 8; ++e) {
            pb[e] = pad;
            pad_base[e] = pad;
            int nb = (cnt[e] + 127) >> 7;
            for (int rb = 0; rb < nb; ++rb) rb_expert[(pad >> 7) + rb] = e;
            pad += nb << 7;
        }
        pb[8] = pad;
        pad_base[8] = pad;
    }
    __syncthreads();

    if (t < 256) {
        int r[16];
        #pragma unroll
        for (int i = 0; i < 16; ++i) r[i] = eid[t * 16 + i];
        #pragma unroll
        for (int e = 0; e < 8; ++e) {
            int o = pb[e] + chist[t][e];
            #pragma unroll
            for (int i = 0; i < 16; ++i) {
                if (r[i] == e) {
                    int slot = t * 16 + i;
                    route_tok[o] = slot >> 1;
                    route_row[slot] = o;
                    o++;
                }
            }
        }
    }
}

// ================================================================ host orchestration
extern "C" void kernel_launch(void* const* d_in, const int* in_sizes, int n_in,
                              void* d_out, int out_size, void* d_ws, size_t ws_size,
                              hipStream_t stream)
{
    const int*   src        = (const int*)  d_in[0];
    const int*   tgt        = (const int*)  d_in[1];
    const float* enc_emb    = (const float*)d_in[2];
    const float* dec_emb    = (const float*)d_in[3];
    const float* enc_attn_w = (const float*)d_in[4];
    const float* enc_attn_b = (const float*)d_in[5];
    const float* enc_ln_g   = (const float*)d_in[6];
    const float* enc_ln_b   = (const float*)d_in[7];
    const float* enc_gate_w = (const float*)d_in[8];
    const float* enc_gate_b = (const float*)d_in[9];
    const float* enc_w1     = (const float*)d_in[10];
    const float* enc_b1     = (const float*)d_in[11];
    const float* enc_w2     = (const float*)d_in[12];
    const float* enc_b2     = (const float*)d_in[13];
    const float* dec_sa_w   = (const float*)d_in[14];
    const float* dec_sa_b   = (const float*)d_in[15];
    const float* dec_ca_w   = (const float*)d_in[16];
    const float* dec_ca_b   = (const float*)d_in[17];
    const float* dec_ln_g   = (const float*)d_in[18];
    const float* dec_ln_b   = (const float*)d_in[19];
    const float* dec_gate_w = (const float*)d_in[20];
    const float* dec_gate_b = (const float*)d_in[21];
    const float* dec_w1     = (const float*)d_in[22];
    const float* dec_b1     = (const float*)d_in[23];
    const float* dec_w2     = (const float*)d_in[24];
    const float* dec_b2     = (const float*)d_in[25];
    const float* out_w      = (const float*)d_in[26];
    const float* out_b      = (const float*)d_in[27];
    float* out = (float*)d_out;

    // ---- d_out scratch (dead until final GEMM overwrites all of it)
    char* ob = (char*)d_out;
    size_t oc = 0;
    auto dalloc = [&](size_t bytes) { char* p = ob + oc; oc += (bytes + 255) & ~(size_t)255; return p; };
    _Float16* qkv_h  = (_Float16*)dalloc((size_t)NTOK * QLD * 2);
    _Float16* qkv_l  = (_Float16*)dalloc((size_t)NTOK * QLD * 2);
    _Float16* vt_h   = (_Float16*)dalloc((size_t)16 * 64 * 1024 * 2);
    _Float16* vt_l   = (_Float16*)dalloc((size_t)16 * 64 * 1024 * 2);
    float* aout  = (float*)dalloc((size_t)NTOK * D_ * 4);
    _Float16* ctx_h = (_Float16*)dalloc((size_t)NTOK * D_ * 2);
    _Float16* ctx_l = (_Float16*)dalloc((size_t)NTOK * D_ * 2);
    _Float16* encA_h = (_Float16*)dalloc((size_t)L_ * 4 * D_ * D_ * 2);
    _Float16* encA_l = (_Float16*)dalloc((size_t)L_ * 4 * D_ * D_ * 2);
    _Float16* saA_h  = (_Float16*)dalloc((size_t)L_ * 4 * D_ * D_ * 2);
    _Float16* saA_l  = (_Float16*)dalloc((size_t)L_ * 4 * D_ * D_ * 2);
    _Float16* caA_h  = (_Float16*)dalloc((size_t)L_ * 4 * D_ * D_ * 2);
    _Float16* caA_l  = (_Float16*)dalloc((size_t)L_ * 4 * D_ * D_ * 2);
    float* xA = (float*)dalloc((size_t)NTOK * D_ * 4);
    float* xB = (float*)dalloc((size_t)NTOK * D_ * 4);
    float* yA = (float*)dalloc((size_t)NTOK * D_ * 4);
    float* yB = (float*)dalloc((size_t)NTOK * D_ * 4);
    _Float16* xA_h = (_Float16*)dalloc((size_t)NTOK * D_ * 2);
    _Float16* xA_l = (_Float16*)dalloc((size_t)NTOK * D_ * 2);
    _Float16* xB_h = (_Float16*)dalloc((size_t)NTOK * D_ * 2);
    _Float16* xB_l = (_Float16*)dalloc((size_t)NTOK * D_ * 2);
    _Float16* yA_h = (_Float16*)dalloc((size_t)NTOK * D_ * 2);
    _Float16* yA_l = (_Float16*)dalloc((size_t)NTOK * D_ * 2);
    _Float16* yB_h = (_Float16*)dalloc((size_t)NTOK * D_ * 2);
    _Float16* yB_l = (_Float16*)dalloc((size_t)NTOK * D_ * 2);

    // ---- ws scratch
    char* wp = (char*)d_ws;
    size_t wc = 0;
    auto walloc = [&](size_t bytes) { char* p = wp + wc; wc += (bytes + 255) & ~(size_t)255; return p; };
    _Float16* outwT_h = (_Float16*)walloc((size_t)V_ * D_ * 2);
    _Float16* final_h = (_Float16*)walloc((size_t)NTOK * D_ * 2);
    _Float16* w1t_h   = (_Float16*)walloc((size_t)E_ * F_ * D_ * 2);
    _Float16* w1t_l   = (_Float16*)walloc((size_t)E_ * F_ * D_ * 2);
    _Float16* w2t_h   = (_Float16*)walloc((size_t)E_ * F_ * D_ * 2);
    _Float16* w2t_l   = (_Float16*)walloc((size_t)E_ * F_ * D_ * 2);
    _Float16* hbuf_h  = (_Float16*)walloc((size_t)MAXPAD * F_ * 2);
    _Float16* hbuf_l  = (_Float16*)walloc((size_t)MAXPAD * F_ * 2);
    float*    eobuf   = (float*)walloc((size_t)MAXPAD * D_ * 4);
    float* lg   = (float*)walloc((size_t)NTOK * E_ * 4);
    float* topv = (float*)walloc((size_t)NTOK * 2 * 4);
    int*   topi = (int*)  walloc((size_t)NTOK * 2 * 4);
    int*   route_tok = (int*)walloc((size_t)MAXPAD * 4);
    int*   route_row = (int*)walloc((size_t)NTOK * 2 * 4);
    int*   counts    = (int*)walloc(64);
    int*   pad_base  = (int*)walloc(64);
    int*   rb_expert = (int*)walloc((size_t)64 * 4);

    // ---- weight transposes (once per launch)
    transpose_w<true><<<dim3(8, 8, 8), 256, 0, stream>>>(enc_attn_w, encA_h, encA_l, D_, D_);
    transpose_w<true><<<dim3(8, 8, 8), 256, 0, stream>>>(dec_sa_w, saA_h, saA_l, D_, D_);
    transpose_w<true><<<dim3(8, 8, 8), 256, 0, stream>>>(dec_ca_w, caA_h, caA_l, D_, D_);
    transpose_w<false><<<dim3(500, 8, 1), 256, 0, stream>>>(out_w, outwT_h, nullptr, D_, V_);

    auto run_mha = [&](const _Float16* q_h, const _Float16* q_l,
                       const _Float16* kv_h, const _Float16* kv_l,
                       const _Float16* wT_h, const _Float16* wT_l, const float* bt,
                       const int* ktoks, int causal, bool fused) {
        if (fused) {
            gemm_mfma<0, false, 2, 3><<<dim3(12, 16), 256, 0, stream>>>(
                q_h, q_l, wT_h, wT_l, bt, nullptr, qkv_h, qkv_l, vt_h, vt_l, 0,
                NTOK, D_, 1536, QLD, nullptr, nullptr, nullptr, nullptr);
        } else {
            gemm_mfma<0, false, 1, 3><<<dim3(4, 16), 256, 0, stream>>>(
                q_h, q_l, wT_h, wT_l, bt, nullptr, qkv_h, qkv_l, nullptr, nullptr, 0,
                NTOK, D_, 512, QLD, nullptr, nullptr, nullptr, nullptr);
            gemm_mfma<0, false, 2, 3><<<dim3(8, 16), 256, 0, stream>>>(
                kv_h, kv_l, wT_h + (size_t)D_ * D_, wT_l + (size_t)D_ * D_, bt + D_,
                nullptr, qkv_h, qkv_l, vt_h, vt_l, 512,
                NTOK, D_, 1024, QLD, nullptr, nullptr, nullptr, nullptr);
        }
        if (causal)
            attn_flash<1><<<dim3(16, 16), 256, 0, stream>>>(qkv_h, qkv_l, vt_h, vt_l, ktoks, ctx_h, ctx_l);
        else
            attn_flash<0><<<dim3(16, 16), 256, 0, stream>>>(qkv_h, qkv_l, vt_h, vt_l, ktoks, ctx_h, ctx_l);
        gemm_mfma<0, false, 0, 3><<<dim3(4, 16), 256, 0, stream>>>(
            ctx_h, ctx_l, wT_h + (size_t)3 * D_ * D_, wT_l + (size_t)3 * D_ * D_,
            bt + 3 * D_, aout, nullptr, nullptr, nullptr, nullptr, 0,
            NTOK, D_, 512, 512, nullptr, nullptr, nullptr, nullptr);
    };

    auto run_moe = [&](const float* x, const _Float16* x_h, const _Float16* x_l,
                       const float* gwp, const float* gbp,
                       const float* w1p, const float* b1p,
                       const float* w2p, const float* b2p) {
        gate_logits<<<NTOK * E_ / 256, 256, 0, stream>>>(x, gwp, gbp, lg);
        gate_top2<<<NTOK / 256, 256, 0, stream>>>(lg, topv, topi);
        build_routes<<<1, 1024, 0, stream>>>(topi, route_tok, route_row, counts, pad_base, rb_expert);
        transpose_w<true><<<dim3(32, 8, 8), 256, 0, stream>>>(w1p, w1t_h, w1t_l, D_, F_);
        transpose_w<true><<<dim3(8, 32, 8), 256, 0, stream>>>(w2p, w2t_h, w2t_l, F_, D_);
        gemm_mfma<1, true, 1, 3><<<dim3(F_ / 128, MAXRB), 256, 0, stream>>>(
            x_h, x_l, w1t_h, w1t_l, b1p, nullptr, hbuf_h, hbuf_l, nullptr, nullptr, 0,
            0, D_, F_, F_, route_tok, rb_expert, pad_base, counts);
        gemm_mfma<2, false, 0, 3><<<dim3(D_ / 128, MAXRB), 256, 0, stream>>>(
            hbuf_h, hbuf_l, w2t_h, w2t_l, b2p, eobuf, nullptr, nullptr, nullptr, nullptr, 0,
            0, F_, D_, D_, route_tok, rb_expert, pad_base, counts);
    };

    // ---------------- encoder ----------------
    embed_pe<<<B_ * S_, 256, 0, stream>>>(src, enc_emb, xA, xA_h, xA_l, S_);
    float* cur = xA; float* alt = xB;
    _Float16* cur_h = xA_h; _Float16* cur_l = xA_l;
    _Float16* alt_h = xB_h; _Float16* alt_l = xB_l;
    for (int l = 0; l < L_; ++l) {
        run_mha(cur_h, cur_l, nullptr, nullptr,
                encA_h + (size_t)l * 4 * D_ * D_, encA_l + (size_t)l * 4 * D_ * D_,
                enc_attn_b + (size_t)l * 4 * D_, src, 0, true);
        ln_add<<<NTOK, 256, 0, stream>>>(cur, aout,
            enc_ln_g + (size_t)(l * 2 + 0) * D_, enc_ln_b + (size_t)(l * 2 + 0) * D_,
            alt, alt_h, alt_l);
        { float* t = cur; cur = alt; alt = t; }
        { _Float16* t = cur_h; cur_h = alt_h; alt_h = t; t = cur_l; cur_l = alt_l; alt_l = t; }
        run_moe(cur, cur_h, cur_l, enc_gate_w + (size_t)l * D_ * E_, enc_gate_b + (size_t)l * E_,
                enc_w1 + (size_t)l * E_ * D_ * F_, enc_b1 + (size_t)l * E_ * F_,
                enc_w2 + (size_t)l * E_ * F_ * D_, enc_b2 + (size_t)l * E_ * D_);
        ln_add_moe<<<NTOK, 256, 0, stream>>>(cur, eobuf, topv, route_row,
            enc_ln_g + (size_t)(l * 2 + 1) * D_, enc_ln_b + (size_t)(l * 2 + 1) * D_,
            alt, alt_h, alt_l);
        { float* t = cur; cur = alt; alt = t; }
        { _Float16* t = cur_h; cur_h = alt_h; alt_h = t; t = cur_l; cur_l = alt_l; alt_l = t; }
    }
    _Float16* enc_h = cur_h; _Float16* enc_l = cur_l;

    // ---------------- decoder ----------------
    embed_pe<<<B_ * T_, 256, 0, stream>>>(tgt, dec_emb, yA, yA_h, yA_l, T_);
    float* dc = yA; float* da = yB;
    _Float16* dc_h = yA_h; _Float16* dc_l = yA_l;
    _Float16* da_h = yB_h; _Float16* da_l = yB_l;
    for (int l = 0; l < L_; ++l) {
        run_mha(dc_h, dc_l, nullptr, nullptr,
                saA_h + (size_t)l * 4 * D_ * D_, saA_l + (size_t)l * 4 * D_ * D_,
                dec_sa_b + (size_t)l * 4 * D_, tgt, 1, true);
        ln_add<<<NTOK, 256, 0, stream>>>(dc, aout,
            dec_ln_g + (size_t)(l * 3 + 0) * D_, dec_ln_b + (size_t)(l * 3 + 0) * D_,
            da, da_h, da_l);
        { float* t = dc; dc = da; da = t; }
        { _Float16* t = dc_h; dc_h = da_h; da_h = t; t = dc_l; dc_l = da_l; da_l = t; }
        run_mha(dc_h, dc_l, enc_h, enc_l,
                caA_h + (size_t)l * 4 * D_ * D_, caA_l + (size_t)l * 4 * D_ * D_,
                dec_ca_b + (size_t)l * 4 * D_, src, 0, false);
        ln_add<<<NTOK, 256, 0, stream>>>(dc, aout,
            dec_ln_g + (size_t)(l * 3 + 1) * D_, dec_ln_b + (size_t)(l * 3 + 1) * D_,
            da, da_h, da_l);
        { float* t = dc; dc = da; da = t; }
        { _Float16* t = dc_h; dc_h = da_h; da_h = t; t = dc_l; dc_l = da_l; da_l = t; }
        run_moe(dc, dc_h, dc_l, dec_gate_w + (size_t)l * D_ * E_, dec_gate_b + (size_t)l * E_,
                dec_w1 + (size_t)l * E_ * D_ * F_, dec_b1 + (size_t)l * E_ * F_,
                dec_w2 + (size_t)l * E_ * F_ * D_, dec_b2 + (size_t)l * E_ * D_);
        bool last = (l == L_ - 1);
        ln_add_moe<<<NTOK, 256, 0, stream>>>(dc, eobuf, topv, route_row,
            dec_ln_g + (size_t)(l * 3 + 2) * D_, dec_ln_b + (size_t)(l * 3 + 2) * D_,
            da, last ? final_h : da_h, da_l);
        { float* t = dc; dc = da; da = t; }
        { _Float16* t = dc_h; dc_h = da_h; da_h = t; t = dc_l; dc_l = da_l; da_l = t; }
    }

    // ---------------- final projection (single-pass f16 MFMA; overwrites all of d_out)
    gemm_mfma<0, false, 0, 1><<<dim3(V_ / 128, NTOK / 128), 256, 0, stream>>>(
        final_h, nullptr, outwT_h, nullptr, out_b, out, nullptr, nullptr, nullptr, nullptr, 0,
        NTOK, D_, V_, V_, nullptr, nullptr, nullptr, nullptr);
}

// Round 6
// 1336.329 us; speedup vs baseline: 4.4190x; 1.1628x over previous
//
#include <hip/hip_runtime.h>
#include <hip/hip_bf16.h>

#define L_ 2
#define D_ 512
#define H_ 8
#define DK_ 64
#define F_ 2048
#define E_ 8
#define V_ 32000
#define B_ 2
#define S_ 1024
#define T_ 1024
#define NTOK (B_*S_)
#define MAXPAD 4608            // per-expert 64-padded total upper bound
#define RB64   72              // MAXPAD/64
#define QLD 1536

typedef unsigned short u16;
typedef _Float16 f16x8 __attribute__((ext_vector_type(8)));
typedef _Float16 f16x4 __attribute__((ext_vector_type(4)));
typedef float f32x4 __attribute__((ext_vector_type(4)));

__device__ __forceinline__ void gload16(const void* g, const void* l) {
    __builtin_amdgcn_global_load_lds(
        (const __attribute__((address_space(1))) void*)g,
        (__attribute__((address_space(3))) void*)l, 16, 0, 0);
}

__device__ __forceinline__ void split_f16(float v, _Float16& h, _Float16& l) {
    h = (_Float16)v;
    l = (_Float16)(v - (float)h);
}

// ---------------------------------------------------------------- embedding + PE (f32 + hi/lo f16)
__global__ __launch_bounds__(256) void embed_pe(const int* __restrict__ toks,
                                                const float* __restrict__ emb,
                                                float* __restrict__ o,
                                                _Float16* __restrict__ oh,
                                                _Float16* __restrict__ ol, int Slen)
{
    int n = blockIdx.x;
    int spos = n % Slen;
    int tok = toks[n];
    const float* erow = emb + (size_t)tok * D_;
    size_t rb = (size_t)n * D_;
    for (int j = threadIdx.x; j < D_; j += 256) {
        int i = j >> 1;
        float arg = (float)spos * expf(-(float)i * 0.035977892f);
        float pe = (j & 1) ? cosf(arg) : sinf(arg);
        float v = erow[j] + pe;
        o[rb + j] = v;
        _Float16 h, l; split_f16(v, h, l);
        oh[rb + j] = h; ol[rb + j] = l;
    }
}

// ---------------------------------------------------------------- weight transpose f32[K][N] -> f16 hi/lo [N][K]
template<bool WLO>
__global__ __launch_bounds__(256) void transpose_w(const float* __restrict__ in,
                                                   _Float16* __restrict__ oh,
                                                   _Float16* __restrict__ ol, int R, int C)
{
    __shared__ float t[64][65];
    size_t sb = (size_t)blockIdx.z * R * C;
    in += sb; oh += sb; if (WLO) ol += sb;
    int c0 = blockIdx.x * 64, r0 = blockIdx.y * 64;
    int tid = threadIdx.x;
    int cc = tid & 63, r4 = tid >> 6;
    #pragma unroll
    for (int p = 0; p < 16; ++p) {
        int r = p * 4 + r4;
        t[r][cc] = in[(size_t)(r0 + r) * C + c0 + cc];
    }
    __syncthreads();
    int rr = tid & 63, c4 = tid >> 6;
    #pragma unroll
    for (int p = 0; p < 16; ++p) {
        int c = p * 4 + c4;
        float v = t[rr][c];
        _Float16 h = (_Float16)v;
        oh[(size_t)(c0 + c) * R + r0 + rr] = h;
        if (WLO) ol[(size_t)(c0 + c) * R + r0 + rr] = (_Float16)(v - (float)h);
    }
}

// ---------------------------------------------------------------- MFMA GEMM (tile-templated)
// rows on blockIdx.x (consecutive ids share weight col-panel), cols on blockIdx.y
template<int MODE, bool RELU, int OUTMODE, int PASSES, int TM, int TN>
__global__ __launch_bounds__(256, 2) void gemm_mfma(
    const _Float16* __restrict__ Ah, const _Float16* __restrict__ Al,
    const _Float16* __restrict__ Wh, const _Float16* __restrict__ Wl,
    const float* __restrict__ biasbase,
    float* __restrict__ Cf, _Float16* __restrict__ Ch, _Float16* __restrict__ Cl,
    _Float16* __restrict__ vt_h, _Float16* __restrict__ vt_l, int cbase,
    int M, int Kd, int N, int ldc,
    const int* __restrict__ route_tok, const int* __restrict__ rb_expert,
    const int* __restrict__ pad_base, const int* __restrict__ counts)
{
    constexpr int AR = TM / 32;       // acc row reps (16-row fragments per wave)
    constexpr int BR = TN / 32;       // acc col reps
    int row0 = blockIdx.x * TM;
    const _Float16* Wmh = Wh;
    const _Float16* Wml = Wl;
    const float* bias = biasbase;
    int vend = M;
    if (MODE != 0) {
        int total = pad_base[E_];
        if (row0 >= total) return;
        int e = rb_expert[row0 >> 6];
        vend = pad_base[e] + counts[e];
        Wmh = Wh + (size_t)e * Kd * N;
        if (PASSES == 3) Wml = Wl + (size_t)e * Kd * N;
        bias = biasbase + (size_t)e * N;
    }
    int col0 = blockIdx.y * TN;
    int tid = threadIdx.x;
    int lane = tid & 63, w = tid >> 6;
    int wm = w >> 1, wn = w & 1;

    __shared__ _Float16 lds[(PASSES == 3 ? 2 : 1) * (TM + TN) * 64];
    _Float16* lAh = lds;
    _Float16* lBh = lds + TM * 64;
    _Float16* lAl = (PASSES == 3) ? lds + (TM + TN) * 64 : nullptr;
    _Float16* lBl = (PASSES == 3) ? lds + (TM + TN) * 64 + TM * 64 : nullptr;

    int srow8 = lane >> 3;
    int q8 = lane & 7;
    size_t aoff[AR], boff[BR];
    #pragma unroll
    for (int j = 0; j < AR; ++j) {
        int m = w * (TM / 4) + j * 8 + srow8;
        int gr = row0 + m;
        int ar = (MODE == 1) ? route_tok[gr] : gr;
        int ss = (q8 ^ (m & 7)) << 3;
        aoff[j] = (size_t)ar * Kd + ss;
    }
    #pragma unroll
    for (int j = 0; j < BR; ++j) {
        int m = w * (TN / 4) + j * 8 + srow8;
        int ss = (q8 ^ (m & 7)) << 3;
        boff[j] = (size_t)(col0 + m) * Kd + ss;
    }

    f32x4 zero4 = {0.f, 0.f, 0.f, 0.f};
    f32x4 acc[AR][BR];
    #pragma unroll
    for (int i = 0; i < AR; ++i)
        #pragma unroll
        for (int j = 0; j < BR; ++j) acc[i][j] = zero4;

    int lm = lane & 15, kg = lane >> 4;

    for (int k0 = 0; k0 < Kd; k0 += 64) {
        #pragma unroll
        for (int j = 0; j < AR; ++j) {
            int lb = (w * (TM / 4) + j * 8) * 64;
            gload16(Ah + aoff[j] + k0, lAh + lb);
            if (PASSES == 3) gload16(Al + aoff[j] + k0, lAl + lb);
        }
        #pragma unroll
        for (int j = 0; j < BR; ++j) {
            int lb = (w * (TN / 4) + j * 8) * 64;
            gload16(Wmh + boff[j] + k0, lBh + lb);
            if (PASSES == 3) gload16(Wml + boff[j] + k0, lBl + lb);
        }
        __syncthreads();
        #pragma unroll
        for (int ks = 0; ks < 2; ++ks) {
            f16x8 ah[AR], bh[BR];
            #pragma unroll
            for (int i = 0; i < AR; ++i) {
                int m = wm * (TM / 2) + i * 16 + lm;
                ah[i] = *(const f16x8*)&lAh[m * 64 + ((((ks << 2) + kg) ^ (m & 7)) << 3)];
            }
            #pragma unroll
            for (int j = 0; j < BR; ++j) {
                int n = wn * (TN / 2) + j * 16 + lm;
                bh[j] = *(const f16x8*)&lBh[n * 64 + ((((ks << 2) + kg) ^ (n & 7)) << 3)];
            }
            #pragma unroll
            for (int i = 0; i < AR; ++i)
                #pragma unroll
                for (int jn = 0; jn < BR; ++jn)
                    acc[i][jn] = __builtin_amdgcn_mfma_f32_16x16x32_f16(ah[i], bh[jn], acc[i][jn], 0, 0, 0);
            if (PASSES == 3) {
                f16x8 bl[BR];
                #pragma unroll
                for (int j = 0; j < BR; ++j) {
                    int n = wn * (TN / 2) + j * 16 + lm;
                    bl[j] = *(const f16x8*)&lBl[n * 64 + ((((ks << 2) + kg) ^ (n & 7)) << 3)];
                }
                #pragma unroll
                for (int i = 0; i < AR; ++i)
                    #pragma unroll
                    for (int jn = 0; jn < BR; ++jn)
                        acc[i][jn] = __builtin_amdgcn_mfma_f32_16x16x32_f16(ah[i], bl[jn], acc[i][jn], 0, 0, 0);
                f16x8 al[AR];
                #pragma unroll
                for (int i = 0; i < AR; ++i) {
                    int m = wm * (TM / 2) + i * 16 + lm;
                    al[i] = *(const f16x8*)&lAl[m * 64 + ((((ks << 2) + kg) ^ (m & 7)) << 3)];
                }
                #pragma unroll
                for (int i = 0; i < AR; ++i)
                    #pragma unroll
                    for (int jn = 0; jn < BR; ++jn)
                        acc[i][jn] = __builtin_amdgcn_mfma_f32_16x16x32_f16(al[i], bh[jn], acc[i][jn], 0, 0, 0);
            }
        }
        __syncthreads();
    }

    float bv[BR];
    #pragma unroll
    for (int jn = 0; jn < BR; ++jn) bv[jn] = bias[col0 + wn * (TN / 2) + jn * 16 + lm];
    int rowb = row0 + wm * (TM / 2) + (lane >> 4) * 4;

    if (OUTMODE == 2 && (col0 + cbase) >= 1024) {
        #pragma unroll
        for (int i = 0; i < AR; ++i) {
            int row = rowb + i * 16;
            int b = row >> 10, q = row & 1023;
            #pragma unroll
            for (int jn = 0; jn < BR; ++jn) {
                int vcol = col0 + cbase - 1024 + wn * (TN / 2) + jn * 16 + lm;
                int hh = vcol >> 6, dd = vcol & 63;
                f16x4 hv, lv;
                #pragma unroll
                for (int r = 0; r < 4; ++r) {
                    float v = acc[i][jn][r] + bv[jn];
                    _Float16 x1, x2; split_f16(v, x1, x2);
                    hv[r] = x1; lv[r] = x2;
                }
                size_t vtoff = ((size_t)((b << 3) + hh) * 64 + dd) * 1024 + q;
                *(f16x4*)&vt_h[vtoff] = hv;
                *(f16x4*)&vt_l[vtoff] = lv;
            }
        }
        return;
    }

    #pragma unroll
    for (int i = 0; i < AR; ++i) {
        #pragma unroll
        for (int r = 0; r < 4; ++r) {
            int row = rowb + i * 16 + r;
            if (MODE != 0 && row >= vend) continue;
            #pragma unroll
            for (int jn = 0; jn < BR; ++jn) {
                float v = acc[i][jn][r] + bv[jn];
                if (RELU) v = fmaxf(v, 0.f);
                int c = col0 + wn * (TN / 2) + jn * 16 + lm;
                if (OUTMODE == 0) {
                    Cf[(size_t)row * ldc + c] = v;
                } else {
                    _Float16 h, l; split_f16(v, h, l);
                    Ch[(size_t)row * ldc + cbase + c] = h;
                    Cl[(size_t)row * ldc + cbase + c] = l;
                }
            }
        }
    }
}

// ---------------------------------------------------------------- flash attention (split-f16 3-pass, online softmax)
template<int CAUSAL>
__global__ __launch_bounds__(256, 2) void attn_flash(
    const _Float16* __restrict__ qkvh, const _Float16* __restrict__ qkvl,
    const _Float16* __restrict__ vth, const _Float16* __restrict__ vtl,
    const int* __restrict__ ktoks,
    _Float16* __restrict__ ch, _Float16* __restrict__ cl)
{
    int q0 = blockIdx.x * 64;
    int bh = blockIdx.y, b = bh >> 3, h = bh & 7;
    int tid = threadIdx.x, lane = tid & 63, w = tid >> 6;
    int lm = lane & 15, kg = lane >> 4;
    int srow8 = lane >> 3, q8 = lane & 7;
    int tb = b * S_;

    __shared__ _Float16 smem[32768];
    _Float16* lQh = smem;
    _Float16* lQl = smem + 4096;
    _Float16* lKh = smem + 8192;
    _Float16* lKl = smem + 12288;
    _Float16* lVh = smem + 16384;
    _Float16* lVl = smem + 20480;
    _Float16* lPh = smem + 24576;
    _Float16* lPl = smem + 28672;

    size_t qbase = (size_t)b * S_ * QLD + h * DK_;
    const _Float16* Qh = qkvh + qbase;
    const _Float16* Ql = qkvl + qbase;
    const _Float16* Kh = qkvh + qbase + 512;
    const _Float16* Kl = qkvl + qbase + 512;
    const _Float16* Vh = vth + (size_t)bh * 64 * 1024;
    const _Float16* Vl = vtl + (size_t)bh * 64 * 1024;

    #pragma unroll
    for (int j = 0; j < 2; ++j) {
        int row = w * 16 + j * 8 + srow8;
        int lb = (w * 16 + j * 8) * 64;
        int ss = (q8 ^ (row & 7)) << 3;
        gload16(Qh + (size_t)(q0 + row) * QLD + ss, lQh + lb);
        gload16(Ql + (size_t)(q0 + row) * QLD + ss, lQl + lb);
    }
    #pragma unroll
    for (int j = 0; j < 2; ++j) {
        int row = w * 16 + j * 8 + srow8;
        int lb = (w * 16 + j * 8) * 64;
        int ss = (q8 ^ (row & 7)) << 3;
        gload16(Kh + (size_t)row * QLD + ss, lKh + lb);
        gload16(Kl + (size_t)row * QLD + ss, lKl + lb);
        gload16(Vh + (size_t)row * 1024 + ss, lVh + lb);
        gload16(Vl + (size_t)row * 1024 + ss, lVl + lb);
    }
    __syncthreads();

    float mreg[4], lreg[4];
    f32x4 od[4];
    f32x4 zero4 = {0.f, 0.f, 0.f, 0.f};
    #pragma unroll
    for (int r = 0; r < 4; ++r) { mreg[r] = -1e30f; lreg[r] = 0.f; }
    #pragma unroll
    for (int jn = 0; jn < 4; ++jn) od[jn] = zero4;

    int qrow[4];
    #pragma unroll
    for (int r = 0; r < 4; ++r) qrow[r] = q0 + w * 16 + (lane >> 4) * 4 + r;

    int nkt = CAUSAL ? (q0 >> 6) + 1 : 16;

    for (int kt = 0; kt < nkt; ++kt) {
        int k0 = kt * 64;
        bool diag = CAUSAL && (kt == (q0 >> 6));

        f32x4 accs[4];
        #pragma unroll
        for (int jn = 0; jn < 4; ++jn) accs[jn] = zero4;
        #pragma unroll
        for (int ks = 0; ks < 2; ++ks) {
            int qm = w * 16 + lm;
            int qoff = qm * 64 + ((((ks << 2) + kg) ^ (qm & 7)) << 3);
            f16x8 ah = *(const f16x8*)&lQh[qoff];
            f16x8 al = *(const f16x8*)&lQl[qoff];
            #pragma unroll
            for (int jn = 0; jn < 4; ++jn) {
                int n = jn * 16 + lm;
                int koff = n * 64 + ((((ks << 2) + kg) ^ (n & 7)) << 3);
                f16x8 bhv = *(const f16x8*)&lKh[koff];
                f16x8 blv = *(const f16x8*)&lKl[koff];
                accs[jn] = __builtin_amdgcn_mfma_f32_16x16x32_f16(ah, bhv, accs[jn], 0, 0, 0);
                accs[jn] = __builtin_amdgcn_mfma_f32_16x16x32_f16(ah, blv, accs[jn], 0, 0, 0);
                accs[jn] = __builtin_amdgcn_mfma_f32_16x16x32_f16(al, bhv, accs[jn], 0, 0, 0);
            }
        }

        float sv[4][4];
        #pragma unroll
        for (int jn = 0; jn < 4; ++jn) {
            int kglob = k0 + jn * 16 + lm;
            bool pad_ok = (ktoks[tb + kglob] != 0);
            #pragma unroll
            for (int r = 0; r < 4; ++r) {
                float s = accs[jn][r] * 0.125f;
                bool keep = pad_ok && (!diag || kglob <= qrow[r]);
                sv[jn][r] = keep ? s : -1e9f;
            }
        }
        float pv[4][4];
        #pragma unroll
        for (int r = 0; r < 4; ++r) {
            float tm = fmaxf(fmaxf(sv[0][r], sv[1][r]), fmaxf(sv[2][r], sv[3][r]));
            tm = fmaxf(tm, __shfl_xor(tm, 1));
            tm = fmaxf(tm, __shfl_xor(tm, 2));
            tm = fmaxf(tm, __shfl_xor(tm, 4));
            tm = fmaxf(tm, __shfl_xor(tm, 8));
            float mnew = fmaxf(mreg[r], tm);
            float corr = expf(mreg[r] - mnew);
            lreg[r] *= corr;
            #pragma unroll
            for (int jn = 0; jn < 4; ++jn) od[jn][r] *= corr;
            float psum = 0.f;
            #pragma unroll
            for (int jn = 0; jn < 4; ++jn) {
                float p = expf(sv[jn][r] - mnew);
                pv[jn][r] = p;
                psum += p;
            }
            psum += __shfl_xor(psum, 1);
            psum += __shfl_xor(psum, 2);
            psum += __shfl_xor(psum, 4);
            psum += __shfl_xor(psum, 8);
            lreg[r] += psum;
            mreg[r] = mnew;
        }

        #pragma unroll
        for (int jn = 0; jn < 4; ++jn) {
            int col = jn * 16 + lm;
            #pragma unroll
            for (int r = 0; r < 4; ++r) {
                int row = w * 16 + (lane >> 4) * 4 + r;
                int idx = row * 64 + (((col >> 3) ^ (row & 7)) << 3) + (col & 7);
                _Float16 hh, ll; split_f16(pv[jn][r], hh, ll);
                lPh[idx] = hh; lPl[idx] = ll;
            }
        }

        #pragma unroll
        for (int ks = 0; ks < 2; ++ks) {
            int prow = w * 16 + lm;
            int poff = prow * 64 + ((((ks << 2) + kg) ^ (prow & 7)) << 3);
            f16x8 pah = *(const f16x8*)&lPh[poff];
            f16x8 pal = *(const f16x8*)&lPl[poff];
            #pragma unroll
            for (int jn = 0; jn < 4; ++jn) {
                int n = jn * 16 + lm;
                int noff = n * 64 + ((((ks << 2) + kg) ^ (n & 7)) << 3);
                f16x8 vbh = *(const f16x8*)&lVh[noff];
                f16x8 vbl = *(const f16x8*)&lVl[noff];
                od[jn] = __builtin_amdgcn_mfma_f32_16x16x32_f16(pah, vbh, od[jn], 0, 0, 0);
                od[jn] = __builtin_amdgcn_mfma_f32_16x16x32_f16(pah, vbl, od[jn], 0, 0, 0);
                od[jn] = __builtin_amdgcn_mfma_f32_16x16x32_f16(pal, vbh, od[jn], 0, 0, 0);
            }
        }
        __syncthreads();

        if (kt + 1 < nkt) {
            int k0n = (kt + 1) * 64;
            #pragma unroll
            for (int j = 0; j < 2; ++j) {
                int row = w * 16 + j * 8 + srow8;
                int lb = (w * 16 + j * 8) * 64;
                int ss = (q8 ^ (row & 7)) << 3;
                gload16(Kh + (size_t)(k0n + row) * QLD + ss, lKh + lb);
                gload16(Kl + (size_t)(k0n + row) * QLD + ss, lKl + lb);
                gload16(Vh + (size_t)row * 1024 + k0n + ss, lVh + lb);
                gload16(Vl + (size_t)row * 1024 + k0n + ss, lVl + lb);
            }
            __syncthreads();
        }
    }

    float inv[4];
    #pragma unroll
    for (int r = 0; r < 4; ++r) inv[r] = 1.0f / lreg[r];
    #pragma unroll
    for (int r = 0; r < 4; ++r) {
        size_t rbase = (size_t)(tb + qrow[r]) * D_ + h * DK_;
        #pragma unroll
        for (int jn = 0; jn < 4; ++jn) {
            float o = od[jn][r] * inv[r];
            _Float16 hh, ll; split_f16(o, hh, ll);
            int d = jn * 16 + lm;
            ch[rbase + d] = hh; cl[rbase + d] = ll;
        }
    }
}

// ---------------------------------------------------------------- residual + LayerNorm (f32 + hi/lo)
__global__ __launch_bounds__(256) void ln_add(const float* __restrict__ x,
                                              const float* __restrict__ r,
                                              const float* __restrict__ g,
                                              const float* __restrict__ be,
                                              float* __restrict__ o,
                                              _Float16* __restrict__ oh,
                                              _Float16* __restrict__ ol)
{
    int row = blockIdx.x;
    const float* xr = x + (size_t)row * D_;
    const float* rr = r + (size_t)row * D_;
    int tid = threadIdx.x;
    float v0 = xr[tid] + rr[tid];
    float v1 = xr[tid + 256] + rr[tid + 256];
    float s = v0 + v1;
    for (int off = 32; off; off >>= 1) s += __shfl_down(s, off);
    __shared__ float red[8];
    int lane = tid & 63, wid = tid >> 6;
    if (!lane) red[wid] = s;
    __syncthreads();
    if (!tid) red[4] = (red[0] + red[1] + red[2] + red[3]) * (1.0f / 512.0f);
    __syncthreads();
    float m = red[4];
    float d0 = v0 - m, d1 = v1 - m;
    s = d0 * d0 + d1 * d1;
    for (int off = 32; off; off >>= 1) s += __shfl_down(s, off);
    if (!lane) red[wid] = s;
    __syncthreads();
    if (!tid) red[5] = rsqrtf((red[0] + red[1] + red[2] + red[3]) * (1.0f / 512.0f) + 1e-5f);
    __syncthreads();
    float rstd = red[5];
    size_t rb = (size_t)row * D_;
    float y0 = d0 * rstd * g[tid] + be[tid];
    float y1 = d1 * rstd * g[tid + 256] + be[tid + 256];
    o[rb + tid] = y0; o[rb + tid + 256] = y1;
    _Float16 h, l;
    split_f16(y0, h, l); oh[rb + tid] = h; ol[rb + tid] = l;
    split_f16(y1, h, l); oh[rb + tid + 256] = h; ol[rb + tid + 256] = l;
}

// ---------------------------------------------------------------- MoE combine + residual + LN fused
__global__ __launch_bounds__(256) void ln_add_moe(const float* __restrict__ x,
                                                  const float* __restrict__ eo,
                                                  const float* __restrict__ topv,
                                                  const int* __restrict__ route_row,
                                                  const float* __restrict__ g,
                                                  const float* __restrict__ be,
                                                  float* __restrict__ o,
                                                  _Float16* __restrict__ oh,
                                                  _Float16* __restrict__ ol)
{
    int row = blockIdx.x;
    int r0 = route_row[row * 2], r1 = route_row[row * 2 + 1];
    float w0 = topv[row * 2], w1 = topv[row * 2 + 1];
    const float* xr = x + (size_t)row * D_;
    const float* e0 = eo + (size_t)r0 * D_;
    const float* e1 = eo + (size_t)r1 * D_;
    int tid = threadIdx.x;
    float v0 = xr[tid] + w0 * e0[tid] + w1 * e1[tid];
    float v1 = xr[tid + 256] + w0 * e0[tid + 256] + w1 * e1[tid + 256];
    float s = v0 + v1;
    for (int off = 32; off; off >>= 1) s += __shfl_down(s, off);
    __shared__ float red[8];
    int lane = tid & 63, wid = tid >> 6;
    if (!lane) red[wid] = s;
    __syncthreads();
    if (!tid) red[4] = (red[0] + red[1] + red[2] + red[3]) * (1.0f / 512.0f);
    __syncthreads();
    float m = red[4];
    float d0 = v0 - m, d1 = v1 - m;
    s = d0 * d0 + d1 * d1;
    for (int off = 32; off; off >>= 1) s += __shfl_down(s, off);
    if (!lane) red[wid] = s;
    __syncthreads();
    if (!tid) red[5] = rsqrtf((red[0] + red[1] + red[2] + red[3]) * (1.0f / 512.0f) + 1e-5f);
    __syncthreads();
    float rstd = red[5];
    size_t rb = (size_t)row * D_;
    float y0 = d0 * rstd * g[tid] + be[tid];
    float y1 = d1 * rstd * g[tid + 256] + be[tid + 256];
    o[rb + tid] = y0; o[rb + tid + 256] = y1;
    _Float16 h, l;
    split_f16(y0, h, l); oh[rb + tid] = h; ol[rb + tid] = l;
    split_f16(y1, h, l); oh[rb + tid + 256] = h; ol[rb + tid + 256] = l;
}

// ---------------------------------------------------------------- MoE gate logits
__global__ __launch_bounds__(256) void gate_logits(const float* __restrict__ xf,
                                                   const float* __restrict__ gw,
                                                   const float* __restrict__ gb,
                                                   float* __restrict__ lg)
{
    int id = blockIdx.x * 256 + threadIdx.x;
    if (id >= NTOK * E_) return;
    int e = id & 7, n = id >> 3;
    const float* x = xf + (size_t)n * D_;
    float s = gb[e];
    for (int d = 0; d < D_; ++d) s += x[d] * gw[d * E_ + e];
    lg[id] = s;
}

// ---------------------------------------------------------------- fused top2 + deterministic routing (64-granular)
__global__ __launch_bounds__(1024) void gate_top2_routes(const float* __restrict__ lg,
                                                         float* __restrict__ topv,
                                                         int* __restrict__ route_tok,
                                                         int* __restrict__ route_row,
                                                         int* __restrict__ counts,
                                                         int* __restrict__ pad_base,
                                                         int* __restrict__ rb_expert)
{
    __shared__ int eid[NTOK * 2];
    __shared__ unsigned short chist[256][8];
    __shared__ int pb[E_ + 1];
    __shared__ int cnt[E_];
    int t = threadIdx.x;
    #pragma unroll
    for (int s2 = 0; s2 < 2; ++s2) {
        int n = t * 2 + s2;
        float l0[E_], p[E_];
        float m = -1e30f;
        #pragma unroll
        for (int e = 0; e < E_; ++e) { l0[e] = lg[n * E_ + e]; m = fmaxf(m, l0[e]); }
        float su = 0.f;
        #pragma unroll
        for (int e = 0; e < E_; ++e) { p[e] = expf(l0[e] - m); su += p[e]; }
        float inv = 1.0f / su;
        int i1 = 0; float v1 = p[0];
        #pragma unroll
        for (int e = 1; e < E_; ++e) if (p[e] > v1) { v1 = p[e]; i1 = e; }
        int i2 = -1; float v2 = -1.f;
        #pragma unroll
        for (int e = 0; e < E_; ++e) if (e != i1 && p[e] > v2) { v2 = p[e]; i2 = e; }
        topv[n * 2] = v1 * inv; topv[n * 2 + 1] = v2 * inv;
        eid[n * 2] = i1; eid[n * 2 + 1] = i2;
    }
    #pragma unroll
    for (int g = 0; g < 5; ++g) route_tok[t + 1024 * g] = 0;
    __syncthreads();

    if (t < 256) {
        int r[16];
        #pragma unroll
        for (int i = 0; i < 16; ++i) r[i] = eid[t * 16 + i];
        #pragma unroll
        for (int e = 0; e < 8; ++e) {
            int h = 0;
            #pragma unroll
            for (int i = 0; i < 16; ++i) h += (r[i] == e) ? 1 : 0;
            chist[t][e] = (unsigned short)h;
        }
    }
    __syncthreads();

    if (t < 8) {
        int run = 0;
        for (int c = 0; c < 256; ++c) {
            int v = chist[c][t];
            chist[c][t] = (unsigned short)run;
            run += v;
        }
        cnt[t] = run;
        counts[t] = run;
    }
    __syncthreads();

    if (t == 0) {
        int pad = 0;
        for (int e = 0; e < 8; ++e) {
            pb[e] = pad;
            pad_base[e] = pad;
            int nb = (cnt[e] + 63) >> 6;
            for (int rb = 0; rb < nb; ++rb) rb_expert[(pad >> 6) + rb] = e;
            pad += nb << 6;
        }
        pb[8] = pad;
        pad_base[8] = pad;
    }
    __syncthreads();

    if (t < 256) {
        int r[16];
        #pragma unroll
        for (int i = 0; i < 16; ++i) r[i] = eid[t * 16 + i];
        #pragma unroll
        for (int e = 0; e < 8; ++e) {
            int o = pb[e] + chist[t][e];
            #pragma unroll
            for (int i = 0; i < 16; ++i) {
                if (r[i] == e) {
                    int slot = t * 16 + i;
                    route_tok[o] = slot >> 1;
                    route_row[slot] = o;
                    o++;
                }
            }
        }
    }
}

// ================================================================ host orchestration
extern "C" void kernel_launch(void* const* d_in, const int* in_sizes, int n_in,
                              void* d_out, int out_size, void* d_ws, size_t ws_size,
                              hipStream_t stream)
{
    const int*   src        = (const int*)  d_in[0];
    const int*   tgt        = (const int*)  d_in[1];
    const float* enc_emb    = (const float*)d_in[2];
    const float* dec_emb    = (const float*)d_in[3];
    const float* enc_attn_w = (const float*)d_in[4];
    const float* enc_attn_b = (const float*)d_in[5];
    const float* enc_ln_g   = (const float*)d_in[6];
    const float* enc_ln_b   = (const float*)d_in[7];
    const float* enc_gate_w = (const float*)d_in[8];
    const float* enc_gate_b = (const float*)d_in[9];
    const float* enc_w1     = (const float*)d_in[10];
    const float* enc_b1     = (const float*)d_in[11];
    const float* enc_w2     = (const float*)d_in[12];
    const float* enc_b2     = (const float*)d_in[13];
    const float* dec_sa_w   = (const float*)d_in[14];
    const float* dec_sa_b   = (const float*)d_in[15];
    const float* dec_ca_w   = (const float*)d_in[16];
    const float* dec_ca_b   = (const float*)d_in[17];
    const float* dec_ln_g   = (const float*)d_in[18];
    const float* dec_ln_b   = (const float*)d_in[19];
    const float* dec_gate_w = (const float*)d_in[20];
    const float* dec_gate_b = (const float*)d_in[21];
    const float* dec_w1     = (const float*)d_in[22];
    const float* dec_b1     = (const float*)d_in[23];
    const float* dec_w2     = (const float*)d_in[24];
    const float* dec_b2     = (const float*)d_in[25];
    const float* out_w      = (const float*)d_in[26];
    const float* out_b      = (const float*)d_in[27];
    float* out = (float*)d_out;

    // ---- d_out scratch (dead until final GEMM overwrites all of it)
    char* ob = (char*)d_out;
    size_t oc = 0;
    auto dalloc = [&](size_t bytes) { char* p = ob + oc; oc += (bytes + 255) & ~(size_t)255; return p; };
    _Float16* qkv_h  = (_Float16*)dalloc((size_t)NTOK * QLD * 2);
    _Float16* qkv_l  = (_Float16*)dalloc((size_t)NTOK * QLD * 2);
    _Float16* vt_h   = (_Float16*)dalloc((size_t)16 * 64 * 1024 * 2);
    _Float16* vt_l   = (_Float16*)dalloc((size_t)16 * 64 * 1024 * 2);
    float* aout  = (float*)dalloc((size_t)NTOK * D_ * 4);
    _Float16* ctx_h = (_Float16*)dalloc((size_t)NTOK * D_ * 2);
    _Float16* ctx_l = (_Float16*)dalloc((size_t)NTOK * D_ * 2);
    _Float16* encA_h = (_Float16*)dalloc((size_t)L_ * 4 * D_ * D_ * 2);
    _Float16* encA_l = (_Float16*)dalloc((size_t)L_ * 4 * D_ * D_ * 2);
    _Float16* saA_h  = (_Float16*)dalloc((size_t)L_ * 4 * D_ * D_ * 2);
    _Float16* saA_l  = (_Float16*)dalloc((size_t)L_ * 4 * D_ * D_ * 2);
    _Float16* caA_h  = (_Float16*)dalloc((size_t)L_ * 4 * D_ * D_ * 2);
    _Float16* caA_l  = (_Float16*)dalloc((size_t)L_ * 4 * D_ * D_ * 2);
    float* xA = (float*)dalloc((size_t)NTOK * D_ * 4);
    float* xB = (float*)dalloc((size_t)NTOK * D_ * 4);
    float* yA = (float*)dalloc((size_t)NTOK * D_ * 4);
    float* yB = (float*)dalloc((size_t)NTOK * D_ * 4);
    _Float16* xA_h = (_Float16*)dalloc((size_t)NTOK * D_ * 2);
    _Float16* xA_l = (_Float16*)dalloc((size_t)NTOK * D_ * 2);
    _Float16* xB_h = (_Float16*)dalloc((size_t)NTOK * D_ * 2);
    _Float16* xB_l = (_Float16*)dalloc((size_t)NTOK * D_ * 2);
    _Float16* yA_h = (_Float16*)dalloc((size_t)NTOK * D_ * 2);
    _Float16* yA_l = (_Float16*)dalloc((size_t)NTOK * D_ * 2);
    _Float16* yB_h = (_Float16*)dalloc((size_t)NTOK * D_ * 2);
    _Float16* yB_l = (_Float16*)dalloc((size_t)NTOK * D_ * 2);

    // ---- ws scratch
    char* wp = (char*)d_ws;
    size_t wc = 0;
    auto walloc = [&](size_t bytes) { char* p = wp + wc; wc += (bytes + 255) & ~(size_t)255; return p; };
    _Float16* outwT_h = (_Float16*)walloc((size_t)V_ * D_ * 2);
    _Float16* final_h = (_Float16*)walloc((size_t)NTOK * D_ * 2);
    _Float16* w1t_h   = (_Float16*)walloc((size_t)E_ * F_ * D_ * 2);
    _Float16* w1t_l   = (_Float16*)walloc((size_t)E_ * F_ * D_ * 2);
    _Float16* w2t_h   = (_Float16*)walloc((size_t)E_ * F_ * D_ * 2);
    _Float16* w2t_l   = (_Float16*)walloc((size_t)E_ * F_ * D_ * 2);
    _Float16* hbuf_h  = (_Float16*)walloc((size_t)MAXPAD * F_ * 2);
    _Float16* hbuf_l  = (_Float16*)walloc((size_t)MAXPAD * F_ * 2);
    float*    eobuf   = (float*)walloc((size_t)MAXPAD * D_ * 4);
    float* lg   = (float*)walloc((size_t)NTOK * E_ * 4);
    float* topv = (float*)walloc((size_t)NTOK * 2 * 4);
    int*   route_tok = (int*)walloc((size_t)5120 * 4);
    int*   route_row = (int*)walloc((size_t)NTOK * 2 * 4);
    int*   counts    = (int*)walloc(64);
    int*   pad_base  = (int*)walloc(64);
    int*   rb_expert = (int*)walloc((size_t)128 * 4);

    // ---- weight transposes (once per launch)
    transpose_w<true><<<dim3(8, 8, 8), 256, 0, stream>>>(enc_attn_w, encA_h, encA_l, D_, D_);
    transpose_w<true><<<dim3(8, 8, 8), 256, 0, stream>>>(dec_sa_w, saA_h, saA_l, D_, D_);
    transpose_w<true><<<dim3(8, 8, 8), 256, 0, stream>>>(dec_ca_w, caA_h, caA_l, D_, D_);
    transpose_w<false><<<dim3(500, 8, 1), 256, 0, stream>>>(out_w, outwT_h, nullptr, D_, V_);

    auto run_mha = [&](const _Float16* q_h, const _Float16* q_l,
                       const _Float16* kv_h, const _Float16* kv_l,
                       const _Float16* wT_h, const _Float16* wT_l, const float* bt,
                       const int* ktoks, int causal, bool fused) {
        if (fused) {
            gemm_mfma<0, false, 2, 3, 64, 128><<<dim3(32, 12), 256, 0, stream>>>(
                q_h, q_l, wT_h, wT_l, bt, nullptr, qkv_h, qkv_l, vt_h, vt_l, 0,
                NTOK, D_, 1536, QLD, nullptr, nullptr, nullptr, nullptr);
        } else {
            gemm_mfma<0, false, 1, 3, 64, 64><<<dim3(32, 8), 256, 0, stream>>>(
                q_h, q_l, wT_h, wT_l, bt, nullptr, qkv_h, qkv_l, nullptr, nullptr, 0,
                NTOK, D_, 512, QLD, nullptr, nullptr, nullptr, nullptr);
            gemm_mfma<0, false, 2, 3, 64, 128><<<dim3(32, 8), 256, 0, stream>>>(
                kv_h, kv_l, wT_h + (size_t)D_ * D_, wT_l + (size_t)D_ * D_, bt + D_,
                nullptr, qkv_h, qkv_l, vt_h, vt_l, 512,
                NTOK, D_, 1024, QLD, nullptr, nullptr, nullptr, nullptr);
        }
        if (causal)
            attn_flash<1><<<dim3(16, 16), 256, 0, stream>>>(qkv_h, qkv_l, vt_h, vt_l, ktoks, ctx_h, ctx_l);
        else
            attn_flash<0><<<dim3(16, 16), 256, 0, stream>>>(qkv_h, qkv_l, vt_h, vt_l, ktoks, ctx_h, ctx_l);
        gemm_mfma<0, false, 0, 3, 64, 64><<<dim3(32, 8), 256, 0, stream>>>(
            ctx_h, ctx_l, wT_h + (size_t)3 * D_ * D_, wT_l + (size_t)3 * D_ * D_,
            bt + 3 * D_, aout, nullptr, nullptr, nullptr, nullptr, 0,
            NTOK, D_, 512, 512, nullptr, nullptr, nullptr, nullptr);
    };

    auto run_moe = [&](const float* x, const _Float16* x_h, const _Float16* x_l,
                       const float* gwp, const float* gbp,
                       const float* w1p, const float* b1p,
                       const float* w2p, const float* b2p) {
        gate_logits<<<NTOK * E_ / 256, 256, 0, stream>>>(x, gwp, gbp, lg);
        gate_top2_routes<<<1, 1024, 0, stream>>>(lg, topv, route_tok, route_row, counts, pad_base, rb_expert);
        transpose_w<true><<<dim3(32, 8, 8), 256, 0, stream>>>(w1p, w1t_h, w1t_l, D_, F_);
        transpose_w<true><<<dim3(8, 32, 8), 256, 0, stream>>>(w2p, w2t_h, w2t_l, F_, D_);
        gemm_mfma<1, true, 1, 3, 64, 128><<<dim3(RB64, 16), 256, 0, stream>>>(
            x_h, x_l, w1t_h, w1t_l, b1p, nullptr, hbuf_h, hbuf_l, nullptr, nullptr, 0,
            0, D_, F_, F_, route_tok, rb_expert, pad_base, counts);
        gemm_mfma<2, false, 0, 3, 64, 64><<<dim3(RB64, 8), 256, 0, stream>>>(
            hbuf_h, hbuf_l, w2t_h, w2t_l, b2p, eobuf, nullptr, nullptr, nullptr, nullptr, 0,
            0, F_, D_, D_, route_tok, rb_expert, pad_base, counts);
    };

    // ---------------- encoder ----------------
    embed_pe<<<B_ * S_, 256, 0, stream>>>(src, enc_emb, xA, xA_h, xA_l, S_);
    float* cur = xA; float* alt = xB;
    _Float16* cur_h = xA_h; _Float16* cur_l = xA_l;
    _Float16* alt_h = xB_h; _Float16* alt_l = xB_l;
    for (int l = 0; l < L_; ++l) {
        run_mha(cur_h, cur_l, nullptr, nullptr,
                encA_h + (size_t)l * 4 * D_ * D_, encA_l + (size_t)l * 4 * D_ * D_,
                enc_attn_b + (size_t)l * 4 * D_, src, 0, true);
        ln_add<<<NTOK, 256, 0, stream>>>(cur, aout,
            enc_ln_g + (size_t)(l * 2 + 0) * D_, enc_ln_b + (size_t)(l * 2 + 0) * D_,
            alt, alt_h, alt_l);
        { float* t = cur; cur = alt; alt = t; }
        { _Float16* t = cur_h; cur_h = alt_h; alt_h = t; t = cur_l; cur_l = alt_l; alt_l = t; }
        run_moe(cur, cur_h, cur_l, enc_gate_w + (size_t)l * D_ * E_, enc_gate_b + (size_t)l * E_,
                enc_w1 + (size_t)l * E_ * D_ * F_, enc_b1 + (size_t)l * E_ * F_,
                enc_w2 + (size_t)l * E_ * F_ * D_, enc_b2 + (size_t)l * E_ * D_);
        ln_add_moe<<<NTOK, 256, 0, stream>>>(cur, eobuf, topv, route_row,
            enc_ln_g + (size_t)(l * 2 + 1) * D_, enc_ln_b + (size_t)(l * 2 + 1) * D_,
            alt, alt_h, alt_l);
        { float* t = cur; cur = alt; alt = t; }
        { _Float16* t = cur_h; cur_h = alt_h; alt_h = t; t = cur_l; cur_l = alt_l; alt_l = t; }
    }
    _Float16* enc_h = cur_h; _Float16* enc_l = cur_l;

    // ---------------- decoder ----------------
    embed_pe<<<B_ * T_, 256, 0, stream>>>(tgt, dec_emb, yA, yA_h, yA_l, T_);
    float* dc = yA; float* da = yB;
    _Float16* dc_h = yA_h; _Float16* dc_l = yA_l;
    _Float16* da_h = yB_h; _Float16* da_l = yB_l;
    for (int l = 0; l < L_; ++l) {
        run_mha(dc_h, dc_l, nullptr, nullptr,
                saA_h + (size_t)l * 4 * D_ * D_, saA_l + (size_t)l * 4 * D_ * D_,
                dec_sa_b + (size_t)l * 4 * D_, tgt, 1, true);
        ln_add<<<NTOK, 256, 0, stream>>>(dc, aout,
            dec_ln_g + (size_t)(l * 3 + 0) * D_, dec_ln_b + (size_t)(l * 3 + 0) * D_,
            da, da_h, da_l);
        { float* t = dc; dc = da; da = t; }
        { _Float16* t = dc_h; dc_h = da_h; da_h = t; t = dc_l; dc_l = da_l; da_l = t; }
        run_mha(dc_h, dc_l, enc_h, enc_l,
                caA_h + (size_t)l * 4 * D_ * D_, caA_l + (size_t)l * 4 * D_ * D_,
                dec_ca_b + (size_t)l * 4 * D_, src, 0, false);
        ln_add<<<NTOK, 256, 0, stream>>>(dc, aout,
            dec_ln_g + (size_t)(l * 3 + 1) * D_, dec_ln_b + (size_t)(l * 3 + 1) * D_,
            da, da_h, da_l);
        { float* t = dc; dc = da; da = t; }
        { _Float16* t = dc_h; dc_h = da_h; da_h = t; t = dc_l; dc_l = da_l; da_l = t; }
        run_moe(dc, dc_h, dc_l, dec_gate_w + (size_t)l * D_ * E_, dec_gate_b + (size_t)l * E_,
                dec_w1 + (size_t)l * E_ * D_ * F_, dec_b1 + (size_t)l * E_ * F_,
                dec_w2 + (size_t)l * E_ * F_ * D_, dec_b2 + (size_t)l * E_ * D_);
        bool last = (l == L_ - 1);
        ln_add_moe<<<NTOK, 256, 0, stream>>>(dc, eobuf, topv, route_row,
            dec_ln_g + (size_t)(l * 3 + 2) * D_, dec_ln_b + (size_t)(l * 3 + 2) * D_,
            da, last ? final_h : da_h, da_l);
        { float* t = dc; dc = da; da = t; }
        { _Float16* t = dc_h; dc_h = da_h; da_h = t; t = dc_l; dc_l = da_l; da_l = t; }
    }

    // ---------------- final projection (single-pass f16 MFMA; overwrites all of d_out)
    gemm_mfma<0, false, 0, 1, 128, 128><<<dim3(NTOK / 128, V_ / 128), 256, 0, stream>>>(
        final_h, nullptr, outwT_h, nullptr, out_b, out, nullptr, nullptr, nullptr, nullptr, 0,
        NTOK, D_, V_, V_, nullptr, nullptr, nullptr, nullptr);
}

// Round 7
// 1258.251 us; speedup vs baseline: 4.6932x; 1.0621x over previous
//
#include <hip/hip_runtime.h>
#include <hip/hip_bf16.h>

#define L_ 2
#define D_ 512
#define H_ 8
#define DK_ 64
#define F_ 2048
#define E_ 8
#define V_ 32000
#define B_ 2
#define S_ 1024
#define T_ 1024
#define NTOK (B_*S_)
#define MAXPAD 4608            // per-expert 64-padded total upper bound
#define RB64   72              // MAXPAD/64
#define QLD 1536

typedef unsigned short u16;
typedef _Float16 f16x8 __attribute__((ext_vector_type(8)));
typedef _Float16 f16x4 __attribute__((ext_vector_type(4)));
typedef float f32x4 __attribute__((ext_vector_type(4)));

__device__ __forceinline__ void gload16(const void* g, const void* l) {
    __builtin_amdgcn_global_load_lds(
        (const __attribute__((address_space(1))) void*)g,
        (__attribute__((address_space(3))) void*)l, 16, 0, 0);
}

__device__ __forceinline__ void split_f16(float v, _Float16& h, _Float16& l) {
    h = (_Float16)v;
    l = (_Float16)(v - (float)h);
}

// ---------------------------------------------------------------- embedding + PE (hi/lo f16 only)
__global__ __launch_bounds__(256) void embed_pe(const int* __restrict__ toks,
                                                const float* __restrict__ emb,
                                                _Float16* __restrict__ oh,
                                                _Float16* __restrict__ ol, int Slen)
{
    int n = blockIdx.x;
    int spos = n % Slen;
    int tok = toks[n];
    const float* erow = emb + (size_t)tok * D_;
    size_t rb = (size_t)n * D_;
    for (int j = threadIdx.x; j < D_; j += 256) {
        int i = j >> 1;
        float arg = (float)spos * expf(-(float)i * 0.035977892f);
        float pe = (j & 1) ? cosf(arg) : sinf(arg);
        float v = erow[j] + pe;
        _Float16 h, l; split_f16(v, h, l);
        oh[rb + j] = h; ol[rb + j] = l;
    }
}

// ---------------------------------------------------------------- weight transpose f32[R][C] -> f16 hi/lo [C][R]
template<bool WLO>
__global__ __launch_bounds__(256) void transpose_w(const float* __restrict__ in,
                                                   _Float16* __restrict__ oh,
                                                   _Float16* __restrict__ ol, int R, int C)
{
    __shared__ float t[64][65];
    size_t sb = (size_t)blockIdx.z * R * C;
    in += sb; oh += sb; if (WLO) ol += sb;
    int c0 = blockIdx.x * 64, r0 = blockIdx.y * 64;
    int tid = threadIdx.x;
    int cc = tid & 63, r4 = tid >> 6;
    #pragma unroll
    for (int p = 0; p < 16; ++p) {
        int r = p * 4 + r4;
        t[r][cc] = in[(size_t)(r0 + r) * C + c0 + cc];
    }
    __syncthreads();
    int rr = tid & 63, c4 = tid >> 6;
    #pragma unroll
    for (int p = 0; p < 16; ++p) {
        int c = p * 4 + c4;
        float v = t[rr][c];
        _Float16 h = (_Float16)v;
        oh[(size_t)(c0 + c) * R + r0 + rr] = h;
        if (WLO) ol[(size_t)(c0 + c) * R + r0 + rr] = (_Float16)(v - (float)h);
    }
}

// ---------------------------------------------------------------- MFMA GEMM (tile-templated)
template<int MODE, bool RELU, int OUTMODE, int PASSES, int TM, int TN>
__global__ __launch_bounds__(256, 2) void gemm_mfma(
    const _Float16* __restrict__ Ah, const _Float16* __restrict__ Al,
    const _Float16* __restrict__ Wh, const _Float16* __restrict__ Wl,
    const float* __restrict__ biasbase,
    float* __restrict__ Cf, _Float16* __restrict__ Ch, _Float16* __restrict__ Cl,
    _Float16* __restrict__ vt_h, _Float16* __restrict__ vt_l, int cbase,
    int M, int Kd, int N, int ldc,
    const int* __restrict__ route_tok, const int* __restrict__ rb_expert,
    const int* __restrict__ pad_base, const int* __restrict__ counts)
{
    constexpr int AR = TM / 32;
    constexpr int BR = TN / 32;
    int row0 = blockIdx.x * TM;
    const _Float16* Wmh = Wh;
    const _Float16* Wml = Wl;
    const float* bias = biasbase;
    int vend = M;
    if (MODE != 0) {
        int total = pad_base[E_];
        if (row0 >= total) return;
        int e = rb_expert[row0 >> 6];
        vend = pad_base[e] + counts[e];
        Wmh = Wh + (size_t)e * Kd * N;
        if (PASSES == 3) Wml = Wl + (size_t)e * Kd * N;
        bias = biasbase + (size_t)e * N;
    }
    int col0 = blockIdx.y * TN;
    int tid = threadIdx.x;
    int lane = tid & 63, w = tid >> 6;
    int wm = w >> 1, wn = w & 1;

    __shared__ _Float16 lds[(PASSES == 3 ? 2 : 1) * (TM + TN) * 64];
    _Float16* lAh = lds;
    _Float16* lBh = lds + TM * 64;
    _Float16* lAl = (PASSES == 3) ? lds + (TM + TN) * 64 : nullptr;
    _Float16* lBl = (PASSES == 3) ? lds + (TM + TN) * 64 + TM * 64 : nullptr;

    int srow8 = lane >> 3;
    int q8 = lane & 7;
    size_t aoff[AR], boff[BR];
    #pragma unroll
    for (int j = 0; j < AR; ++j) {
        int m = w * (TM / 4) + j * 8 + srow8;
        int gr = row0 + m;
        int ar = (MODE == 1) ? route_tok[gr] : gr;
        int ss = (q8 ^ (m & 7)) << 3;
        aoff[j] = (size_t)ar * Kd + ss;
    }
    #pragma unroll
    for (int j = 0; j < BR; ++j) {
        int m = w * (TN / 4) + j * 8 + srow8;
        int ss = (q8 ^ (m & 7)) << 3;
        boff[j] = (size_t)(col0 + m) * Kd + ss;
    }

    f32x4 zero4 = {0.f, 0.f, 0.f, 0.f};
    f32x4 acc[AR][BR];
    #pragma unroll
    for (int i = 0; i < AR; ++i)
        #pragma unroll
        for (int j = 0; j < BR; ++j) acc[i][j] = zero4;

    int lm = lane & 15, kg = lane >> 4;

    for (int k0 = 0; k0 < Kd; k0 += 64) {
        #pragma unroll
        for (int j = 0; j < AR; ++j) {
            int lb = (w * (TM / 4) + j * 8) * 64;
            gload16(Ah + aoff[j] + k0, lAh + lb);
            if (PASSES == 3) gload16(Al + aoff[j] + k0, lAl + lb);
        }
        #pragma unroll
        for (int j = 0; j < BR; ++j) {
            int lb = (w * (TN / 4) + j * 8) * 64;
            gload16(Wmh + boff[j] + k0, lBh + lb);
            if (PASSES == 3) gload16(Wml + boff[j] + k0, lBl + lb);
        }
        __syncthreads();
        #pragma unroll
        for (int ks = 0; ks < 2; ++ks) {
            f16x8 ah[AR], bh[BR];
            #pragma unroll
            for (int i = 0; i < AR; ++i) {
                int m = wm * (TM / 2) + i * 16 + lm;
                ah[i] = *(const f16x8*)&lAh[m * 64 + ((((ks << 2) + kg) ^ (m & 7)) << 3)];
            }
            #pragma unroll
            for (int j = 0; j < BR; ++j) {
                int n = wn * (TN / 2) + j * 16 + lm;
                bh[j] = *(const f16x8*)&lBh[n * 64 + ((((ks << 2) + kg) ^ (n & 7)) << 3)];
            }
            #pragma unroll
            for (int i = 0; i < AR; ++i)
                #pragma unroll
                for (int jn = 0; jn < BR; ++jn)
                    acc[i][jn] = __builtin_amdgcn_mfma_f32_16x16x32_f16(ah[i], bh[jn], acc[i][jn], 0, 0, 0);
            if (PASSES == 3) {
                f16x8 bl[BR];
                #pragma unroll
                for (int j = 0; j < BR; ++j) {
                    int n = wn * (TN / 2) + j * 16 + lm;
                    bl[j] = *(const f16x8*)&lBl[n * 64 + ((((ks << 2) + kg) ^ (n & 7)) << 3)];
                }
                #pragma unroll
                for (int i = 0; i < AR; ++i)
                    #pragma unroll
                    for (int jn = 0; jn < BR; ++jn)
                        acc[i][jn] = __builtin_amdgcn_mfma_f32_16x16x32_f16(ah[i], bl[jn], acc[i][jn], 0, 0, 0);
                f16x8 al[AR];
                #pragma unroll
                for (int i = 0; i < AR; ++i) {
                    int m = wm * (TM / 2) + i * 16 + lm;
                    al[i] = *(const f16x8*)&lAl[m * 64 + ((((ks << 2) + kg) ^ (m & 7)) << 3)];
                }
                #pragma unroll
                for (int i = 0; i < AR; ++i)
                    #pragma unroll
                    for (int jn = 0; jn < BR; ++jn)
                        acc[i][jn] = __builtin_amdgcn_mfma_f32_16x16x32_f16(al[i], bh[jn], acc[i][jn], 0, 0, 0);
            }
        }
        __syncthreads();
    }

    float bv[BR];
    #pragma unroll
    for (int jn = 0; jn < BR; ++jn) bv[jn] = bias[col0 + wn * (TN / 2) + jn * 16 + lm];
    int rowb = row0 + wm * (TM / 2) + (lane >> 4) * 4;

    if (OUTMODE == 2 && (col0 + cbase) >= 1024) {
        #pragma unroll
        for (int i = 0; i < AR; ++i) {
            int row = rowb + i * 16;
            int b = row >> 10, q = row & 1023;
            #pragma unroll
            for (int jn = 0; jn < BR; ++jn) {
                int vcol = col0 + cbase - 1024 + wn * (TN / 2) + jn * 16 + lm;
                int hh = vcol >> 6, dd = vcol & 63;
                f16x4 hv, lv;
                #pragma unroll
                for (int r = 0; r < 4; ++r) {
                    float v = acc[i][jn][r] + bv[jn];
                    _Float16 x1, x2; split_f16(v, x1, x2);
                    hv[r] = x1; lv[r] = x2;
                }
                size_t vtoff = ((size_t)((b << 3) + hh) * 64 + dd) * 1024 + q;
                *(f16x4*)&vt_h[vtoff] = hv;
                *(f16x4*)&vt_l[vtoff] = lv;
            }
        }
        return;
    }

    #pragma unroll
    for (int i = 0; i < AR; ++i) {
        #pragma unroll
        for (int r = 0; r < 4; ++r) {
            int row = rowb + i * 16 + r;
            if (MODE != 0 && row >= vend) continue;
            #pragma unroll
            for (int jn = 0; jn < BR; ++jn) {
                float v = acc[i][jn][r] + bv[jn];
                if (RELU) v = fmaxf(v, 0.f);
                int c = col0 + wn * (TN / 2) + jn * 16 + lm;
                if (OUTMODE == 0) {
                    Cf[(size_t)row * ldc + c] = v;
                } else {
                    _Float16 h, l; split_f16(v, h, l);
                    Ch[(size_t)row * ldc + cbase + c] = h;
                    Cl[(size_t)row * ldc + cbase + c] = l;
                }
            }
        }
    }
}

// ---------------------------------------------------------------- flash attention, 8-wave split-K
// grid (16 q-tiles, 16 bh), 512 thr. wave w: qg=w&3 owns 16 q-rows; kh=w>>2 picks k-tiles 2i+kh.
template<int CAUSAL>
__global__ __launch_bounds__(512, 1) void attn_flash(
    const _Float16* __restrict__ qkvh, const _Float16* __restrict__ qkvl,
    const _Float16* __restrict__ vth, const _Float16* __restrict__ vtl,
    const int* __restrict__ ktoks,
    _Float16* __restrict__ ch, _Float16* __restrict__ cl)
{
    int q0 = blockIdx.x * 64;
    int bh = blockIdx.y, b = bh >> 3, h = bh & 7;
    int tid = threadIdx.x, lane = tid & 63, w = tid >> 6;
    int qg = w & 3, kh = w >> 2;
    int lm = lane & 15, kg = lane >> 4;
    int srow8 = lane >> 3, q8 = lane & 7;
    int tb = b * S_;

    __shared__ _Float16 smem[49152];     // 96 KB: K/V 2 halves (64KB) + P (32KB)
    _Float16* hb  = smem + kh * 16384;
    _Float16* lKh = hb;
    _Float16* lKl = hb + 4096;
    _Float16* lVh = hb + 8192;
    _Float16* lVl = hb + 12288;
    _Float16* lPh = smem + 32768 + w * 1024;
    _Float16* lPl = smem + 40960 + w * 1024;

    size_t qbase = (size_t)b * S_ * QLD + h * DK_;
    const _Float16* Qh = qkvh + qbase;
    const _Float16* Ql = qkvl + qbase;
    const _Float16* Kh = qkvh + qbase + 512;
    const _Float16* Kl = qkvl + qbase + 512;
    const _Float16* Vh = vth + (size_t)bh * 64 * 1024;
    const _Float16* Vl = vtl + (size_t)bh * 64 * 1024;

    // Q fragments in registers (per wave: 16 rows, loaded once)
    f16x8 qfh[2], qfl[2];
    {
        int qr = q0 + qg * 16 + lm;
        #pragma unroll
        for (int ks = 0; ks < 2; ++ks) {
            qfh[ks] = *(const f16x8*)&Qh[(size_t)qr * QLD + ks * 32 + kg * 8];
            qfl[ks] = *(const f16x8*)&Ql[(size_t)qr * QLD + ks * 32 + kg * 8];
        }
    }

    float mreg[4], lreg[4];
    f32x4 od[4];
    f32x4 zero4 = {0.f, 0.f, 0.f, 0.f};
    #pragma unroll
    for (int r = 0; r < 4; ++r) { mreg[r] = -1e30f; lreg[r] = 0.f; }
    #pragma unroll
    for (int jn = 0; jn < 4; ++jn) od[jn] = zero4;

    int qrow[4];
    #pragma unroll
    for (int r = 0; r < 4; ++r) qrow[r] = q0 + qg * 16 + (lane >> 4) * 4 + r;

    int nkt = CAUSAL ? (q0 >> 6) + 1 : 16;
    int nhalf = (nkt + 1) >> 1;

    for (int it = 0; it < nhalf; ++it) {
        int kt = 2 * it + kh;
        bool active = kt < nkt;
        int k0 = kt * 64;

        if (active) {
            // this half's 4 waves stage its K/V tile (16 rows each)
            #pragma unroll
            for (int j = 0; j < 2; ++j) {
                int row = qg * 16 + j * 8 + srow8;
                int lb = (qg * 16 + j * 8) * 64;
                int ss = (q8 ^ (row & 7)) << 3;
                gload16(Kh + (size_t)(k0 + row) * QLD + ss, lKh + lb);
                gload16(Kl + (size_t)(k0 + row) * QLD + ss, lKl + lb);
                gload16(Vh + (size_t)row * 1024 + k0 + ss, lVh + lb);
                gload16(Vl + (size_t)row * 1024 + k0 + ss, lVl + lb);
            }
        }
        __syncthreads();

        if (active) {
            bool diag = CAUSAL && (kt == (q0 >> 6));
            f32x4 accs[4];
            #pragma unroll
            for (int jn = 0; jn < 4; ++jn) accs[jn] = zero4;
            #pragma unroll
            for (int ks = 0; ks < 2; ++ks) {
                #pragma unroll
                for (int jn = 0; jn < 4; ++jn) {
                    int n = jn * 16 + lm;
                    int koff = n * 64 + ((((ks << 2) + kg) ^ (n & 7)) << 3);
                    f16x8 bhv = *(const f16x8*)&lKh[koff];
                    f16x8 blv = *(const f16x8*)&lKl[koff];
                    accs[jn] = __builtin_amdgcn_mfma_f32_16x16x32_f16(qfh[ks], bhv, accs[jn], 0, 0, 0);
                    accs[jn] = __builtin_amdgcn_mfma_f32_16x16x32_f16(qfh[ks], blv, accs[jn], 0, 0, 0);
                    accs[jn] = __builtin_amdgcn_mfma_f32_16x16x32_f16(qfl[ks], bhv, accs[jn], 0, 0, 0);
                }
            }

            float sv[4][4];
            #pragma unroll
            for (int jn = 0; jn < 4; ++jn) {
                int kglob = k0 + jn * 16 + lm;
                bool pad_ok = (ktoks[tb + kglob] != 0);
                #pragma unroll
                for (int r = 0; r < 4; ++r) {
                    float s = accs[jn][r] * 0.125f;
                    bool keep = pad_ok && (!diag || kglob <= qrow[r]);
                    sv[jn][r] = keep ? s : -1e9f;
                }
            }
            float pv[4][4];
            #pragma unroll
            for (int r = 0; r < 4; ++r) {
                float tm = fmaxf(fmaxf(sv[0][r], sv[1][r]), fmaxf(sv[2][r], sv[3][r]));
                tm = fmaxf(tm, __shfl_xor(tm, 1));
                tm = fmaxf(tm, __shfl_xor(tm, 2));
                tm = fmaxf(tm, __shfl_xor(tm, 4));
                tm = fmaxf(tm, __shfl_xor(tm, 8));
                float mnew = fmaxf(mreg[r], tm);
                float corr = expf(mreg[r] - mnew);
                lreg[r] *= corr;
                #pragma unroll
                for (int jn = 0; jn < 4; ++jn) od[jn][r] *= corr;
                float psum = 0.f;
                #pragma unroll
                for (int jn = 0; jn < 4; ++jn) {
                    float p = expf(sv[jn][r] - mnew);
                    pv[jn][r] = p;
                    psum += p;
                }
                psum += __shfl_xor(psum, 1);
                psum += __shfl_xor(psum, 2);
                psum += __shfl_xor(psum, 4);
                psum += __shfl_xor(psum, 8);
                lreg[r] += psum;
                mreg[r] = mnew;
            }

            // P hi/lo into wave-private LDS (16 rows x 64)
            #pragma unroll
            for (int jn = 0; jn < 4; ++jn) {
                int col = jn * 16 + lm;
                #pragma unroll
                for (int r = 0; r < 4; ++r) {
                    int rr = (lane >> 4) * 4 + r;
                    int idx = rr * 64 + (((col >> 3) ^ (rr & 7)) << 3) + (col & 7);
                    _Float16 hh, ll; split_f16(pv[jn][r], hh, ll);
                    lPh[idx] = hh; lPl[idx] = ll;
                }
            }

            #pragma unroll
            for (int ks = 0; ks < 2; ++ks) {
                int poff = lm * 64 + ((((ks << 2) + kg) ^ (lm & 7)) << 3);
                f16x8 pah = *(const f16x8*)&lPh[poff];
                f16x8 pal = *(const f16x8*)&lPl[poff];
                #pragma unroll
                for (int jn = 0; jn < 4; ++jn) {
                    int n = jn * 16 + lm;
                    int noff = n * 64 + ((((ks << 2) + kg) ^ (n & 7)) << 3);
                    f16x8 vbh = *(const f16x8*)&lVh[noff];
                    f16x8 vbl = *(const f16x8*)&lVl[noff];
                    od[jn] = __builtin_amdgcn_mfma_f32_16x16x32_f16(pah, vbh, od[jn], 0, 0, 0);
                    od[jn] = __builtin_amdgcn_mfma_f32_16x16x32_f16(pah, vbl, od[jn], 0, 0, 0);
                    od[jn] = __builtin_amdgcn_mfma_f32_16x16x32_f16(pal, vbh, od[jn], 0, 0, 0);
                }
            }
        }
        __syncthreads();
    }

    // ---- merge the two split-K states (reuse P region as float scratch)
    float* mrg = (float*)(smem + 32768);
    if (kh == 1) {
        float* mp = mrg + ((size_t)qg * 64 + lane) * 24;
        #pragma unroll
        for (int jn = 0; jn < 4; ++jn)
            #pragma unroll
            for (int r = 0; r < 4; ++r) mp[jn * 4 + r] = od[jn][r];
        #pragma unroll
        for (int r = 0; r < 4; ++r) { mp[16 + r] = mreg[r]; mp[20 + r] = lreg[r]; }
    }
    __syncthreads();
    if (kh == 0) {
        float* mp = mrg + ((size_t)qg * 64 + lane) * 24;
        #pragma unroll
        for (int r = 0; r < 4; ++r) {
            float m1 = mp[16 + r], l1 = mp[20 + r];
            float m = fmaxf(mreg[r], m1);
            float c0 = expf(mreg[r] - m), c1 = expf(m1 - m);
            float inv = 1.0f / (lreg[r] * c0 + l1 * c1);
            size_t rbase = (size_t)(tb + qrow[r]) * D_ + h * DK_;
            #pragma unroll
            for (int jn = 0; jn < 4; ++jn) {
                float o = (od[jn][r] * c0 + mp[jn * 4 + r] * c1) * inv;
                _Float16 hh, ll; split_f16(o, hh, ll);
                int d = jn * 16 + lm;
                ch[rbase + d] = hh; cl[rbase + d] = ll;
            }
        }
    }
}

// ---------------------------------------------------------------- residual + LN (+ optional fused gate logits)
template<bool GATE>
__global__ __launch_bounds__(256) void ln_add(const _Float16* __restrict__ xh,
                                              const _Float16* __restrict__ xl,
                                              const float* __restrict__ r,
                                              const float* __restrict__ g,
                                              const float* __restrict__ be,
                                              _Float16* __restrict__ oh,
                                              _Float16* __restrict__ ol,
                                              const float* __restrict__ gw,
                                              const float* __restrict__ gb,
                                              float* __restrict__ lg)
{
    int row = blockIdx.x;
    size_t rb = (size_t)row * D_;
    int tid = threadIdx.x;
    float v0 = (float)xh[rb + tid] + (float)xl[rb + tid] + r[rb + tid];
    float v1 = (float)xh[rb + tid + 256] + (float)xl[rb + tid + 256] + r[rb + tid + 256];
    float s = v0 + v1;
    for (int off = 32; off; off >>= 1) s += __shfl_down(s, off);
    __shared__ float red[8];
    __shared__ float gred[4][E_];
    int lane = tid & 63, wid = tid >> 6;
    if (!lane) red[wid] = s;
    __syncthreads();
    if (!tid) red[4] = (red[0] + red[1] + red[2] + red[3]) * (1.0f / 512.0f);
    __syncthreads();
    float m = red[4];
    float d0 = v0 - m, d1 = v1 - m;
    s = d0 * d0 + d1 * d1;
    for (int off = 32; off; off >>= 1) s += __shfl_down(s, off);
    if (!lane) red[wid] = s;
    __syncthreads();
    if (!tid) red[5] = rsqrtf((red[0] + red[1] + red[2] + red[3]) * (1.0f / 512.0f) + 1e-5f);
    __syncthreads();
    float rstd = red[5];
    float y0 = d0 * rstd * g[tid] + be[tid];
    float y1 = d1 * rstd * g[tid + 256] + be[tid + 256];
    _Float16 h, l;
    split_f16(y0, h, l); oh[rb + tid] = h; ol[rb + tid] = l;
    split_f16(y1, h, l); oh[rb + tid + 256] = h; ol[rb + tid + 256] = l;
    if (GATE) {
        float acc[E_];
        const float* g0 = gw + (size_t)tid * E_;
        const float* g1 = gw + (size_t)(tid + 256) * E_;
        #pragma unroll
        for (int e = 0; e < E_; ++e) acc[e] = y0 * g0[e] + y1 * g1[e];
        #pragma unroll
        for (int e = 0; e < E_; ++e)
            for (int off = 32; off; off >>= 1) acc[e] += __shfl_down(acc[e], off);
        if (!lane) {
            #pragma unroll
            for (int e = 0; e < E_; ++e) gred[wid][e] = acc[e];
        }
        __syncthreads();
        if (tid < E_)
            lg[(size_t)row * E_ + tid] = gred[0][tid] + gred[1][tid] + gred[2][tid] + gred[3][tid] + gb[tid];
    }
}

// ---------------------------------------------------------------- MoE combine + residual + LN fused
__global__ __launch_bounds__(256) void ln_add_moe(const _Float16* __restrict__ xh,
                                                  const _Float16* __restrict__ xl,
                                                  const float* __restrict__ eo,
                                                  const float* __restrict__ topv,
                                                  const int* __restrict__ route_row,
                                                  const float* __restrict__ g,
                                                  const float* __restrict__ be,
                                                  _Float16* __restrict__ oh,
                                                  _Float16* __restrict__ ol)
{
    int row = blockIdx.x;
    int r0 = route_row[row * 2], r1 = route_row[row * 2 + 1];
    float w0 = topv[row * 2], w1 = topv[row * 2 + 1];
    size_t rb = (size_t)row * D_;
    const float* e0 = eo + (size_t)r0 * D_;
    const float* e1 = eo + (size_t)r1 * D_;
    int tid = threadIdx.x;
    float v0 = (float)xh[rb + tid] + (float)xl[rb + tid] + w0 * e0[tid] + w1 * e1[tid];
    float v1 = (float)xh[rb + tid + 256] + (float)xl[rb + tid + 256] + w0 * e0[tid + 256] + w1 * e1[tid + 256];
    float s = v0 + v1;
    for (int off = 32; off; off >>= 1) s += __shfl_down(s, off);
    __shared__ float red[8];
    int lane = tid & 63, wid = tid >> 6;
    if (!lane) red[wid] = s;
    __syncthreads();
    if (!tid) red[4] = (red[0] + red[1] + red[2] + red[3]) * (1.0f / 512.0f);
    __syncthreads();
    float m = red[4];
    float d0 = v0 - m, d1 = v1 - m;
    s = d0 * d0 + d1 * d1;
    for (int off = 32; off; off >>= 1) s += __shfl_down(s, off);
    if (!lane) red[wid] = s;
    __syncthreads();
    if (!tid) red[5] = rsqrtf((red[0] + red[1] + red[2] + red[3]) * (1.0f / 512.0f) + 1e-5f);
    __syncthreads();
    float rstd = red[5];
    float y0 = d0 * rstd * g[tid] + be[tid];
    float y1 = d1 * rstd * g[tid + 256] + be[tid + 256];
    _Float16 h, l;
    split_f16(y0, h, l); oh[rb + tid] = h; ol[rb + tid] = l;
    split_f16(y1, h, l); oh[rb + tid + 256] = h; ol[rb + tid + 256] = l;
}

// ---------------------------------------------------------------- fused top2 + deterministic routing (64-granular)
__global__ __launch_bounds__(1024) void gate_top2_routes(const float* __restrict__ lg,
                                                         float* __restrict__ topv,
                                                         int* __restrict__ route_tok,
                                                         int* __restrict__ route_row,
                                                         int* __restrict__ counts,
                                                         int* __restrict__ pad_base,
                                                         int* __restrict__ rb_expert)
{
    __shared__ int eid[NTOK * 2];
    __shared__ unsigned short chist[256][8];
    __shared__ int pb[E_ + 1];
    __shared__ int cnt[E_];
    int t = threadIdx.x;
    #pragma unroll
    for (int s2 = 0; s2 < 2; ++s2) {
        int n = t * 2 + s2;
        float l0[E_], p[E_];
        float m = -1e30f;
        #pragma unroll
        for (int e = 0; e < E_; ++e) { l0[e] = lg[n * E_ + e]; m = fmaxf(m, l0[e]); }
        float su = 0.f;
        #pragma unroll
        for (int e = 0; e < E_; ++e) { p[e] = expf(l0[e] - m); su += p[e]; }
        float inv = 1.0f / su;
        int i1 = 0; float v1 = p[0];
        #pragma unroll
        for (int e = 1; e < E_; ++e) if (p[e] > v1) { v1 = p[e]; i1 = e; }
        int i2 = -1; float v2 = -1.f;
        #pragma unroll
        for (int e = 0; e < E_; ++e) if (e != i1 && p[e] > v2) { v2 = p[e]; i2 = e; }
        topv[n * 2] = v1 * inv; topv[n * 2 + 1] = v2 * inv;
        eid[n * 2] = i1; eid[n * 2 + 1] = i2;
    }
    #pragma unroll
    for (int g = 0; g < 5; ++g) route_tok[t + 1024 * g] = 0;
    __syncthreads();

    if (t < 256) {
        int r[16];
        #pragma unroll
        for (int i = 0; i < 16; ++i) r[i] = eid[t * 16 + i];
        #pragma unroll
        for (int e = 0; e < 8; ++e) {
            int h = 0;
            #pragma unroll
            for (int i = 0; i < 16; ++i) h += (r[i] == e) ? 1 : 0;
            chist[t][e] = (unsigned short)h;
        }
    }
    __syncthreads();

    if (t < 8) {
        int run = 0;
        for (int c = 0; c < 256; ++c) {
            int v = chist[c][t];
            chist[c][t] = (unsigned short)run;
            run += v;
        }
        cnt[t] = run;
        counts[t] = run;
    }
    __syncthreads();

    if (t == 0) {
        int pad = 0;
        for (int e = 0; e < 8; ++e) {
            pb[e] = pad;
            pad_base[e] = pad;
            int nb = (cnt[e] + 63) >> 6;
            for (int rb = 0; rb < nb; ++rb) rb_expert[(pad >> 6) + rb] = e;
            pad += nb << 6;
        }
        pb[8] = pad;
        pad_base[8] = pad;
    }
    __syncthreads();

    if (t < 256) {
        int r[16];
        #pragma unroll
        for (int i = 0; i < 16; ++i) r[i] = eid[t * 16 + i];
        #pragma unroll
        for (int e = 0; e < 8; ++e) {
            int o = pb[e] + chist[t][e];
            #pragma unroll
            for (int i = 0; i < 16; ++i) {
                if (r[i] == e) {
                    int slot = t * 16 + i;
                    route_tok[o] = slot >> 1;
                    route_row[slot] = o;
                    o++;
                }
            }
        }
    }
}

// ================================================================ host orchestration
extern "C" void kernel_launch(void* const* d_in, const int* in_sizes, int n_in,
                              void* d_out, int out_size, void* d_ws, size_t ws_size,
                              hipStream_t stream)
{
    const int*   src        = (const int*)  d_in[0];
    const int*   tgt        = (const int*)  d_in[1];
    const float* enc_emb    = (const float*)d_in[2];
    const float* dec_emb    = (const float*)d_in[3];
    const float* enc_attn_w = (const float*)d_in[4];
    const float* enc_attn_b = (const float*)d_in[5];
    const float* enc_ln_g   = (const float*)d_in[6];
    const float* enc_ln_b   = (const float*)d_in[7];
    const float* enc_gate_w = (const float*)d_in[8];
    const float* enc_gate_b = (const float*)d_in[9];
    const float* enc_w1     = (const float*)d_in[10];
    const float* enc_b1     = (const float*)d_in[11];
    const float* enc_w2     = (const float*)d_in[12];
    const float* enc_b2     = (const float*)d_in[13];
    const float* dec_sa_w   = (const float*)d_in[14];
    const float* dec_sa_b   = (const float*)d_in[15];
    const float* dec_ca_w   = (const float*)d_in[16];
    const float* dec_ca_b   = (const float*)d_in[17];
    const float* dec_ln_g   = (const float*)d_in[18];
    const float* dec_ln_b   = (const float*)d_in[19];
    const float* dec_gate_w = (const float*)d_in[20];
    const float* dec_gate_b = (const float*)d_in[21];
    const float* dec_w1     = (const float*)d_in[22];
    const float* dec_b1     = (const float*)d_in[23];
    const float* dec_w2     = (const float*)d_in[24];
    const float* dec_b2     = (const float*)d_in[25];
    const float* out_w      = (const float*)d_in[26];
    const float* out_b      = (const float*)d_in[27];
    float* out = (float*)d_out;

    // ---- d_out scratch (dead until final GEMM overwrites all of it)
    char* ob = (char*)d_out;
    size_t oc = 0;
    auto dalloc = [&](size_t bytes) { char* p = ob + oc; oc += (bytes + 255) & ~(size_t)255; return p; };
    _Float16* qkv_h  = (_Float16*)dalloc((size_t)NTOK * QLD * 2);
    _Float16* qkv_l  = (_Float16*)dalloc((size_t)NTOK * QLD * 2);
    _Float16* vt_h   = (_Float16*)dalloc((size_t)16 * 64 * 1024 * 2);
    _Float16* vt_l   = (_Float16*)dalloc((size_t)16 * 64 * 1024 * 2);
    float* aout  = (float*)dalloc((size_t)NTOK * D_ * 4);
    _Float16* ctx_h = (_Float16*)dalloc((size_t)NTOK * D_ * 2);
    _Float16* ctx_l = (_Float16*)dalloc((size_t)NTOK * D_ * 2);
    _Float16* encA_h = (_Float16*)dalloc((size_t)L_ * 4 * D_ * D_ * 2);
    _Float16* encA_l = (_Float16*)dalloc((size_t)L_ * 4 * D_ * D_ * 2);
    _Float16* saA_h  = (_Float16*)dalloc((size_t)L_ * 4 * D_ * D_ * 2);
    _Float16* saA_l  = (_Float16*)dalloc((size_t)L_ * 4 * D_ * D_ * 2);
    _Float16* caA_h  = (_Float16*)dalloc((size_t)L_ * 4 * D_ * D_ * 2);
    _Float16* caA_l  = (_Float16*)dalloc((size_t)L_ * 4 * D_ * D_ * 2);
    _Float16* xA_h = (_Float16*)dalloc((size_t)NTOK * D_ * 2);
    _Float16* xA_l = (_Float16*)dalloc((size_t)NTOK * D_ * 2);
    _Float16* xB_h = (_Float16*)dalloc((size_t)NTOK * D_ * 2);
    _Float16* xB_l = (_Float16*)dalloc((size_t)NTOK * D_ * 2);
    _Float16* yA_h = (_Float16*)dalloc((size_t)NTOK * D_ * 2);
    _Float16* yA_l = (_Float16*)dalloc((size_t)NTOK * D_ * 2);
    _Float16* yB_h = (_Float16*)dalloc((size_t)NTOK * D_ * 2);
    _Float16* yB_l = (_Float16*)dalloc((size_t)NTOK * D_ * 2);

    // ---- ws scratch (~360 MB of ~1 GB)
    char* wp = (char*)d_ws;
    size_t wc = 0;
    auto walloc = [&](size_t bytes) { char* p = wp + wc; wc += (bytes + 255) & ~(size_t)255; return p; };
    _Float16* outwT_h = (_Float16*)walloc((size_t)V_ * D_ * 2);
    _Float16* final_h = (_Float16*)walloc((size_t)NTOK * D_ * 2);
    size_t wsz = (size_t)L_ * E_ * D_ * F_;          // 16.78M elems per tensor set
    _Float16* ew1t_h = (_Float16*)walloc(wsz * 2);
    _Float16* ew1t_l = (_Float16*)walloc(wsz * 2);
    _Float16* ew2t_h = (_Float16*)walloc(wsz * 2);
    _Float16* ew2t_l = (_Float16*)walloc(wsz * 2);
    _Float16* dw1t_h = (_Float16*)walloc(wsz * 2);
    _Float16* dw1t_l = (_Float16*)walloc(wsz * 2);
    _Float16* dw2t_h = (_Float16*)walloc(wsz * 2);
    _Float16* dw2t_l = (_Float16*)walloc(wsz * 2);
    _Float16* hbuf_h  = (_Float16*)walloc((size_t)MAXPAD * F_ * 2);
    _Float16* hbuf_l  = (_Float16*)walloc((size_t)MAXPAD * F_ * 2);
    float*    eobuf   = (float*)walloc((size_t)MAXPAD * D_ * 4);
    float* lg   = (float*)walloc((size_t)NTOK * E_ * 4);
    float* topv = (float*)walloc((size_t)NTOK * 2 * 4);
    int*   route_tok = (int*)walloc((size_t)5120 * 4);
    int*   route_row = (int*)walloc((size_t)NTOK * 2 * 4);
    int*   counts    = (int*)walloc(64);
    int*   pad_base  = (int*)walloc(64);
    int*   rb_expert = (int*)walloc((size_t)128 * 4);

    // ---- all weight transposes upfront
    transpose_w<true><<<dim3(8, 8, 8), 256, 0, stream>>>(enc_attn_w, encA_h, encA_l, D_, D_);
    transpose_w<true><<<dim3(8, 8, 8), 256, 0, stream>>>(dec_sa_w, saA_h, saA_l, D_, D_);
    transpose_w<true><<<dim3(8, 8, 8), 256, 0, stream>>>(dec_ca_w, caA_h, caA_l, D_, D_);
    transpose_w<false><<<dim3(500, 8, 1), 256, 0, stream>>>(out_w, outwT_h, nullptr, D_, V_);
    transpose_w<true><<<dim3(32, 8, L_ * E_), 256, 0, stream>>>(enc_w1, ew1t_h, ew1t_l, D_, F_);
    transpose_w<true><<<dim3(8, 32, L_ * E_), 256, 0, stream>>>(enc_w2, ew2t_h, ew2t_l, F_, D_);
    transpose_w<true><<<dim3(32, 8, L_ * E_), 256, 0, stream>>>(dec_w1, dw1t_h, dw1t_l, D_, F_);
    transpose_w<true><<<dim3(8, 32, L_ * E_), 256, 0, stream>>>(dec_w2, dw2t_h, dw2t_l, F_, D_);

    auto run_mha = [&](const _Float16* q_h, const _Float16* q_l,
                       const _Float16* kv_h, const _Float16* kv_l,
                       const _Float16* wT_h, const _Float16* wT_l, const float* bt,
                       const int* ktoks, int causal, bool fused) {
        if (fused) {
            gemm_mfma<0, false, 2, 3, 64, 128><<<dim3(32, 12), 256, 0, stream>>>(
                q_h, q_l, wT_h, wT_l, bt, nullptr, qkv_h, qkv_l, vt_h, vt_l, 0,
                NTOK, D_, 1536, QLD, nullptr, nullptr, nullptr, nullptr);
        } else {
            gemm_mfma<0, false, 1, 3, 64, 64><<<dim3(32, 8), 256, 0, stream>>>(
                q_h, q_l, wT_h, wT_l, bt, nullptr, qkv_h, qkv_l, nullptr, nullptr, 0,
                NTOK, D_, 512, QLD, nullptr, nullptr, nullptr, nullptr);
            gemm_mfma<0, false, 2, 3, 64, 128><<<dim3(32, 8), 256, 0, stream>>>(
                kv_h, kv_l, wT_h + (size_t)D_ * D_, wT_l + (size_t)D_ * D_, bt + D_,
                nullptr, qkv_h, qkv_l, vt_h, vt_l, 512,
                NTOK, D_, 1024, QLD, nullptr, nullptr, nullptr, nullptr);
        }
        if (causal)
            attn_flash<1><<<dim3(16, 16), 512, 0, stream>>>(qkv_h, qkv_l, vt_h, vt_l, ktoks, ctx_h, ctx_l);
        else
            attn_flash<0><<<dim3(16, 16), 512, 0, stream>>>(qkv_h, qkv_l, vt_h, vt_l, ktoks, ctx_h, ctx_l);
        gemm_mfma<0, false, 0, 3, 64, 64><<<dim3(32, 8), 256, 0, stream>>>(
            ctx_h, ctx_l, wT_h + (size_t)3 * D_ * D_, wT_l + (size_t)3 * D_ * D_,
            bt + 3 * D_, aout, nullptr, nullptr, nullptr, nullptr, 0,
            NTOK, D_, 512, 512, nullptr, nullptr, nullptr, nullptr);
    };

    auto run_moe = [&](const _Float16* x_h, const _Float16* x_l,
                       const _Float16* w1h, const _Float16* w1l,
                       const _Float16* w2h, const _Float16* w2l,
                       const float* b1p, const float* b2p) {
        gate_top2_routes<<<1, 1024, 0, stream>>>(lg, topv, route_tok, route_row, counts, pad_base, rb_expert);
        gemm_mfma<1, true, 1, 3, 64, 128><<<dim3(RB64, 16), 256, 0, stream>>>(
            x_h, x_l, w1h, w1l, b1p, nullptr, hbuf_h, hbuf_l, nullptr, nullptr, 0,
            0, D_, F_, F_, route_tok, rb_expert, pad_base, counts);
        gemm_mfma<2, false, 0, 3, 64, 64><<<dim3(RB64, 8), 256, 0, stream>>>(
            hbuf_h, hbuf_l, w2h, w2l, b2p, eobuf, nullptr, nullptr, nullptr, nullptr, 0,
            0, F_, D_, D_, route_tok, rb_expert, pad_base, counts);
    };

    // ---------------- encoder ----------------
    embed_pe<<<B_ * S_, 256, 0, stream>>>(src, enc_emb, xA_h, xA_l, S_);
    _Float16* cur_h = xA_h; _Float16* cur_l = xA_l;
    _Float16* alt_h = xB_h; _Float16* alt_l = xB_l;
    for (int l = 0; l < L_; ++l) {
        run_mha(cur_h, cur_l, nullptr, nullptr,
                encA_h + (size_t)l * 4 * D_ * D_, encA_l + (size_t)l * 4 * D_ * D_,
                enc_attn_b + (size_t)l * 4 * D_, src, 0, true);
        ln_add<true><<<NTOK, 256, 0, stream>>>(cur_h, cur_l, aout,
            enc_ln_g + (size_t)(l * 2 + 0) * D_, enc_ln_b + (size_t)(l * 2 + 0) * D_,
            alt_h, alt_l, enc_gate_w + (size_t)l * D_ * E_, enc_gate_b + (size_t)l * E_, lg);
        { _Float16* t = cur_h; cur_h = alt_h; alt_h = t; t = cur_l; cur_l = alt_l; alt_l = t; }
        run_moe(cur_h, cur_l,
                ew1t_h + (size_t)l * E_ * D_ * F_, ew1t_l + (size_t)l * E_ * D_ * F_,
                ew2t_h + (size_t)l * E_ * D_ * F_, ew2t_l + (size_t)l * E_ * D_ * F_,
                enc_b1 + (size_t)l * E_ * F_, enc_b2 + (size_t)l * E_ * D_);
        ln_add_moe<<<NTOK, 256, 0, stream>>>(cur_h, cur_l, eobuf, topv, route_row,
            enc_ln_g + (size_t)(l * 2 + 1) * D_, enc_ln_b + (size_t)(l * 2 + 1) * D_,
            alt_h, alt_l);
        { _Float16* t = cur_h; cur_h = alt_h; alt_h = t; t = cur_l; cur_l = alt_l; alt_l = t; }
    }
    _Float16* enc_h = cur_h; _Float16* enc_l = cur_l;

    // ---------------- decoder ----------------
    embed_pe<<<B_ * T_, 256, 0, stream>>>(tgt, dec_emb, yA_h, yA_l, T_);
    _Float16* dc_h = yA_h; _Float16* dc_l = yA_l;
    _Float16* da_h = yB_h; _Float16* da_l = yB_l;
    for (int l = 0; l < L_; ++l) {
        run_mha(dc_h, dc_l, nullptr, nullptr,
                saA_h + (size_t)l * 4 * D_ * D_, saA_l + (size_t)l * 4 * D_ * D_,
                dec_sa_b + (size_t)l * 4 * D_, tgt, 1, true);
        ln_add<false><<<NTOK, 256, 0, stream>>>(dc_h, dc_l, aout,
            dec_ln_g + (size_t)(l * 3 + 0) * D_, dec_ln_b + (size_t)(l * 3 + 0) * D_,
            da_h, da_l, nullptr, nullptr, nullptr);
        { _Float16* t = dc_h; dc_h = da_h; da_h = t; t = dc_l; dc_l = da_l; da_l = t; }
        run_mha(dc_h, dc_l, enc_h, enc_l,
                caA_h + (size_t)l * 4 * D_ * D_, caA_l + (size_t)l * 4 * D_ * D_,
                dec_ca_b + (size_t)l * 4 * D_, src, 0, false);
        ln_add<true><<<NTOK, 256, 0, stream>>>(dc_h, dc_l, aout,
            dec_ln_g + (size_t)(l * 3 + 1) * D_, dec_ln_b + (size_t)(l * 3 + 1) * D_,
            da_h, da_l, dec_gate_w + (size_t)l * D_ * E_, dec_gate_b + (size_t)l * E_, lg);
        { _Float16* t = dc_h; dc_h = da_h; da_h = t; t = dc_l; dc_l = da_l; da_l = t; }
        run_moe(dc_h, dc_l,
                dw1t_h + (size_t)l * E_ * D_ * F_, dw1t_l + (size_t)l * E_ * D_ * F_,
                dw2t_h + (size_t)l * E_ * D_ * F_, dw2t_l + (size_t)l * E_ * D_ * F_,
                dec_b1 + (size_t)l * E_ * F_, dec_b2 + (size_t)l * E_ * D_);
        bool last = (l == L_ - 1);
        ln_add_moe<<<NTOK, 256, 0, stream>>>(dc_h, dc_l, eobuf, topv, route_row,
            dec_ln_g + (size_t)(l * 3 + 2) * D_, dec_ln_b + (size_t)(l * 3 + 2) * D_,
            last ? final_h : da_h, da_l);
        { _Float16* t = dc_h; dc_h = da_h; da_h = t; t = dc_l; dc_l = da_l; da_l = t; }
    }

    // ---------------- final projection (single-pass f16 MFMA; overwrites all of d_out)
    gemm_mfma<0, false, 0, 1, 128, 128><<<dim3(NTOK / 128, V_ / 128), 256, 0, stream>>>(
        final_h, nullptr, outwT_h, nullptr, out_b, out, nullptr, nullptr, nullptr, nullptr, 0,
        NTOK, D_, V_, V_, nullptr, nullptr, nullptr, nullptr);
}

// Round 8
// 1223.688 us; speedup vs baseline: 4.8258x; 1.0282x over previous
//
#include <hip/hip_runtime.h>
#include <hip/hip_bf16.h>

#define L_ 2
#define D_ 512
#define H_ 8
#define DK_ 64
#define F_ 2048
#define E_ 8
#define V_ 32000
#define B_ 2
#define S_ 1024
#define T_ 1024
#define NTOK (B_*S_)
#define MAXPAD 4608            // per-expert 64-padded total upper bound
#define RB64   72              // MAXPAD/64
#define QLD 1536

typedef unsigned short u16;
typedef _Float16 f16x8 __attribute__((ext_vector_type(8)));
typedef _Float16 f16x4 __attribute__((ext_vector_type(4)));
typedef float f32x4 __attribute__((ext_vector_type(4)));

__device__ __forceinline__ void gload16(const void* g, const void* l) {
    __builtin_amdgcn_global_load_lds(
        (const __attribute__((address_space(1))) void*)g,
        (__attribute__((address_space(3))) void*)l, 16, 0, 0);
}

__device__ __forceinline__ void split_f16(float v, _Float16& h, _Float16& l) {
    h = (_Float16)v;
    l = (_Float16)(v - (float)h);
}

// ---------------------------------------------------------------- embedding + PE (hi/lo f16 only)
__global__ __launch_bounds__(256) void embed_pe(const int* __restrict__ toks,
                                                const float* __restrict__ emb,
                                                _Float16* __restrict__ oh,
                                                _Float16* __restrict__ ol, int Slen)
{
    int n = blockIdx.x;
    int spos = n % Slen;
    int tok = toks[n];
    const float* erow = emb + (size_t)tok * D_;
    size_t rb = (size_t)n * D_;
    for (int j = threadIdx.x; j < D_; j += 256) {
        int i = j >> 1;
        float arg = (float)spos * expf(-(float)i * 0.035977892f);
        float pe = (j & 1) ? cosf(arg) : sinf(arg);
        float v = erow[j] + pe;
        _Float16 h, l; split_f16(v, h, l);
        oh[rb + j] = h; ol[rb + j] = l;
    }
}

// ---------------------------------------------------------------- weight transpose f32[R][C] -> f16 hi/lo [C][R]
// vectorized: float4 loads, f16x4 stores
template<bool WLO>
__global__ __launch_bounds__(256) void transpose_w(const float* __restrict__ in,
                                                   _Float16* __restrict__ oh,
                                                   _Float16* __restrict__ ol, int R, int C)
{
    __shared__ float t[64][65];
    size_t sb = (size_t)blockIdx.z * R * C;
    in += sb; oh += sb; if (WLO) ol += sb;
    int c0 = blockIdx.x * 64, r0 = blockIdx.y * 64;
    int tid = threadIdx.x;
    {
        int r = tid >> 4;
        int cq = (tid & 15) * 4;
        #pragma unroll
        for (int p = 0; p < 4; ++p) {
            int rr = r + p * 16;
            float4 v = *(const float4*)&in[(size_t)(r0 + rr) * C + c0 + cq];
            t[rr][cq] = v.x; t[rr][cq + 1] = v.y; t[rr][cq + 2] = v.z; t[rr][cq + 3] = v.w;
        }
    }
    __syncthreads();
    int rp = (tid & 15) * 4;
    int cb = tid >> 4;
    #pragma unroll
    for (int p = 0; p < 4; ++p) {
        int c = cb + p * 16;
        f16x4 hv, lv;
        #pragma unroll
        for (int j = 0; j < 4; ++j) {
            float v = t[rp + j][c];
            _Float16 h = (_Float16)v;
            hv[j] = h;
            if (WLO) lv[j] = (_Float16)(v - (float)h);
        }
        *(f16x4*)&oh[(size_t)(c0 + c) * R + r0 + rp] = hv;
        if (WLO) *(f16x4*)&ol[(size_t)(c0 + c) * R + r0 + rp] = lv;
    }
}

// ---------------------------------------------------------------- MFMA GEMM (tile-templated)
template<int MODE, bool RELU, int OUTMODE, int PASSES, int TM, int TN>
__global__ __launch_bounds__(256, 2) void gemm_mfma(
    const _Float16* __restrict__ Ah, const _Float16* __restrict__ Al,
    const _Float16* __restrict__ Wh, const _Float16* __restrict__ Wl,
    const float* __restrict__ biasbase,
    float* __restrict__ Cf, _Float16* __restrict__ Ch, _Float16* __restrict__ Cl,
    _Float16* __restrict__ vt_h, _Float16* __restrict__ vt_l, int cbase,
    int M, int Kd, int N, int ldc,
    const int* __restrict__ route_tok, const int* __restrict__ rb_expert,
    const int* __restrict__ pad_base, const int* __restrict__ counts)
{
    constexpr int AR = TM / 32;
    constexpr int BR = TN / 32;
    int row0 = blockIdx.x * TM;
    const _Float16* Wmh = Wh;
    const _Float16* Wml = Wl;
    const float* bias = biasbase;
    int vend = M;
    if (MODE != 0) {
        int total = pad_base[E_];
        if (row0 >= total) return;
        int e = rb_expert[row0 >> 6];
        vend = pad_base[e] + counts[e];
        Wmh = Wh + (size_t)e * Kd * N;
        if (PASSES == 3) Wml = Wl + (size_t)e * Kd * N;
        bias = biasbase + (size_t)e * N;
    }
    int col0 = blockIdx.y * TN;
    int tid = threadIdx.x;
    int lane = tid & 63, w = tid >> 6;
    int wm = w >> 1, wn = w & 1;

    __shared__ _Float16 lds[(PASSES == 3 ? 2 : 1) * (TM + TN) * 64];
    _Float16* lAh = lds;
    _Float16* lBh = lds + TM * 64;
    _Float16* lAl = (PASSES == 3) ? lds + (TM + TN) * 64 : nullptr;
    _Float16* lBl = (PASSES == 3) ? lds + (TM + TN) * 64 + TM * 64 : nullptr;

    int srow8 = lane >> 3;
    int q8 = lane & 7;
    size_t aoff[AR], boff[BR];
    #pragma unroll
    for (int j = 0; j < AR; ++j) {
        int m = w * (TM / 4) + j * 8 + srow8;
        int gr = row0 + m;
        int ar = (MODE == 1) ? route_tok[gr] : gr;
        int ss = (q8 ^ (m & 7)) << 3;
        aoff[j] = (size_t)ar * Kd + ss;
    }
    #pragma unroll
    for (int j = 0; j < BR; ++j) {
        int m = w * (TN / 4) + j * 8 + srow8;
        int ss = (q8 ^ (m & 7)) << 3;
        boff[j] = (size_t)(col0 + m) * Kd + ss;
    }

    f32x4 zero4 = {0.f, 0.f, 0.f, 0.f};
    f32x4 acc[AR][BR];
    #pragma unroll
    for (int i = 0; i < AR; ++i)
        #pragma unroll
        for (int j = 0; j < BR; ++j) acc[i][j] = zero4;

    int lm = lane & 15, kg = lane >> 4;

    for (int k0 = 0; k0 < Kd; k0 += 64) {
        #pragma unroll
        for (int j = 0; j < AR; ++j) {
            int lb = (w * (TM / 4) + j * 8) * 64;
            gload16(Ah + aoff[j] + k0, lAh + lb);
            if (PASSES == 3) gload16(Al + aoff[j] + k0, lAl + lb);
        }
        #pragma unroll
        for (int j = 0; j < BR; ++j) {
            int lb = (w * (TN / 4) + j * 8) * 64;
            gload16(Wmh + boff[j] + k0, lBh + lb);
            if (PASSES == 3) gload16(Wml + boff[j] + k0, lBl + lb);
        }
        __syncthreads();
        #pragma unroll
        for (int ks = 0; ks < 2; ++ks) {
            f16x8 ah[AR], bh[BR];
            #pragma unroll
            for (int i = 0; i < AR; ++i) {
                int m = wm * (TM / 2) + i * 16 + lm;
                ah[i] = *(const f16x8*)&lAh[m * 64 + ((((ks << 2) + kg) ^ (m & 7)) << 3)];
            }
            #pragma unroll
            for (int j = 0; j < BR; ++j) {
                int n = wn * (TN / 2) + j * 16 + lm;
                bh[j] = *(const f16x8*)&lBh[n * 64 + ((((ks << 2) + kg) ^ (n & 7)) << 3)];
            }
            #pragma unroll
            for (int i = 0; i < AR; ++i)
                #pragma unroll
                for (int jn = 0; jn < BR; ++jn)
                    acc[i][jn] = __builtin_amdgcn_mfma_f32_16x16x32_f16(ah[i], bh[jn], acc[i][jn], 0, 0, 0);
            if (PASSES == 3) {
                f16x8 bl[BR];
                #pragma unroll
                for (int j = 0; j < BR; ++j) {
                    int n = wn * (TN / 2) + j * 16 + lm;
                    bl[j] = *(const f16x8*)&lBl[n * 64 + ((((ks << 2) + kg) ^ (n & 7)) << 3)];
                }
                #pragma unroll
                for (int i = 0; i < AR; ++i)
                    #pragma unroll
                    for (int jn = 0; jn < BR; ++jn)
                        acc[i][jn] = __builtin_amdgcn_mfma_f32_16x16x32_f16(ah[i], bl[jn], acc[i][jn], 0, 0, 0);
                f16x8 al[AR];
                #pragma unroll
                for (int i = 0; i < AR; ++i) {
                    int m = wm * (TM / 2) + i * 16 + lm;
                    al[i] = *(const f16x8*)&lAl[m * 64 + ((((ks << 2) + kg) ^ (m & 7)) << 3)];
                }
                #pragma unroll
                for (int i = 0; i < AR; ++i)
                    #pragma unroll
                    for (int jn = 0; jn < BR; ++jn)
                        acc[i][jn] = __builtin_amdgcn_mfma_f32_16x16x32_f16(al[i], bh[jn], acc[i][jn], 0, 0, 0);
            }
        }
        __syncthreads();
    }

    float bv[BR];
    #pragma unroll
    for (int jn = 0; jn < BR; ++jn) bv[jn] = bias[col0 + wn * (TN / 2) + jn * 16 + lm];
    int rowb = row0 + wm * (TM / 2) + (lane >> 4) * 4;

    if (OUTMODE == 2 && (col0 + cbase) >= 1024) {
        #pragma unroll
        for (int i = 0; i < AR; ++i) {
            int row = rowb + i * 16;
            int b = row >> 10, q = row & 1023;
            #pragma unroll
            for (int jn = 0; jn < BR; ++jn) {
                int vcol = col0 + cbase - 1024 + wn * (TN / 2) + jn * 16 + lm;
                int hh = vcol >> 6, dd = vcol & 63;
                f16x4 hv, lv;
                #pragma unroll
                for (int r = 0; r < 4; ++r) {
                    float v = acc[i][jn][r] + bv[jn];
                    _Float16 x1, x2; split_f16(v, x1, x2);
                    hv[r] = x1; lv[r] = x2;
                }
                size_t vtoff = ((size_t)((b << 3) + hh) * 64 + dd) * 1024 + q;
                *(f16x4*)&vt_h[vtoff] = hv;
                *(f16x4*)&vt_l[vtoff] = lv;
            }
        }
        return;
    }

    #pragma unroll
    for (int i = 0; i < AR; ++i) {
        #pragma unroll
        for (int r = 0; r < 4; ++r) {
            int row = rowb + i * 16 + r;
            if (MODE != 0 && row >= vend) continue;
            #pragma unroll
            for (int jn = 0; jn < BR; ++jn) {
                float v = acc[i][jn][r] + bv[jn];
                if (RELU) v = fmaxf(v, 0.f);
                int c = col0 + wn * (TN / 2) + jn * 16 + lm;
                if (OUTMODE == 0) {
                    Cf[(size_t)row * ldc + c] = v;
                } else {
                    _Float16 h, l; split_f16(v, h, l);
                    Ch[(size_t)row * ldc + cbase + c] = h;
                    Cl[(size_t)row * ldc + cbase + c] = l;
                }
            }
        }
    }
}

// ---------------------------------------------------------------- flash attention, 8-wave split-K
template<int CAUSAL>
__global__ __launch_bounds__(512, 1) void attn_flash(
    const _Float16* __restrict__ qkvh, const _Float16* __restrict__ qkvl,
    const _Float16* __restrict__ vth, const _Float16* __restrict__ vtl,
    const int* __restrict__ ktoks,
    _Float16* __restrict__ ch, _Float16* __restrict__ cl)
{
    int q0 = blockIdx.x * 64;
    int bh = blockIdx.y, b = bh >> 3, h = bh & 7;
    int tid = threadIdx.x, lane = tid & 63, w = tid >> 6;
    int qg = w & 3, kh = w >> 2;
    int lm = lane & 15, kg = lane >> 4;
    int srow8 = lane >> 3, q8 = lane & 7;
    int tb = b * S_;

    __shared__ _Float16 smem[49152];
    _Float16* hb  = smem + kh * 16384;
    _Float16* lKh = hb;
    _Float16* lKl = hb + 4096;
    _Float16* lVh = hb + 8192;
    _Float16* lVl = hb + 12288;
    _Float16* lPh = smem + 32768 + w * 1024;
    _Float16* lPl = smem + 40960 + w * 1024;

    size_t qbase = (size_t)b * S_ * QLD + h * DK_;
    const _Float16* Qh = qkvh + qbase;
    const _Float16* Ql = qkvl + qbase;
    const _Float16* Kh = qkvh + qbase + 512;
    const _Float16* Kl = qkvl + qbase + 512;
    const _Float16* Vh = vth + (size_t)bh * 64 * 1024;
    const _Float16* Vl = vtl + (size_t)bh * 64 * 1024;

    f16x8 qfh[2], qfl[2];
    {
        int qr = q0 + qg * 16 + lm;
        #pragma unroll
        for (int ks = 0; ks < 2; ++ks) {
            qfh[ks] = *(const f16x8*)&Qh[(size_t)qr * QLD + ks * 32 + kg * 8];
            qfl[ks] = *(const f16x8*)&Ql[(size_t)qr * QLD + ks * 32 + kg * 8];
        }
    }

    float mreg[4], lreg[4];
    f32x4 od[4];
    f32x4 zero4 = {0.f, 0.f, 0.f, 0.f};
    #pragma unroll
    for (int r = 0; r < 4; ++r) { mreg[r] = -1e30f; lreg[r] = 0.f; }
    #pragma unroll
    for (int jn = 0; jn < 4; ++jn) od[jn] = zero4;

    int qrow[4];
    #pragma unroll
    for (int r = 0; r < 4; ++r) qrow[r] = q0 + qg * 16 + (lane >> 4) * 4 + r;

    int nkt = CAUSAL ? (q0 >> 6) + 1 : 16;
    int nhalf = (nkt + 1) >> 1;

    for (int it = 0; it < nhalf; ++it) {
        int kt = 2 * it + kh;
        bool active = kt < nkt;
        int k0 = kt * 64;

        if (active) {
            #pragma unroll
            for (int j = 0; j < 2; ++j) {
                int row = qg * 16 + j * 8 + srow8;
                int lb = (qg * 16 + j * 8) * 64;
                int ss = (q8 ^ (row & 7)) << 3;
                gload16(Kh + (size_t)(k0 + row) * QLD + ss, lKh + lb);
                gload16(Kl + (size_t)(k0 + row) * QLD + ss, lKl + lb);
                gload16(Vh + (size_t)row * 1024 + k0 + ss, lVh + lb);
                gload16(Vl + (size_t)row * 1024 + k0 + ss, lVl + lb);
            }
        }
        __syncthreads();

        if (active) {
            bool diag = CAUSAL && (kt == (q0 >> 6));
            f32x4 accs[4];
            #pragma unroll
            for (int jn = 0; jn < 4; ++jn) accs[jn] = zero4;
            #pragma unroll
            for (int ks = 0; ks < 2; ++ks) {
                #pragma unroll
                for (int jn = 0; jn < 4; ++jn) {
                    int n = jn * 16 + lm;
                    int koff = n * 64 + ((((ks << 2) + kg) ^ (n & 7)) << 3);
                    f16x8 bhv = *(const f16x8*)&lKh[koff];
                    f16x8 blv = *(const f16x8*)&lKl[koff];
                    accs[jn] = __builtin_amdgcn_mfma_f32_16x16x32_f16(qfh[ks], bhv, accs[jn], 0, 0, 0);
                    accs[jn] = __builtin_amdgcn_mfma_f32_16x16x32_f16(qfh[ks], blv, accs[jn], 0, 0, 0);
                    accs[jn] = __builtin_amdgcn_mfma_f32_16x16x32_f16(qfl[ks], bhv, accs[jn], 0, 0, 0);
                }
            }

            float sv[4][4];
            #pragma unroll
            for (int jn = 0; jn < 4; ++jn) {
                int kglob = k0 + jn * 16 + lm;
                bool pad_ok = (ktoks[tb + kglob] != 0);
                #pragma unroll
                for (int r = 0; r < 4; ++r) {
                    float s = accs[jn][r] * 0.125f;
                    bool keep = pad_ok && (!diag || kglob <= qrow[r]);
                    sv[jn][r] = keep ? s : -1e9f;
                }
            }
            float pv[4][4];
            #pragma unroll
            for (int r = 0; r < 4; ++r) {
                float tm = fmaxf(fmaxf(sv[0][r], sv[1][r]), fmaxf(sv[2][r], sv[3][r]));
                tm = fmaxf(tm, __shfl_xor(tm, 1));
                tm = fmaxf(tm, __shfl_xor(tm, 2));
                tm = fmaxf(tm, __shfl_xor(tm, 4));
                tm = fmaxf(tm, __shfl_xor(tm, 8));
                float mnew = fmaxf(mreg[r], tm);
                float corr = expf(mreg[r] - mnew);
                lreg[r] *= corr;
                #pragma unroll
                for (int jn = 0; jn < 4; ++jn) od[jn][r] *= corr;
                float psum = 0.f;
                #pragma unroll
                for (int jn = 0; jn < 4; ++jn) {
                    float p = expf(sv[jn][r] - mnew);
                    pv[jn][r] = p;
                    psum += p;
                }
                psum += __shfl_xor(psum, 1);
                psum += __shfl_xor(psum, 2);
                psum += __shfl_xor(psum, 4);
                psum += __shfl_xor(psum, 8);
                lreg[r] += psum;
                mreg[r] = mnew;
            }

            #pragma unroll
            for (int jn = 0; jn < 4; ++jn) {
                int col = jn * 16 + lm;
                #pragma unroll
                for (int r = 0; r < 4; ++r) {
                    int rr = (lane >> 4) * 4 + r;
                    int idx = rr * 64 + (((col >> 3) ^ (rr & 7)) << 3) + (col & 7);
                    _Float16 hh, ll; split_f16(pv[jn][r], hh, ll);
                    lPh[idx] = hh; lPl[idx] = ll;
                }
            }

            #pragma unroll
            for (int ks = 0; ks < 2; ++ks) {
                int poff = lm * 64 + ((((ks << 2) + kg) ^ (lm & 7)) << 3);
                f16x8 pah = *(const f16x8*)&lPh[poff];
                f16x8 pal = *(const f16x8*)&lPl[poff];
                #pragma unroll
                for (int jn = 0; jn < 4; ++jn) {
                    int n = jn * 16 + lm;
                    int noff = n * 64 + ((((ks << 2) + kg) ^ (n & 7)) << 3);
                    f16x8 vbh = *(const f16x8*)&lVh[noff];
                    f16x8 vbl = *(const f16x8*)&lVl[noff];
                    od[jn] = __builtin_amdgcn_mfma_f32_16x16x32_f16(pah, vbh, od[jn], 0, 0, 0);
                    od[jn] = __builtin_amdgcn_mfma_f32_16x16x32_f16(pah, vbl, od[jn], 0, 0, 0);
                    od[jn] = __builtin_amdgcn_mfma_f32_16x16x32_f16(pal, vbh, od[jn], 0, 0, 0);
                }
            }
        }
        __syncthreads();
    }

    float* mrg = (float*)(smem + 32768);
    if (kh == 1) {
        float* mp = mrg + ((size_t)qg * 64 + lane) * 24;
        #pragma unroll
        for (int jn = 0; jn < 4; ++jn)
            #pragma unroll
            for (int r = 0; r < 4; ++r) mp[jn * 4 + r] = od[jn][r];
        #pragma unroll
        for (int r = 0; r < 4; ++r) { mp[16 + r] = mreg[r]; mp[20 + r] = lreg[r]; }
    }
    __syncthreads();
    if (kh == 0) {
        float* mp = mrg + ((size_t)qg * 64 + lane) * 24;
        #pragma unroll
        for (int r = 0; r < 4; ++r) {
            float m1 = mp[16 + r], l1 = mp[20 + r];
            float m = fmaxf(mreg[r], m1);
            float c0 = expf(mreg[r] - m), c1 = expf(m1 - m);
            float inv = 1.0f / (lreg[r] * c0 + l1 * c1);
            size_t rbase = (size_t)(tb + qrow[r]) * D_ + h * DK_;
            #pragma unroll
            for (int jn = 0; jn < 4; ++jn) {
                float o = (od[jn][r] * c0 + mp[jn * 4 + r] * c1) * inv;
                _Float16 hh, ll; split_f16(o, hh, ll);
                int d = jn * 16 + lm;
                ch[rbase + d] = hh; cl[rbase + d] = ll;
            }
        }
    }
}

// ---------------------------------------------------------------- residual + LN (+ optional fused gate logits)
template<bool GATE>
__global__ __launch_bounds__(256) void ln_add(const _Float16* __restrict__ xh,
                                              const _Float16* __restrict__ xl,
                                              const float* __restrict__ r,
                                              const float* __restrict__ g,
                                              const float* __restrict__ be,
                                              _Float16* __restrict__ oh,
                                              _Float16* __restrict__ ol,
                                              const float* __restrict__ gw,
                                              const float* __restrict__ gb,
                                              float* __restrict__ lg)
{
    int row = blockIdx.x;
    size_t rb = (size_t)row * D_;
    int tid = threadIdx.x;
    float v0 = (float)xh[rb + tid] + (float)xl[rb + tid] + r[rb + tid];
    float v1 = (float)xh[rb + tid + 256] + (float)xl[rb + tid + 256] + r[rb + tid + 256];
    float s = v0 + v1;
    for (int off = 32; off; off >>= 1) s += __shfl_down(s, off);
    __shared__ float red[8];
    __shared__ float gred[4][E_];
    int lane = tid & 63, wid = tid >> 6;
    if (!lane) red[wid] = s;
    __syncthreads();
    if (!tid) red[4] = (red[0] + red[1] + red[2] + red[3]) * (1.0f / 512.0f);
    __syncthreads();
    float m = red[4];
    float d0 = v0 - m, d1 = v1 - m;
    s = d0 * d0 + d1 * d1;
    for (int off = 32; off; off >>= 1) s += __shfl_down(s, off);
    if (!lane) red[wid] = s;
    __syncthreads();
    if (!tid) red[5] = rsqrtf((red[0] + red[1] + red[2] + red[3]) * (1.0f / 512.0f) + 1e-5f);
    __syncthreads();
    float rstd = red[5];
    float y0 = d0 * rstd * g[tid] + be[tid];
    float y1 = d1 * rstd * g[tid + 256] + be[tid + 256];
    _Float16 h, l;
    split_f16(y0, h, l); oh[rb + tid] = h; ol[rb + tid] = l;
    split_f16(y1, h, l); oh[rb + tid + 256] = h; ol[rb + tid + 256] = l;
    if (GATE) {
        float acc[E_];
        const float* g0 = gw + (size_t)tid * E_;
        const float* g1 = gw + (size_t)(tid + 256) * E_;
        #pragma unroll
        for (int e = 0; e < E_; ++e) acc[e] = y0 * g0[e] + y1 * g1[e];
        #pragma unroll
        for (int e = 0; e < E_; ++e)
            for (int off = 32; off; off >>= 1) acc[e] += __shfl_down(acc[e], off);
        if (!lane) {
            #pragma unroll
            for (int e = 0; e < E_; ++e) gred[wid][e] = acc[e];
        }
        __syncthreads();
        if (tid < E_)
            lg[(size_t)row * E_ + tid] = gred[0][tid] + gred[1][tid] + gred[2][tid] + gred[3][tid] + gb[tid];
    }
}

// ---------------------------------------------------------------- MoE combine + residual + LN fused
__global__ __launch_bounds__(256) void ln_add_moe(const _Float16* __restrict__ xh,
                                                  const _Float16* __restrict__ xl,
                                                  const float* __restrict__ eo,
                                                  const float* __restrict__ topv,
                                                  const int* __restrict__ route_row,
                                                  const float* __restrict__ g,
                                                  const float* __restrict__ be,
                                                  _Float16* __restrict__ oh,
                                                  _Float16* __restrict__ ol)
{
    int row = blockIdx.x;
    int r0 = route_row[row * 2], r1 = route_row[row * 2 + 1];
    float w0 = topv[row * 2], w1 = topv[row * 2 + 1];
    size_t rb = (size_t)row * D_;
    const float* e0 = eo + (size_t)r0 * D_;
    const float* e1 = eo + (size_t)r1 * D_;
    int tid = threadIdx.x;
    float v0 = (float)xh[rb + tid] + (float)xl[rb + tid] + w0 * e0[tid] + w1 * e1[tid];
    float v1 = (float)xh[rb + tid + 256] + (float)xl[rb + tid + 256] + w0 * e0[tid + 256] + w1 * e1[tid + 256];
    float s = v0 + v1;
    for (int off = 32; off; off >>= 1) s += __shfl_down(s, off);
    __shared__ float red[8];
    int lane = tid & 63, wid = tid >> 6;
    if (!lane) red[wid] = s;
    __syncthreads();
    if (!tid) red[4] = (red[0] + red[1] + red[2] + red[3]) * (1.0f / 512.0f);
    __syncthreads();
    float m = red[4];
    float d0 = v0 - m, d1 = v1 - m;
    s = d0 * d0 + d1 * d1;
    for (int off = 32; off; off >>= 1) s += __shfl_down(s, off);
    if (!lane) red[wid] = s;
    __syncthreads();
    if (!tid) red[5] = rsqrtf((red[0] + red[1] + red[2] + red[3]) * (1.0f / 512.0f) + 1e-5f);
    __syncthreads();
    float rstd = red[5];
    float y0 = d0 * rstd * g[tid] + be[tid];
    float y1 = d1 * rstd * g[tid + 256] + be[tid + 256];
    _Float16 h, l;
    split_f16(y0, h, l); oh[rb + tid] = h; ol[rb + tid] = l;
    split_f16(y1, h, l); oh[rb + tid + 256] = h; ol[rb + tid + 256] = l;
}

// ---------------------------------------------------------------- fused top2 + deterministic routing (64-granular)
__global__ __launch_bounds__(1024) void gate_top2_routes(const float* __restrict__ lg,
                                                         float* __restrict__ topv,
                                                         int* __restrict__ route_tok,
                                                         int* __restrict__ route_row,
                                                         int* __restrict__ counts,
                                                         int* __restrict__ pad_base,
                                                         int* __restrict__ rb_expert)
{
    __shared__ int eid[NTOK * 2];
    __shared__ unsigned short chist[256][8];
    __shared__ int pb[E_ + 1];
    __shared__ int cnt[E_];
    int t = threadIdx.x;
    #pragma unroll
    for (int s2 = 0; s2 < 2; ++s2) {
        int n = t * 2 + s2;
        float l0[E_], p[E_];
        float m = -1e30f;
        #pragma unroll
        for (int e = 0; e < E_; ++e) { l0[e] = lg[n * E_ + e]; m = fmaxf(m, l0[e]); }
        float su = 0.f;
        #pragma unroll
        for (int e = 0; e < E_; ++e) { p[e] = expf(l0[e] - m); su += p[e]; }
        float inv = 1.0f / su;
        int i1 = 0; float v1 = p[0];
        #pragma unroll
        for (int e = 1; e < E_; ++e) if (p[e] > v1) { v1 = p[e]; i1 = e; }
        int i2 = -1; float v2 = -1.f;
        #pragma unroll
        for (int e = 0; e < E_; ++e) if (e != i1 && p[e] > v2) { v2 = p[e]; i2 = e; }
        topv[n * 2] = v1 * inv; topv[n * 2 + 1] = v2 * inv;
        eid[n * 2] = i1; eid[n * 2 + 1] = i2;
    }
    #pragma unroll
    for (int g = 0; g < 5; ++g) route_tok[t + 1024 * g] = 0;
    __syncthreads();

    if (t < 256) {
        int r[16];
        #pragma unroll
        for (int i = 0; i < 16; ++i) r[i] = eid[t * 16 + i];
        #pragma unroll
        for (int e = 0; e < 8; ++e) {
            int h = 0;
            #pragma unroll
            for (int i = 0; i < 16; ++i) h += (r[i] == e) ? 1 : 0;
            chist[t][e] = (unsigned short)h;
        }
    }
    __syncthreads();

    if (t < 8) {
        int run = 0;
        for (int c = 0; c < 256; ++c) {
            int v = chist[c][t];
            chist[c][t] = (unsigned short)run;
            run += v;
        }
        cnt[t] = run;
        counts[t] = run;
    }
    __syncthreads();

    if (t == 0) {
        int pad = 0;
        for (int e = 0; e < 8; ++e) {
            pb[e] = pad;
            pad_base[e] = pad;
            int nb = (cnt[e] + 63) >> 6;
            for (int rb = 0; rb < nb; ++rb) rb_expert[(pad >> 6) + rb] = e;
            pad += nb << 6;
        }
        pb[8] = pad;
        pad_base[8] = pad;
    }
    __syncthreads();

    if (t < 256) {
        int r[16];
        #pragma unroll
        for (int i = 0; i < 16; ++i) r[i] = eid[t * 16 + i];
        #pragma unroll
        for (int e = 0; e < 8; ++e) {
            int o = pb[e] + chist[t][e];
            #pragma unroll
            for (int i = 0; i < 16; ++i) {
                if (r[i] == e) {
                    int slot = t * 16 + i;
                    route_tok[o] = slot >> 1;
                    route_row[slot] = o;
                    o++;
                }
            }
        }
    }
}

// ================================================================ host orchestration
extern "C" void kernel_launch(void* const* d_in, const int* in_sizes, int n_in,
                              void* d_out, int out_size, void* d_ws, size_t ws_size,
                              hipStream_t stream)
{
    const int*   src        = (const int*)  d_in[0];
    const int*   tgt        = (const int*)  d_in[1];
    const float* enc_emb    = (const float*)d_in[2];
    const float* dec_emb    = (const float*)d_in[3];
    const float* enc_attn_w = (const float*)d_in[4];
    const float* enc_attn_b = (const float*)d_in[5];
    const float* enc_ln_g   = (const float*)d_in[6];
    const float* enc_ln_b   = (const float*)d_in[7];
    const float* enc_gate_w = (const float*)d_in[8];
    const float* enc_gate_b = (const float*)d_in[9];
    const float* enc_w1     = (const float*)d_in[10];
    const float* enc_b1     = (const float*)d_in[11];
    const float* enc_w2     = (const float*)d_in[12];
    const float* enc_b2     = (const float*)d_in[13];
    const float* dec_sa_w   = (const float*)d_in[14];
    const float* dec_sa_b   = (const float*)d_in[15];
    const float* dec_ca_w   = (const float*)d_in[16];
    const float* dec_ca_b   = (const float*)d_in[17];
    const float* dec_ln_g   = (const float*)d_in[18];
    const float* dec_ln_b   = (const float*)d_in[19];
    const float* dec_gate_w = (const float*)d_in[20];
    const float* dec_gate_b = (const float*)d_in[21];
    const float* dec_w1     = (const float*)d_in[22];
    const float* dec_b1     = (const float*)d_in[23];
    const float* dec_w2     = (const float*)d_in[24];
    const float* dec_b2     = (const float*)d_in[25];
    const float* out_w      = (const float*)d_in[26];
    const float* out_b      = (const float*)d_in[27];
    float* out = (float*)d_out;

    // ---- d_out scratch (dead until final GEMM overwrites all of it)
    char* ob = (char*)d_out;
    size_t oc = 0;
    auto dalloc = [&](size_t bytes) { char* p = ob + oc; oc += (bytes + 255) & ~(size_t)255; return p; };
    _Float16* qkv_h  = (_Float16*)dalloc((size_t)NTOK * QLD * 2);
    _Float16* qkv_l  = (_Float16*)dalloc((size_t)NTOK * QLD * 2);
    _Float16* vt_h   = (_Float16*)dalloc((size_t)16 * 64 * 1024 * 2);
    _Float16* vt_l   = (_Float16*)dalloc((size_t)16 * 64 * 1024 * 2);
    float* aout  = (float*)dalloc((size_t)NTOK * D_ * 4);
    _Float16* ctx_h = (_Float16*)dalloc((size_t)NTOK * D_ * 2);
    _Float16* ctx_l = (_Float16*)dalloc((size_t)NTOK * D_ * 2);
    _Float16* encA_h = (_Float16*)dalloc((size_t)L_ * 4 * D_ * D_ * 2);
    _Float16* encA_l = (_Float16*)dalloc((size_t)L_ * 4 * D_ * D_ * 2);
    _Float16* saA_h  = (_Float16*)dalloc((size_t)L_ * 4 * D_ * D_ * 2);
    _Float16* saA_l  = (_Float16*)dalloc((size_t)L_ * 4 * D_ * D_ * 2);
    _Float16* caA_h  = (_Float16*)dalloc((size_t)L_ * 4 * D_ * D_ * 2);
    _Float16* caA_l  = (_Float16*)dalloc((size_t)L_ * 4 * D_ * D_ * 2);
    _Float16* xA_h = (_Float16*)dalloc((size_t)NTOK * D_ * 2);
    _Float16* xA_l = (_Float16*)dalloc((size_t)NTOK * D_ * 2);
    _Float16* xB_h = (_Float16*)dalloc((size_t)NTOK * D_ * 2);
    _Float16* xB_l = (_Float16*)dalloc((size_t)NTOK * D_ * 2);
    _Float16* yA_h = (_Float16*)dalloc((size_t)NTOK * D_ * 2);
    _Float16* yA_l = (_Float16*)dalloc((size_t)NTOK * D_ * 2);
    _Float16* yB_h = (_Float16*)dalloc((size_t)NTOK * D_ * 2);
    _Float16* yB_l = (_Float16*)dalloc((size_t)NTOK * D_ * 2);

    // ---- ws scratch (~360 MB of ~1 GB)
    char* wp = (char*)d_ws;
    size_t wc = 0;
    auto walloc = [&](size_t bytes) { char* p = wp + wc; wc += (bytes + 255) & ~(size_t)255; return p; };
    _Float16* outwT_h = (_Float16*)walloc((size_t)V_ * D_ * 2);
    _Float16* final_h = (_Float16*)walloc((size_t)NTOK * D_ * 2);
    size_t wsz = (size_t)L_ * E_ * D_ * F_;
    _Float16* ew1t_h = (_Float16*)walloc(wsz * 2);
    _Float16* ew1t_l = (_Float16*)walloc(wsz * 2);
    _Float16* ew2t_h = (_Float16*)walloc(wsz * 2);
    _Float16* ew2t_l = (_Float16*)walloc(wsz * 2);
    _Float16* dw1t_h = (_Float16*)walloc(wsz * 2);
    _Float16* dw1t_l = (_Float16*)walloc(wsz * 2);
    _Float16* dw2t_h = (_Float16*)walloc(wsz * 2);
    _Float16* dw2t_l = (_Float16*)walloc(wsz * 2);
    _Float16* hbuf_h  = (_Float16*)walloc((size_t)MAXPAD * F_ * 2);
    _Float16* hbuf_l  = (_Float16*)walloc((size_t)MAXPAD * F_ * 2);
    float*    eobuf   = (float*)walloc((size_t)MAXPAD * D_ * 4);
    float* lg   = (float*)walloc((size_t)NTOK * E_ * 4);
    float* topv = (float*)walloc((size_t)NTOK * 2 * 4);
    int*   route_tok = (int*)walloc((size_t)5120 * 4);
    int*   route_row = (int*)walloc((size_t)NTOK * 2 * 4);
    int*   counts    = (int*)walloc(64);
    int*   pad_base  = (int*)walloc(64);
    int*   rb_expert = (int*)walloc((size_t)128 * 4);

    // ---- all weight transposes upfront
    transpose_w<true><<<dim3(8, 8, 8), 256, 0, stream>>>(enc_attn_w, encA_h, encA_l, D_, D_);
    transpose_w<true><<<dim3(8, 8, 8), 256, 0, stream>>>(dec_sa_w, saA_h, saA_l, D_, D_);
    transpose_w<true><<<dim3(8, 8, 8), 256, 0, stream>>>(dec_ca_w, caA_h, caA_l, D_, D_);
    transpose_w<false><<<dim3(500, 8, 1), 256, 0, stream>>>(out_w, outwT_h, nullptr, D_, V_);
    transpose_w<true><<<dim3(32, 8, L_ * E_), 256, 0, stream>>>(enc_w1, ew1t_h, ew1t_l, D_, F_);
    transpose_w<true><<<dim3(8, 32, L_ * E_), 256, 0, stream>>>(enc_w2, ew2t_h, ew2t_l, F_, D_);
    transpose_w<true><<<dim3(32, 8, L_ * E_), 256, 0, stream>>>(dec_w1, dw1t_h, dw1t_l, D_, F_);
    transpose_w<true><<<dim3(8, 32, L_ * E_), 256, 0, stream>>>(dec_w2, dw2t_h, dw2t_l, F_, D_);

    auto run_mha = [&](const _Float16* q_h, const _Float16* q_l,
                       const _Float16* kv_h, const _Float16* kv_l,
                       const _Float16* wT_h, const _Float16* wT_l, const float* bt,
                       const int* ktoks, int causal, bool fused) {
        if (fused) {
            gemm_mfma<0, false, 2, 3, 64, 128><<<dim3(32, 12), 256, 0, stream>>>(
                q_h, q_l, wT_h, wT_l, bt, nullptr, qkv_h, qkv_l, vt_h, vt_l, 0,
                NTOK, D_, 1536, QLD, nullptr, nullptr, nullptr, nullptr);
        } else {
            gemm_mfma<0, false, 1, 3, 64, 64><<<dim3(32, 8), 256, 0, stream>>>(
                q_h, q_l, wT_h, wT_l, bt, nullptr, qkv_h, qkv_l, nullptr, nullptr, 0,
                NTOK, D_, 512, QLD, nullptr, nullptr, nullptr, nullptr);
            gemm_mfma<0, false, 2, 3, 64, 128><<<dim3(32, 8), 256, 0, stream>>>(
                kv_h, kv_l, wT_h + (size_t)D_ * D_, wT_l + (size_t)D_ * D_, bt + D_,
                nullptr, qkv_h, qkv_l, vt_h, vt_l, 512,
                NTOK, D_, 1024, QLD, nullptr, nullptr, nullptr, nullptr);
        }
        if (causal)
            attn_flash<1><<<dim3(16, 16), 512, 0, stream>>>(qkv_h, qkv_l, vt_h, vt_l, ktoks, ctx_h, ctx_l);
        else
            attn_flash<0><<<dim3(16, 16), 512, 0, stream>>>(qkv_h, qkv_l, vt_h, vt_l, ktoks, ctx_h, ctx_l);
        gemm_mfma<0, false, 0, 3, 64, 64><<<dim3(32, 8), 256, 0, stream>>>(
            ctx_h, ctx_l, wT_h + (size_t)3 * D_ * D_, wT_l + (size_t)3 * D_ * D_,
            bt + 3 * D_, aout, nullptr, nullptr, nullptr, nullptr, 0,
            NTOK, D_, 512, 512, nullptr, nullptr, nullptr, nullptr);
    };

    auto run_moe = [&](const _Float16* x_h, const _Float16* x_l,
                       const _Float16* w1h, const _Float16* w1l,
                       const _Float16* w2h, const _Float16* w2l,
                       const float* b1p, const float* b2p, bool p3) {
        gate_top2_routes<<<1, 1024, 0, stream>>>(lg, topv, route_tok, route_row, counts, pad_base, rb_expert);
        if (p3) {
            gemm_mfma<1, true, 1, 3, 64, 128><<<dim3(RB64, 16), 256, 0, stream>>>(
                x_h, x_l, w1h, w1l, b1p, nullptr, hbuf_h, hbuf_l, nullptr, nullptr, 0,
                0, D_, F_, F_, route_tok, rb_expert, pad_base, counts);
            gemm_mfma<2, false, 0, 3, 64, 64><<<dim3(RB64, 8), 256, 0, stream>>>(
                hbuf_h, hbuf_l, w2h, w2l, b2p, eobuf, nullptr, nullptr, nullptr, nullptr, 0,
                0, F_, D_, D_, route_tok, rb_expert, pad_base, counts);
        } else {
            // post-last-gate: single-pass f16 (error ~2e-3 on eo, no routing impact)
            gemm_mfma<1, true, 1, 1, 64, 128><<<dim3(RB64, 16), 256, 0, stream>>>(
                x_h, nullptr, w1h, nullptr, b1p, nullptr, hbuf_h, hbuf_l, nullptr, nullptr, 0,
                0, D_, F_, F_, route_tok, rb_expert, pad_base, counts);
            gemm_mfma<2, false, 0, 1, 64, 64><<<dim3(RB64, 8), 256, 0, stream>>>(
                hbuf_h, nullptr, w2h, nullptr, b2p, eobuf, nullptr, nullptr, nullptr, nullptr, 0,
                0, F_, D_, D_, route_tok, rb_expert, pad_base, counts);
        }
    };

    // ---------------- encoder ----------------
    embed_pe<<<B_ * S_, 256, 0, stream>>>(src, enc_emb, xA_h, xA_l, S_);
    _Float16* cur_h = xA_h; _Float16* cur_l = xA_l;
    _Float16* alt_h = xB_h; _Float16* alt_l = xB_l;
    for (int l = 0; l < L_; ++l) {
        run_mha(cur_h, cur_l, nullptr, nullptr,
                encA_h + (size_t)l * 4 * D_ * D_, encA_l + (size_t)l * 4 * D_ * D_,
                enc_attn_b + (size_t)l * 4 * D_, src, 0, true);
        ln_add<true><<<NTOK, 256, 0, stream>>>(cur_h, cur_l, aout,
            enc_ln_g + (size_t)(l * 2 + 0) * D_, enc_ln_b + (size_t)(l * 2 + 0) * D_,
            alt_h, alt_l, enc_gate_w + (size_t)l * D_ * E_, enc_gate_b + (size_t)l * E_, lg);
        { _Float16* t = cur_h; cur_h = alt_h; alt_h = t; t = cur_l; cur_l = alt_l; alt_l = t; }
        run_moe(cur_h, cur_l,
                ew1t_h + (size_t)l * E_ * D_ * F_, ew1t_l + (size_t)l * E_ * D_ * F_,
                ew2t_h + (size_t)l * E_ * D_ * F_, ew2t_l + (size_t)l * E_ * D_ * F_,
                enc_b1 + (size_t)l * E_ * F_, enc_b2 + (size_t)l * E_ * D_, true);
        ln_add_moe<<<NTOK, 256, 0, stream>>>(cur_h, cur_l, eobuf, topv, route_row,
            enc_ln_g + (size_t)(l * 2 + 1) * D_, enc_ln_b + (size_t)(l * 2 + 1) * D_,
            alt_h, alt_l);
        { _Float16* t = cur_h; cur_h = alt_h; alt_h = t; t = cur_l; cur_l = alt_l; alt_l = t; }
    }
    _Float16* enc_h = cur_h; _Float16* enc_l = cur_l;

    // ---------------- decoder ----------------
    embed_pe<<<B_ * T_, 256, 0, stream>>>(tgt, dec_emb, yA_h, yA_l, T_);
    _Float16* dc_h = yA_h; _Float16* dc_l = yA_l;
    _Float16* da_h = yB_h; _Float16* da_l = yB_l;
    for (int l = 0; l < L_; ++l) {
        run_mha(dc_h, dc_l, nullptr, nullptr,
                saA_h + (size_t)l * 4 * D_ * D_, saA_l + (size_t)l * 4 * D_ * D_,
                dec_sa_b + (size_t)l * 4 * D_, tgt, 1, true);
        ln_add<false><<<NTOK, 256, 0, stream>>>(dc_h, dc_l, aout,
            dec_ln_g + (size_t)(l * 3 + 0) * D_, dec_ln_b + (size_t)(l * 3 + 0) * D_,
            da_h, da_l, nullptr, nullptr, nullptr);
        { _Float16* t = dc_h; dc_h = da_h; da_h = t; t = dc_l; dc_l = da_l; da_l = t; }
        run_mha(dc_h, dc_l, enc_h, enc_l,
                caA_h + (size_t)l * 4 * D_ * D_, caA_l + (size_t)l * 4 * D_ * D_,
                dec_ca_b + (size_t)l * 4 * D_, src, 0, false);
        ln_add<true><<<NTOK, 256, 0, stream>>>(dc_h, dc_l, aout,
            dec_ln_g + (size_t)(l * 3 + 1) * D_, dec_ln_b + (size_t)(l * 3 + 1) * D_,
            da_h, da_l, dec_gate_w + (size_t)l * D_ * E_, dec_gate_b + (size_t)l * E_, lg);
        { _Float16* t = dc_h; dc_h = da_h; da_h = t; t = dc_l; dc_l = da_l; da_l = t; }
        bool last = (l == L_ - 1);
        run_moe(dc_h, dc_l,
                dw1t_h + (size_t)l * E_ * D_ * F_, dw1t_l + (size_t)l * E_ * D_ * F_,
                dw2t_h + (size_t)l * E_ * D_ * F_, dw2t_l + (size_t)l * E_ * D_ * F_,
                dec_b1 + (size_t)l * E_ * F_, dec_b2 + (size_t)l * E_ * D_, !last);
        ln_add_moe<<<NTOK, 256, 0, stream>>>(dc_h, dc_l, eobuf, topv, route_row,
            dec_ln_g + (size_t)(l * 3 + 2) * D_, dec_ln_b + (size_t)(l * 3 + 2) * D_,
            last ? final_h : da_h, da_l);
        { _Float16* t = dc_h; dc_h = da_h; da_h = t; t = dc_l; dc_l = da_l; da_l = t; }
    }

    // ---------------- final projection (single-pass f16 MFMA; overwrites all of d_out)
    gemm_mfma<0, false, 0, 1, 128, 128><<<dim3(NTOK / 128, V_ / 128), 256, 0, stream>>>(
        final_h, nullptr, outwT_h, nullptr, out_b, out, nullptr, nullptr, nullptr, nullptr, 0,
        NTOK, D_, V_, V_, nullptr, nullptr, nullptr, nullptr);
}